// Round 4
// baseline (1124.800 us; speedup 1.0000x reference)
//
#include <hip/hip_runtime.h>
#include <hip/hip_bf16.h>
#include <math.h>

#define Hh 360
#define Ww 720
#define Cc 64
#define Bb 2
#define BC (Bb*Cc)        // 128
#define Mrows (BC*Hh)     // 46080
#define CHUNKS 4
#define CM (Mrows/CHUNKS) // 11520
#define KF3 1152          // fwd K: [hi|lo|hi] blocks of 384
#define NF 384            // fwd N (361 bins padded)
#define KI 768            // inv K: [Re(384) | Im(384)]
#define NI 768            // inv N alloc (720 used)
#define NSTORE_INV 720
#define SCALE 0.037267799624996496f   // 1/sqrt(720)
#define TWO_PI 6.2831853071795864769f

typedef __attribute__((ext_vector_type(8))) short s16x8;
typedef __attribute__((ext_vector_type(4))) float f32x4;
typedef __hip_bfloat16 bf16;

__device__ __forceinline__ void gload_lds16(const void* g, void* l) {
    __builtin_amdgcn_global_load_lds(
        (const __attribute__((address_space(1))) unsigned int*)g,
        (__attribute__((address_space(3))) unsigned int*)l, 16, 0, 0);
}

// ---------------------------------------------------------- B-matrix builds
__global__ __launch_bounds__(256) void build_bfwd_kernel(bf16* __restrict__ Bc,
                                                         bf16* __restrict__ Bs) {
    int g = blockIdx.x * 256 + threadIdx.x;
    if (g >= NF * KF3) return;
    int wext = g % KF3;
    int j = g / KF3;
    int blk = wext / 384;
    int w = wext - blk * 384;
    float c = 0.f, s = 0.f;
    if (w <= 360 && j <= 360) {
        int idx = (j * w) % Ww;
        float a = (TWO_PI / Ww) * (float)idx;
        float sv, cv;
        sincosf(a, &sv, &cv);
        c = SCALE * cv;
        s = -SCALE * sv;
    }
    bf16 chi = __float2bfloat16(c);
    bf16 shi = __float2bfloat16(s);
    if (blk == 2) {
        Bc[g] = __float2bfloat16(c - __bfloat162float(chi));
        Bs[g] = __float2bfloat16(s - __bfloat162float(shi));
    } else {
        Bc[g] = chi;
        Bs[g] = shi;
    }
}

__global__ __launch_bounds__(256) void build_binv_kernel(bf16* __restrict__ Bi) {
    int g = blockIdx.x * 256 + threadIdx.x;
    if (g >= NI * KI) return;
    int k = g % KI, n = g / KI;
    float v = 0.f;
    if (n < NSTORE_INV) {
        if (k <= 360) {
            int j = k;
            float f = (j == 0 || j == 360) ? 1.f : 2.f;
            int idx = (j * n) % Ww;
            v = SCALE * f * cosf((TWO_PI / Ww) * (float)idx);
        } else if (k >= 384 && k <= 744) {
            int j = k - 384;
            int idx = (j * n) % Ww;
            v = -2.f * SCALE * sinf((TWO_PI / Ww) * (float)idx);
        }
    }
    Bi[g] = __float2bfloat16(v);
}

// W1ext/W2ext: [128 n][256 k] bf16. k<128: hi of M(n,k); k>=128: lo of M(n,k-128).
// M(n,kk): n<64 (Re out): kk<64: wr[n][kk]; kk>=64: -wi[n][kk-64]
//          n>=64 (Im out, p=n-64): kk<64: wi[p][kk]; kk>=64: wr[p][kk-64]
__global__ __launch_bounds__(256) void build_wext_kernel(
    const float* __restrict__ w1_r, const float* __restrict__ w1_i,
    const float* __restrict__ w2_r, const float* __restrict__ w2_i,
    bf16* __restrict__ W1e, bf16* __restrict__ W2e)
{
    int g = blockIdx.x * 256 + threadIdx.x;
    if (g >= 2 * 128 * 256) return;
    int which = g >> 15;           // 0: W1, 1: W2
    int gg = g & 32767;
    int n = gg >> 8;
    int k = gg & 255;
    int kk = k & 127;
    const float* wr = which ? w2_r : w1_r;
    const float* wi = which ? w2_i : w1_i;
    float v;
    if (n < 64) v = (kk < 64) ? wr[n * 64 + kk] : -wi[n * 64 + kk - 64];
    else { int p = n - 64; v = (kk < 64) ? wi[p * 64 + kk] : wr[p * 64 + kk - 64]; }
    bf16 h = __float2bfloat16(v);
    bf16 out = (k < 128) ? h : __float2bfloat16(v - __bfloat162float(h));
    (which ? W2e : W1e)[gg] = out;
}

// ------------------------------------------------------------- row starts
__global__ __launch_bounds__(256) void row_starts_kernel(const int* __restrict__ rows,
                                                         int T, int* __restrict__ rs) {
    int h = blockIdx.x * 256 + threadIdx.x;
    if (h > Hh) return;
    if (h == Hh) { rs[Hh] = T; return; }
    int lo = 0, hi = T;
    while (lo < hi) {
        int mid = (lo + hi) >> 1;
        if (rows[mid] < h) lo = mid + 1; else hi = mid;
    }
    rs[h] = lo;
}

// --------------------------------------------- pack x chunk -> A_ext (p,q)
__global__ __launch_bounds__(256) void pack_kernel(const float* __restrict__ x,
                                                   bf16* __restrict__ Ap,
                                                   bf16* __restrict__ Aq) {
    int g = blockIdx.x * 256 + threadIdx.x;
    if (g >= CM * KF3) return;
    int wext = g % KF3;
    int row = g / KF3;
    int blk = wext / 384;
    int w = wext - blk * 384;
    float p = 0.f, q = 0.f;
    if (w == 0 || w == 360) {
        p = x[(size_t)row * Ww + w];
    } else if (w < 360) {
        float a = x[(size_t)row * Ww + w];
        float b = x[(size_t)row * Ww + (Ww - w)];
        p = a + b;
        q = a - b;
    }
    bf16 phi = __float2bfloat16(p);
    bf16 qhi = __float2bfloat16(q);
    if (blk == 1) {
        Ap[g] = __float2bfloat16(p - __bfloat162float(phi));
        Aq[g] = __float2bfloat16(q - __bfloat162float(qhi));
    } else {
        Ap[g] = phi;
        Aq[g] = qhi;
    }
}

// ----------------------------------------------------------------- zero fill
__global__ __launch_bounds__(256) void fill_zero_kernel(uint4* __restrict__ p, long n) {
    long i = (long)blockIdx.x * 256 + threadIdx.x;
    long stride = (long)gridDim.x * 256;
    uint4 z = make_uint4(0u, 0u, 0u, 0u);
    for (; i < n; i += stride) p[i] = z;
}

// ------------------------------------------- fwd MFMA GEMM, compact epilogue
// Xc[bc][t] (fp32, stride T128) with t = rs[h]+j for j < cnt(h).
__global__ __launch_bounds__(256) void gemm_fwd_compact_kernel(
    const bf16* __restrict__ A, const bf16* __restrict__ Bt,
    float* __restrict__ Xc, const int* __restrict__ rs, int T128, int mbase)
{
    __shared__ __align__(128) bf16 As[128][64];
    __shared__ __align__(128) bf16 Bs[128][64];
    const int tid = threadIdx.x;
    const int lane = tid & 63;
    const int wave = tid >> 6;
    const int m0 = blockIdx.x * 128;
    const int n0 = blockIdx.y * 128;
    const int wr = (wave >> 1) * 64;
    const int wc = (wave & 1) * 64;
    const int srow = tid >> 3;
    const int scol = (tid & 7) << 3;
    f32x4 acc[4][4] = {};
    for (int k0 = 0; k0 < KF3; k0 += 64) {
#pragma unroll
        for (int i = 0; i < 4; ++i) {
            const bf16* ga = A  + (size_t)(m0 + i * 32 + srow) * KF3 + k0 + scol;
            const bf16* gb = Bt + (size_t)(n0 + i * 32 + srow) * KF3 + k0 + scol;
            gload_lds16(ga, ((char*)&As[0][0]) + (size_t)(i * 256 + tid) * 16);
            gload_lds16(gb, ((char*)&Bs[0][0]) + (size_t)(i * 256 + tid) * 16);
        }
        __syncthreads();
#pragma unroll
        for (int kk = 0; kk < 64; kk += 32) {
            s16x8 a[4], b[4];
#pragma unroll
            for (int m = 0; m < 4; ++m)
                a[m] = *(const s16x8*)&As[wr + m * 16 + (lane & 15)][kk + (lane >> 4) * 8];
#pragma unroll
            for (int n = 0; n < 4; ++n)
                b[n] = *(const s16x8*)&Bs[wc + n * 16 + (lane & 15)][kk + (lane >> 4) * 8];
#pragma unroll
            for (int m = 0; m < 4; ++m)
#pragma unroll
                for (int n = 0; n < 4; ++n)
                    acc[m][n] = __builtin_amdgcn_mfma_f32_16x16x32_bf16(a[m], b[n], acc[m][n], 0, 0, 0);
        }
        __syncthreads();
    }
    const int rbase = (lane >> 4) * 4;
    const int cidx = lane & 15;
#pragma unroll
    for (int m = 0; m < 4; ++m) {
#pragma unroll
        for (int r = 0; r < 4; ++r) {
            int grow = mbase + m0 + wr + m * 16 + rbase + r;
            int bc = grow / Hh;
            int h = grow - bc * Hh;
            int t0 = rs[h];
            int cnt = rs[h + 1] - t0;
#pragma unroll
            for (int n = 0; n < 4; ++n) {
                int j = n0 + wc + n * 16 + cidx;
                if (j < cnt)
                    Xc[(size_t)bc * T128 + t0 + j] = acc[m][n][r];
            }
        }
    }
}

// --------------------------------------------------------------- inv GEMM
__global__ __launch_bounds__(256) void gemm_bt_kernel(
    const bf16* __restrict__ A, const bf16* __restrict__ Bt,
    float* __restrict__ C, int K, int ldc, int nstore)
{
    __shared__ __align__(128) bf16 As[128][64];
    __shared__ __align__(128) bf16 Bs[128][64];
    const int tid = threadIdx.x;
    const int lane = tid & 63;
    const int wave = tid >> 6;
    const int m0 = blockIdx.x * 128;
    const int n0 = blockIdx.y * 128;
    const int wr = (wave >> 1) * 64;
    const int wc = (wave & 1) * 64;
    const int srow = tid >> 3;
    const int scol = (tid & 7) << 3;
    f32x4 acc[4][4] = {};
    for (int k0 = 0; k0 < K; k0 += 64) {
#pragma unroll
        for (int i = 0; i < 4; ++i) {
            const bf16* ga = A  + (size_t)(m0 + i * 32 + srow) * K + k0 + scol;
            const bf16* gb = Bt + (size_t)(n0 + i * 32 + srow) * K + k0 + scol;
            gload_lds16(ga, ((char*)&As[0][0]) + (size_t)(i * 256 + tid) * 16);
            gload_lds16(gb, ((char*)&Bs[0][0]) + (size_t)(i * 256 + tid) * 16);
        }
        __syncthreads();
#pragma unroll
        for (int kk = 0; kk < 64; kk += 32) {
            s16x8 a[4], b[4];
#pragma unroll
            for (int m = 0; m < 4; ++m)
                a[m] = *(const s16x8*)&As[wr + m * 16 + (lane & 15)][kk + (lane >> 4) * 8];
#pragma unroll
            for (int n = 0; n < 4; ++n)
                b[n] = *(const s16x8*)&Bs[wc + n * 16 + (lane & 15)][kk + (lane >> 4) * 8];
#pragma unroll
            for (int m = 0; m < 4; ++m)
#pragma unroll
                for (int n = 0; n < 4; ++n)
                    acc[m][n] = __builtin_amdgcn_mfma_f32_16x16x32_bf16(a[m], b[n], acc[m][n], 0, 0, 0);
        }
        __syncthreads();
    }
    const int rbase = (lane >> 4) * 4;
    const int cidx = lane & 15;
#pragma unroll
    for (int m = 0; m < 4; ++m) {
#pragma unroll
        for (int n = 0; n < 4; ++n) {
            int gcol = n0 + wc + n * 16 + cidx;
            if (gcol < nstore) {
#pragma unroll
                for (int r = 0; r < 4; ++r) {
                    int grow = m0 + wr + m * 16 + rbase + r;
                    C[(size_t)grow * ldc + gcol] = acc[m][n][r];
                }
            }
        }
    }
}

// ------------------------------------------------------- fused middle stage
__device__ __forceinline__ float gelu_exact(float v) {
    return 0.5f * v * (1.0f + erff(v * 0.7071067811865476f));
}

#define R1OFF 0
#define R2OFF 67584
#define METAOFF (2*67584)
#define SMEMSZ (METAOFF + 128*20)

__global__ __launch_bounds__(512, 1) void middle_fused_kernel(
    const float* __restrict__ Xcr, const float* __restrict__ Xci,
    bf16* __restrict__ Xm, bf16* __restrict__ Ainv,
    const float* __restrict__ mean_r, const float* __restrict__ mean_i,
    const float* __restrict__ stdv,
    const float* __restrict__ mags_r, const float* __restrict__ mags_i,
    const float* __restrict__ bias_r, const float* __restrict__ bias_i,
    const bf16* __restrict__ W1e, const bf16* __restrict__ W2e,
    const float* __restrict__ brelu_p,
    const float* __restrict__ glu_mags, const float* __restrict__ glu_phases,
    const int* __restrict__ rows, const int* __restrict__ cols,
    int T, int T128)
{
    __shared__ __align__(16) char smem[SMEMSZ];
    bf16*  H1  = (bf16*)(smem + R1OFF);    // [128][264]
    float* aL  = (float*)(smem + R1OFF);   // [128][132]
    bf16*  W2L = (bf16*)(smem + R1OFF);    // [128][264]
    float* cL  = (float*)(smem + R1OFF);   // [128][132]
    bf16*  W1L = (bf16*)(smem + R2OFF);    // [128][264]
    bf16*  H2  = (bf16*)(smem + R2OFF);    // [128][264]
    int*   rowsL = (int*)(smem + METAOFF);
    int*   colsL = rowsL + 128;
    float* mrL = (float*)(colsL + 128);
    float* miL = mrL + 128;
    float* sdL = miL + 128;

    const int tid = threadIdx.x;
    const int b = blockIdx.y;
    const int t0 = blockIdx.x * 128;
    const int c = tid & 63;
    const int trow = tid >> 6;     // 0..7
    const int lane = tid & 63;
    const int wv = tid >> 6;
    const int wt = (wv >> 1) * 32;
    const int wn = (wv & 1) * 64;

    // ---- phase 0: meta + W1 stage
    if (tid < 128) {
        int t = t0 + tid;
        if (t < T) {
            rowsL[tid] = rows[t]; colsL[tid] = cols[t];
            mrL[tid] = mean_r[t]; miL[tid] = mean_i[t]; sdL[tid] = stdv[t];
        } else {
            rowsL[tid] = 0; colsL[tid] = 0;
            mrL[tid] = 0.f; miL[tid] = 0.f; sdL[tid] = 1.f;
        }
    }
    for (int i = tid; i < 4096; i += 512) {
        int r = i >> 5, gc = (i & 31) << 3;
        *(s16x8*)&W1L[r * 264 + gc] = *(const s16x8*)&W1e[r * 256 + gc];
    }
    __syncthreads();

    // ---- phase 1: gather + h1 (+ Xm store)
    {
        const float magr = mags_r[c], magi = mags_i[c];
        const float bsr = bias_r[c], bsi = bias_i[c];
        const float* xrp = Xcr + (size_t)(b * 64 + c) * T128;
        const float* xip = Xci + (size_t)(b * 64 + c) * T128;
        for (int it = 0; it < 16; ++it) {
            int tl = trow * 16 + it;
            int t = t0 + tl;
            float xr = 0.f, xi = 0.f;
            if (t < T) { xr = xrp[t]; xi = xip[t]; }
            size_t xmb = ((size_t)b * T128 + t) * 128;
            Xm[xmb + c] = __float2bfloat16(xr);
            Xm[xmb + 64 + c] = __float2bfloat16(xi);
            float inv = 1.0f / (1e-12f + sdL[tl]);
            float hr = (xr - mrL[tl]) * inv;
            float hi = (xi - miL[tl]) * inv;
            float h1r = fmaf(hr, magr, fmaf(-hi, magi, bsr));
            float h1i = fmaf(hr, magi, fmaf(hi, magr, bsi));
            bf16 rh = __float2bfloat16(h1r);
            bf16 ih = __float2bfloat16(h1i);
            H1[tl * 264 + c] = rh;
            H1[tl * 264 + 64 + c] = ih;
            H1[tl * 264 + 128 + c] = __float2bfloat16(h1r - __bfloat162float(rh));
            H1[tl * 264 + 192 + c] = __float2bfloat16(h1i - __bfloat162float(ih));
        }
    }
    __syncthreads();

    // ---- phase 2: GEMM1 (A=H1, B=W1L), 3-term split over 6 logical chunks
    constexpr int ASRC[6] = {0, 1, 2, 3, 0, 1};
    constexpr int BSRC[6] = {0, 1, 0, 1, 2, 3};
    f32x4 acc[2][4] = {};
#pragma unroll
    for (int lc = 0; lc < 6; ++lc) {
        const int ka = ASRC[lc] * 64, kb = BSRC[lc] * 64;
#pragma unroll
        for (int kk = 0; kk < 64; kk += 32) {
            s16x8 af[2], bfr[4];
#pragma unroll
            for (int m = 0; m < 2; ++m)
                af[m] = *(const s16x8*)&H1[(wt + m * 16 + (lane & 15)) * 264 + ka + kk + (lane >> 4) * 8];
#pragma unroll
            for (int n = 0; n < 4; ++n)
                bfr[n] = *(const s16x8*)&W1L[(wn + n * 16 + (lane & 15)) * 264 + kb + kk + (lane >> 4) * 8];
#pragma unroll
            for (int m = 0; m < 2; ++m)
#pragma unroll
                for (int n = 0; n < 4; ++n)
                    acc[m][n] = __builtin_amdgcn_mfma_f32_16x16x32_bf16(af[m], bfr[n], acc[m][n], 0, 0, 0);
        }
    }
    __syncthreads();

    // ---- phase 3: a -> LDS (overwrites H1)
#pragma unroll
    for (int m = 0; m < 2; ++m)
#pragma unroll
        for (int n = 0; n < 4; ++n)
#pragma unroll
            for (int r = 0; r < 4; ++r) {
                int row = wt + m * 16 + (lane >> 4) * 4 + r;
                int col = wn + n * 16 + (lane & 15);
                aL[row * 132 + col] = acc[m][n][r];
            }
    __syncthreads();

    // ---- phase 4: gelu -> H2 (overwrites W1L)
    {
        const float brelu = brelu_p[0];
        for (int it = 0; it < 16; ++it) {
            int tl = trow * 16 + it;
            float ar = aL[tl * 132 + c];
            float ai = aL[tl * 132 + 64 + c];
            float r = sqrtf(ar * ar + ai * ai);
            float g = gelu_exact(r + brelu);
            float h2r, h2i;
            if (r > 0.f) { float f = g / r; h2r = f * ar; h2i = f * ai; }
            else { h2r = g; h2i = 0.f; }
            bf16 rh = __float2bfloat16(h2r);
            bf16 ih = __float2bfloat16(h2i);
            H2[tl * 264 + c] = rh;
            H2[tl * 264 + 64 + c] = ih;
            H2[tl * 264 + 128 + c] = __float2bfloat16(h2r - __bfloat162float(rh));
            H2[tl * 264 + 192 + c] = __float2bfloat16(h2i - __bfloat162float(ih));
        }
    }
    __syncthreads();

    // ---- phase 5: W2 stage -> r1 (overwrites aL)
    for (int i = tid; i < 4096; i += 512) {
        int r = i >> 5, gc = (i & 31) << 3;
        *(s16x8*)&W2L[r * 264 + gc] = *(const s16x8*)&W2e[r * 256 + gc];
    }
    __syncthreads();

    // ---- phase 6: GEMM2 (A=H2, B=W2L)
    f32x4 acc2[2][4] = {};
#pragma unroll
    for (int lc = 0; lc < 6; ++lc) {
        const int ka = ASRC[lc] * 64, kb = BSRC[lc] * 64;
#pragma unroll
        for (int kk = 0; kk < 64; kk += 32) {
            s16x8 af[2], bfr[4];
#pragma unroll
            for (int m = 0; m < 2; ++m)
                af[m] = *(const s16x8*)&H2[(wt + m * 16 + (lane & 15)) * 264 + ka + kk + (lane >> 4) * 8];
#pragma unroll
            for (int n = 0; n < 4; ++n)
                bfr[n] = *(const s16x8*)&W2L[(wn + n * 16 + (lane & 15)) * 264 + kb + kk + (lane >> 4) * 8];
#pragma unroll
            for (int m = 0; m < 2; ++m)
#pragma unroll
                for (int n = 0; n < 4; ++n)
                    acc2[m][n] = __builtin_amdgcn_mfma_f32_16x16x32_bf16(af[m], bfr[n], acc2[m][n], 0, 0, 0);
        }
    }
    __syncthreads();

    // ---- phase 7: c -> LDS (overwrites W2L)
#pragma unroll
    for (int m = 0; m < 2; ++m)
#pragma unroll
        for (int n = 0; n < 4; ++n)
#pragma unroll
            for (int r = 0; r < 4; ++r) {
                int row = wt + m * 16 + (lane >> 4) * 4 + r;
                int col = wn + n * 16 + (lane & 15);
                cL[row * 132 + col] = acc2[m][n][r];
            }
    __syncthreads();

    // ---- phase 8: gate + scatter to Ainv
    for (int it = 0; it < 16; ++it) {
        int tl = trow * 16 + it;
        int t = t0 + tl;
        if (t >= T) continue;
        float cr = cL[tl * 132 + c];
        float ci = cL[tl * 132 + 64 + c];
        size_t xmb = ((size_t)b * T128 + t) * 128;
        float xr = __bfloat162float(Xm[xmb + c]);
        float xi = __bfloat162float(Xm[xmb + 64 + c]);
        float r3 = sqrtf(cr * cr + ci * ci);
        float gm = glu_mags[(size_t)c * T + t];
        float gp = glu_phases[(size_t)c * T + t];
        float sg = 1.0f / (1.0f + expf(-(r3 + gm)));
        float ux, uy;
        if (r3 > 0.f) { float ir3 = 1.0f / r3; ux = cr * ir3; uy = ci * ir3; }
        else { ux = 1.f; uy = 0.f; }
        float sp, cp;
        sincosf(gp, &sp, &cp);
        float gx = sg * (ux * cp - uy * sp);
        float gy = sg * (ux * sp + uy * cp);
        int h = rowsL[tl], j = colsL[tl];
        size_t widx = ((size_t)(b * 64 + c) * Hh + h) * KI + j;
        Ainv[widx]       = __float2bfloat16(xr * gx - xi * gy);
        Ainv[widx + 384] = __float2bfloat16(xr * gy + xi * gx);
    }
}

// -------------------------------------------------- depthwise conv + add
__global__ __launch_bounds__(256) void conv_add_kernel(
    const float* __restrict__ y, const float* __restrict__ dw,
    float* __restrict__ out)
{
    int g = blockIdx.x * 256 + threadIdx.x;
    if (g >= Bb * Cc * Hh * Ww) return;
    int w = g % Ww;
    int rem = g / Ww;
    int h = rem % Hh;
    int bc = rem / Hh;
    int c = bc & (Cc - 1);
    const float* yb = y + (size_t)bc * Hh * NI;
    int walt = (w >= Ww / 2) ? (w - Ww / 2) : (w + Ww / 2);
    float acc = yb[h * NI + w];
#pragma unroll
    for (int k = 0; k < 11; ++k) {
        int hp = h + k - 5;
        int hh, ww;
        if (hp < 0)        { hh = -1 - hp;         ww = walt; }
        else if (hp >= Hh) { hh = 2 * Hh - 1 - hp; ww = walt; }
        else               { hh = hp;              ww = w; }
        acc = fmaf(dw[c * 11 + k], yb[hh * NI + ww], acc);
    }
    out[g] = acc;
}

// ------------------------------------------------------------------ launch
extern "C" void kernel_launch(void* const* d_in, const int* in_sizes, int n_in,
                              void* d_out, int out_size, void* d_ws, size_t ws_size,
                              hipStream_t stream)
{
    const float* x      = (const float*)d_in[0];
    const float* mean_r = (const float*)d_in[1];
    const float* mean_i = (const float*)d_in[2];
    const float* stdv   = (const float*)d_in[3];
    const float* mags_r = (const float*)d_in[4];
    const float* mags_i = (const float*)d_in[5];
    const float* bias_r = (const float*)d_in[6];
    const float* bias_i = (const float*)d_in[7];
    const float* w1_r   = (const float*)d_in[8];
    const float* w1_i   = (const float*)d_in[9];
    const float* brelu  = (const float*)d_in[10];
    const float* w2_r   = (const float*)d_in[11];
    const float* w2_i   = (const float*)d_in[12];
    const float* glu_m  = (const float*)d_in[13];
    const float* glu_p  = (const float*)d_in[14];
    const float* dw     = (const float*)d_in[15];
    const int*   rows   = (const int*)d_in[16];
    const int*   cols   = (const int*)d_in[17];
    const int T = in_sizes[16];
    const int T128 = ((T + 127) / 128) * 128;

    char* ws = (char*)d_ws;
    // Layout (~213.7 MB):
    //  [0, 70.8M)          Ainv bf16 [46080][768]  (fwd-phase: Ap,Aq,Bce,Bse alias here)
    //  [70.8M, +42.6M)     Xcr fp32 [128][T128]
    //  next  +42.6M        Xci fp32
    //  next  +42.6M        Xm  bf16 [2][T128][128]
    //  [70.8M, 212.3M)     y fp32 [46080][768]   (aliases Xcr/Xci/Xm after middle)
    //  [212.3M, ...)       Binv, W1ext, W2ext, rs
    const size_t AINV_SZ = (size_t)Mrows * KI * 2;      // 70,778,880
    const size_t XC_SZ   = (size_t)BC * T128 * 4;       // ~42.6 MB
    bf16*  Ainv = (bf16*)ws;
    const size_t SApc = (size_t)CM * KF3 * 2;
    bf16*  Ap   = (bf16*)ws;
    bf16*  Aq   = (bf16*)(ws + SApc);
    bf16*  Bce  = (bf16*)(ws + 2 * SApc);
    bf16*  Bse  = (bf16*)(ws + 2 * SApc + (size_t)NF * KF3 * 2);
    float* Xcr  = (float*)(ws + AINV_SZ);
    float* Xci  = (float*)(ws + AINV_SZ + XC_SZ);
    bf16*  Xm   = (bf16*)(ws + AINV_SZ + 2 * XC_SZ);
    float* y    = (float*)(ws + AINV_SZ);
    size_t boff = AINV_SZ + (size_t)Mrows * NI * 4;     // 212,336,640
    bf16*  Bti  = (bf16*)(ws + boff);
    bf16*  W1e  = (bf16*)(ws + boff + (size_t)NI * KI * 2);
    bf16*  W2e  = (bf16*)(ws + boff + (size_t)NI * KI * 2 + 65536);
    int*   rs   = (int*)(ws + boff + (size_t)NI * KI * 2 + 2 * 65536);

    build_bfwd_kernel<<<(NF * KF3 + 255) / 256, 256, 0, stream>>>(Bce, Bse);
    build_binv_kernel<<<(NI * KI + 255) / 256, 256, 0, stream>>>(Bti);
    build_wext_kernel<<<(2 * 128 * 256 + 255) / 256, 256, 0, stream>>>(
        w1_r, w1_i, w2_r, w2_i, W1e, W2e);
    row_starts_kernel<<<2, 256, 0, stream>>>(rows, T, rs);

    for (int ch = 0; ch < CHUNKS; ++ch) {
        pack_kernel<<<(CM * KF3 + 255) / 256, 256, 0, stream>>>(
            x + (size_t)ch * CM * Ww, Ap, Aq);
        gemm_fwd_compact_kernel<<<dim3(CM / 128, NF / 128), 256, 0, stream>>>(
            Ap, Bce, Xcr, rs, T128, ch * CM);
        gemm_fwd_compact_kernel<<<dim3(CM / 128, NF / 128), 256, 0, stream>>>(
            Aq, Bse, Xci, rs, T128, ch * CM);
    }

    fill_zero_kernel<<<2048, 256, 0, stream>>>((uint4*)Ainv, (long)(AINV_SZ / 16));

    const int nT128 = (T + 127) / 128;
    middle_fused_kernel<<<dim3(nT128, Bb), 512, 0, stream>>>(
        Xcr, Xci, Xm, Ainv, mean_r, mean_i, stdv, mags_r, mags_i,
        bias_r, bias_i, W1e, W2e, brelu, glu_m, glu_p, rows, cols, T, T128);

    gemm_bt_kernel<<<dim3(Mrows / 128, NI / 128), 256, 0, stream>>>(
        Ainv, Bti, y, KI, NI, NSTORE_INV);

    conv_add_kernel<<<(Bb * Cc * Hh * Ww + 255) / 256, 256, 0, stream>>>(y, dw, (float*)d_out);
}

// Round 5
// 895.900 us; speedup vs baseline: 1.2555x; 1.2555x over previous
//
#include <hip/hip_runtime.h>
#include <hip/hip_bf16.h>
#include <math.h>

#define Hh 360
#define Ww 720
#define Cc 64
#define Bb 2
#define BC (Bb*Cc)        // 128
#define Mrows (BC*Hh)     // 46080
#define CHUNKS 4
#define CM (Mrows/CHUNKS) // 11520
#define KF3 1152          // fwd K: [hi|lo|hi] blocks of 384
#define NF 384            // fwd N (361 bins padded)
#define KI 768            // inv K: [Re(384) | Im(384)]
#define NI 768            // inv N alloc (720 used)
#define NSTORE_INV 720
#define SCALE 0.037267799624996496f   // 1/sqrt(720)
#define TWO_PI 6.2831853071795864769f

typedef __attribute__((ext_vector_type(8))) short s16x8;
typedef __attribute__((ext_vector_type(4))) float f32x4;
typedef __hip_bfloat16 bf16;

__device__ __forceinline__ void gload_lds16(const void* g, void* l) {
    __builtin_amdgcn_global_load_lds(
        (const __attribute__((address_space(1))) unsigned int*)g,
        (__attribute__((address_space(3))) unsigned int*)l, 16, 0, 0);
}

// ---------------------------------------------------------- B-matrix builds
__global__ __launch_bounds__(256) void build_bfwd_kernel(bf16* __restrict__ Bc,
                                                         bf16* __restrict__ Bs) {
    int g = blockIdx.x * 256 + threadIdx.x;
    if (g >= NF * KF3) return;
    int wext = g % KF3;
    int j = g / KF3;
    int blk = wext / 384;
    int w = wext - blk * 384;
    float c = 0.f, s = 0.f;
    if (w <= 360 && j <= 360) {
        int idx = (j * w) % Ww;
        float a = (TWO_PI / Ww) * (float)idx;
        float sv, cv;
        sincosf(a, &sv, &cv);
        c = SCALE * cv;
        s = -SCALE * sv;
    }
    bf16 chi = __float2bfloat16(c);
    bf16 shi = __float2bfloat16(s);
    if (blk == 2) {
        Bc[g] = __float2bfloat16(c - __bfloat162float(chi));
        Bs[g] = __float2bfloat16(s - __bfloat162float(shi));
    } else {
        Bc[g] = chi;
        Bs[g] = shi;
    }
}

__global__ __launch_bounds__(256) void build_binv_kernel(bf16* __restrict__ Bi) {
    int g = blockIdx.x * 256 + threadIdx.x;
    if (g >= NI * KI) return;
    int k = g % KI, n = g / KI;
    float v = 0.f;
    if (n < NSTORE_INV) {
        if (k <= 360) {
            int j = k;
            float f = (j == 0 || j == 360) ? 1.f : 2.f;
            int idx = (j * n) % Ww;
            v = SCALE * f * cosf((TWO_PI / Ww) * (float)idx);
        } else if (k >= 384 && k <= 744) {
            int j = k - 384;
            int idx = (j * n) % Ww;
            v = -2.f * SCALE * sinf((TWO_PI / Ww) * (float)idx);
        }
    }
    Bi[g] = __float2bfloat16(v);
}

// W1ext/W2ext: [128 n][256 k] bf16. k<128: hi of M(n,k); k>=128: lo of M(n,k-128).
__global__ __launch_bounds__(256) void build_wext_kernel(
    const float* __restrict__ w1_r, const float* __restrict__ w1_i,
    const float* __restrict__ w2_r, const float* __restrict__ w2_i,
    bf16* __restrict__ W1e, bf16* __restrict__ W2e)
{
    int g = blockIdx.x * 256 + threadIdx.x;
    if (g >= 2 * 128 * 256) return;
    int which = g >> 15;           // 0: W1, 1: W2
    int gg = g & 32767;
    int n = gg >> 8;
    int k = gg & 255;
    int kk = k & 127;
    const float* wr = which ? w2_r : w1_r;
    const float* wi = which ? w2_i : w1_i;
    float v;
    if (n < 64) v = (kk < 64) ? wr[n * 64 + kk] : -wi[n * 64 + kk - 64];
    else { int p = n - 64; v = (kk < 64) ? wi[p * 64 + kk] : wr[p * 64 + kk - 64]; }
    bf16 h = __float2bfloat16(v);
    bf16 out = (k < 128) ? h : __float2bfloat16(v - __bfloat162float(h));
    (which ? W2e : W1e)[gg] = out;
}

// ---------------------------------------- row starts (compact + 8-padded)
__global__ __launch_bounds__(512) void row_starts_kernel(const int* __restrict__ rows,
                                                         int T, int* __restrict__ rs,
                                                         int* __restrict__ rs8) {
    int h = threadIdx.x;
    if (h <= Hh) {
        if (h == Hh) rs[Hh] = T;
        else {
            int lo = 0, hi = T;
            while (lo < hi) {
                int mid = (lo + hi) >> 1;
                if (rows[mid] < h) lo = mid + 1; else hi = mid;
            }
            rs[h] = lo;
        }
    }
    __syncthreads();
    if (threadIdx.x == 0) {
        int acc = 0;
        for (int i = 0; i < Hh; ++i) {
            rs8[i] = acc;
            int cnt = rs[i + 1] - rs[i];
            acc += (cnt + 7) & ~7;
        }
        rs8[Hh] = acc;
    }
}

// --------------------------------------------- pack x chunk -> A_ext (p,q)
__global__ __launch_bounds__(256) void pack_kernel(const float* __restrict__ x,
                                                   bf16* __restrict__ Ap,
                                                   bf16* __restrict__ Aq) {
    int g = blockIdx.x * 256 + threadIdx.x;
    if (g >= CM * KF3) return;
    int wext = g % KF3;
    int row = g / KF3;
    int blk = wext / 384;
    int w = wext - blk * 384;
    float p = 0.f, q = 0.f;
    if (w == 0 || w == 360) {
        p = x[(size_t)row * Ww + w];
    } else if (w < 360) {
        float a = x[(size_t)row * Ww + w];
        float b = x[(size_t)row * Ww + (Ww - w)];
        p = a + b;
        q = a - b;
    }
    bf16 phi = __float2bfloat16(p);
    bf16 qhi = __float2bfloat16(q);
    if (blk == 1) {
        Ap[g] = __float2bfloat16(p - __bfloat162float(phi));
        Aq[g] = __float2bfloat16(q - __bfloat162float(qhi));
    } else {
        Ap[g] = phi;
        Aq[g] = qhi;
    }
}

// ----------------------------------------------------------------- zero fill
__global__ __launch_bounds__(256) void fill_zero_kernel(uint4* __restrict__ p, long n) {
    long i = (long)blockIdx.x * 256 + threadIdx.x;
    long stride = (long)gridDim.x * 256;
    uint4 z = make_uint4(0u, 0u, 0u, 0u);
    for (; i < n; i += stride) p[i] = z;
}

// ------------------------------------------- fwd MFMA GEMM, compact epilogue
__global__ __launch_bounds__(256) void gemm_fwd_compact_kernel(
    const bf16* __restrict__ A, const bf16* __restrict__ Bt,
    float* __restrict__ Xc, const int* __restrict__ rs, int T128, int mbase)
{
    __shared__ __align__(128) bf16 As[128][64];
    __shared__ __align__(128) bf16 Bs[128][64];
    const int tid = threadIdx.x;
    const int lane = tid & 63;
    const int wave = tid >> 6;
    const int m0 = blockIdx.x * 128;
    const int n0 = blockIdx.y * 128;
    const int wr = (wave >> 1) * 64;
    const int wc = (wave & 1) * 64;
    const int srow = tid >> 3;
    const int scol = (tid & 7) << 3;
    f32x4 acc[4][4] = {};
    for (int k0 = 0; k0 < KF3; k0 += 64) {
#pragma unroll
        for (int i = 0; i < 4; ++i) {
            const bf16* ga = A  + (size_t)(m0 + i * 32 + srow) * KF3 + k0 + scol;
            const bf16* gb = Bt + (size_t)(n0 + i * 32 + srow) * KF3 + k0 + scol;
            gload_lds16(ga, ((char*)&As[0][0]) + (size_t)(i * 256 + tid) * 16);
            gload_lds16(gb, ((char*)&Bs[0][0]) + (size_t)(i * 256 + tid) * 16);
        }
        __syncthreads();
#pragma unroll
        for (int kk = 0; kk < 64; kk += 32) {
            s16x8 a[4], b[4];
#pragma unroll
            for (int m = 0; m < 4; ++m)
                a[m] = *(const s16x8*)&As[wr + m * 16 + (lane & 15)][kk + (lane >> 4) * 8];
#pragma unroll
            for (int n = 0; n < 4; ++n)
                b[n] = *(const s16x8*)&Bs[wc + n * 16 + (lane & 15)][kk + (lane >> 4) * 8];
#pragma unroll
            for (int m = 0; m < 4; ++m)
#pragma unroll
                for (int n = 0; n < 4; ++n)
                    acc[m][n] = __builtin_amdgcn_mfma_f32_16x16x32_bf16(a[m], b[n], acc[m][n], 0, 0, 0);
        }
        __syncthreads();
    }
    const int rbase = (lane >> 4) * 4;
    const int cidx = lane & 15;
#pragma unroll
    for (int m = 0; m < 4; ++m) {
#pragma unroll
        for (int r = 0; r < 4; ++r) {
            int grow = mbase + m0 + wr + m * 16 + rbase + r;
            int bc = grow / Hh;
            int h = grow - bc * Hh;
            int t0 = rs[h];
            int cnt = rs[h + 1] - t0;
#pragma unroll
            for (int n = 0; n < 4; ++n) {
                int j = n0 + wc + n * 16 + cidx;
                if (j < cnt)
                    Xc[(size_t)bc * T128 + t0 + j] = acc[m][n][r];
            }
        }
    }
}

// --------------------------------- inverse GEMM from compact gated spectrum
__global__ __launch_bounds__(256) void gemm_inv_kernel(
    const bf16* __restrict__ Xgr, const bf16* __restrict__ Xgi,
    const bf16* __restrict__ Bt, const int* __restrict__ rs8,
    float* __restrict__ C, int T8cap)
{
    __shared__ __align__(128) bf16 As[128][64];
    __shared__ __align__(128) bf16 Bs[128][64];
    __shared__ int rsL[Hh + 1];
    const int tid = threadIdx.x;
    for (int i = tid; i <= Hh; i += 256) rsL[i] = rs8[i];
    const int lane = tid & 63;
    const int wave = tid >> 6;
    const int m0 = blockIdx.x * 128;
    const int n0 = blockIdx.y * 128;
    const int wr = (wave >> 1) * 64;
    const int wc = (wave & 1) * 64;
    const int srow = tid >> 3;
    const int scol = (tid & 7) << 3;
    __syncthreads();
    f32x4 acc[4][4] = {};
    for (int k0 = 0; k0 < KI; k0 += 64) {
#pragma unroll
        for (int i = 0; i < 4; ++i)
            gload_lds16(Bt + (size_t)(n0 + i * 32 + srow) * KI + k0 + scol,
                        ((char*)&Bs[0][0]) + (size_t)(i * 256 + tid) * 16);
        {
            int k = k0 + scol;
            int j0 = (k < 384) ? k : k - 384;
            const bf16* base = (k < 384) ? Xgr : Xgi;
#pragma unroll
            for (int i = 0; i < 4; ++i) {
                int grow = m0 + i * 32 + srow;
                int bc = grow / Hh;
                int h = grow - bc * Hh;
                int t0v = rsL[h];
                int cnt8 = rsL[h + 1] - t0v;
                s16x8 v = (s16x8){0, 0, 0, 0, 0, 0, 0, 0};
                if (j0 < cnt8)
                    v = *(const s16x8*)(base + (size_t)bc * T8cap + t0v + j0);
                *(s16x8*)&As[i * 32 + srow][scol] = v;
            }
        }
        __syncthreads();
#pragma unroll
        for (int kk = 0; kk < 64; kk += 32) {
            s16x8 a[4], b[4];
#pragma unroll
            for (int m = 0; m < 4; ++m)
                a[m] = *(const s16x8*)&As[wr + m * 16 + (lane & 15)][kk + (lane >> 4) * 8];
#pragma unroll
            for (int n = 0; n < 4; ++n)
                b[n] = *(const s16x8*)&Bs[wc + n * 16 + (lane & 15)][kk + (lane >> 4) * 8];
#pragma unroll
            for (int m = 0; m < 4; ++m)
#pragma unroll
                for (int n = 0; n < 4; ++n)
                    acc[m][n] = __builtin_amdgcn_mfma_f32_16x16x32_bf16(a[m], b[n], acc[m][n], 0, 0, 0);
        }
        __syncthreads();
    }
    const int rbase = (lane >> 4) * 4;
    const int cidx = lane & 15;
#pragma unroll
    for (int m = 0; m < 4; ++m) {
#pragma unroll
        for (int n = 0; n < 4; ++n) {
            int gcol = n0 + wc + n * 16 + cidx;
            if (gcol < NSTORE_INV) {
#pragma unroll
                for (int r = 0; r < 4; ++r) {
                    int grow = m0 + wr + m * 16 + rbase + r;
                    C[(size_t)grow * NI + gcol] = acc[m][n][r];
                }
            }
        }
    }
}

// ------------------------------------------------------- fused middle stage
__device__ __forceinline__ float gelu_exact(float v) {
    return 0.5f * v * (1.0f + erff(v * 0.7071067811865476f));
}

__global__ __launch_bounds__(256, 2) void middle_fused_kernel(
    const float* __restrict__ Xcr, const float* __restrict__ Xci,
    bf16* __restrict__ Xgr, bf16* __restrict__ Xgi,
    const float* __restrict__ mean_r, const float* __restrict__ mean_i,
    const float* __restrict__ stdv,
    const float* __restrict__ mags_r, const float* __restrict__ mags_i,
    const float* __restrict__ bias_r, const float* __restrict__ bias_i,
    const bf16* __restrict__ W1e, const bf16* __restrict__ W2e,
    const float* __restrict__ brelu_p,
    const float* __restrict__ glu_mags, const float* __restrict__ glu_phases,
    const int* __restrict__ rows, const int* __restrict__ cols,
    const int* __restrict__ rs8,
    int T, int T128, int T8cap)
{
    __shared__ __align__(16) char smemA[64 * 264 * 2];   // 33,792 B
    __shared__ __align__(16) char smemB[64 * 264 * 2];
    bf16*  H1  = (bf16*)smemA;    // [64][264] hi/lo split input
    float* aL  = (float*)smemA;   // [64][132] GEMM1 result
    bf16*  WLb = (bf16*)smemA;    // W2 half tiles (GEMM2 B)
    bf16*  WLa = (bf16*)smemB;    // W1 half tiles (GEMM1 B)
    bf16*  H2  = (bf16*)smemB;    // [64][264] gelu output
    float* cL  = (float*)smemB;   // [64][132] GEMM2 result

    const int tid = threadIdx.x;
    const int b = blockIdx.y;
    const int t0 = blockIdx.x * 64;
    const int tl = tid & 63;
    const int cg = tid >> 6;           // 0..3
    const int t = t0 + tl;
    const bool valid = (t < T);
    const int lane = tid & 63;
    const int wv = tid >> 6;

    // ---- phase 1: normalize -> H1 (transposed mapping, coalesced reads)
    float mr = 0.f, mi = 0.f, isd = 0.f;
    if (valid) { mr = mean_r[t]; mi = mean_i[t]; isd = 1.0f / (1e-12f + stdv[t]); }
    for (int ci = 0; ci < 16; ++ci) {
        int c = cg * 16 + ci;
        float xr = 0.f, xi = 0.f;
        if (valid) {
            xr = Xcr[(size_t)(b * 64 + c) * T128 + t];
            xi = Xci[(size_t)(b * 64 + c) * T128 + t];
        }
        float hr = (xr - mr) * isd;
        float hi = (xi - mi) * isd;
        float h1r = fmaf(hr, mags_r[c], fmaf(-hi, mags_i[c], bias_r[c]));
        float h1i = fmaf(hr, mags_i[c], fmaf(hi, mags_r[c], bias_i[c]));
        bf16 rh = __float2bfloat16(h1r), ih = __float2bfloat16(h1i);
        H1[tl * 264 + c]       = rh;
        H1[tl * 264 + 64 + c]  = ih;
        H1[tl * 264 + 128 + c] = __float2bfloat16(h1r - __bfloat162float(rh));
        H1[tl * 264 + 192 + c] = __float2bfloat16(h1i - __bfloat162float(ih));
    }

    constexpr int ASRC[6] = {0, 1, 2, 3, 0, 1};
    constexpr int BSRC[6] = {0, 1, 0, 1, 2, 3};
    const int frow = (lane & 15);
    const int fcol = (lane >> 4) * 8;

    // ---- GEMM1: acc[half][n], A = H1 (R1), B = W1 halves staged in R2
    f32x4 acc[2][4] = {};
    for (int half = 0; half < 2; ++half) {
        if (half) __syncthreads();
        for (int i = tid; i < 2048; i += 256) {
            int r = i >> 5, gc = (i & 31) << 3;
            *(s16x8*)&WLa[r * 264 + gc] = *(const s16x8*)&W1e[(half * 64 + r) * 256 + gc];
        }
        __syncthreads();
#pragma unroll
        for (int lc = 0; lc < 6; ++lc) {
            const int ka = ASRC[lc] * 64, kb = BSRC[lc] * 64;
#pragma unroll
            for (int kk = 0; kk < 64; kk += 32) {
                s16x8 af = *(const s16x8*)&H1[(wv * 16 + frow) * 264 + ka + kk + fcol];
#pragma unroll
                for (int n = 0; n < 4; ++n) {
                    s16x8 bf = *(const s16x8*)&WLa[(n * 16 + frow) * 264 + kb + kk + fcol];
                    acc[half][n] = __builtin_amdgcn_mfma_f32_16x16x32_bf16(af, bf, acc[half][n], 0, 0, 0);
                }
            }
        }
    }
    __syncthreads();

    // ---- phase 3: acc -> aL (overwrites H1)
    const int rbase = (lane >> 4) * 4;
    const int cidx = lane & 15;
#pragma unroll
    for (int half = 0; half < 2; ++half)
#pragma unroll
        for (int n = 0; n < 4; ++n)
#pragma unroll
            for (int r = 0; r < 4; ++r)
                aL[(wv * 16 + rbase + r) * 132 + half * 64 + n * 16 + cidx] = acc[half][n][r];
    __syncthreads();

    // ---- phase 4: gelu (transposed) -> H2 (overwrites WLa region)
    {
        const float brelu = brelu_p[0];
        for (int ci = 0; ci < 16; ++ci) {
            int c = cg * 16 + ci;
            float ar = aL[tl * 132 + c];
            float ai = aL[tl * 132 + 64 + c];
            float r = sqrtf(ar * ar + ai * ai);
            float g = gelu_exact(r + brelu);
            float h2r, h2i;
            if (r > 0.f) { float f = g / r; h2r = f * ar; h2i = f * ai; }
            else { h2r = g; h2i = 0.f; }
            bf16 rh = __float2bfloat16(h2r), ih = __float2bfloat16(h2i);
            H2[tl * 264 + c]       = rh;
            H2[tl * 264 + 64 + c]  = ih;
            H2[tl * 264 + 128 + c] = __float2bfloat16(h2r - __bfloat162float(rh));
            H2[tl * 264 + 192 + c] = __float2bfloat16(h2i - __bfloat162float(ih));
        }
    }

    // ---- GEMM2: acc2[half][n], A = H2 (R2), B = W2 halves staged in R1
    f32x4 acc2[2][4] = {};
    for (int half = 0; half < 2; ++half) {
        __syncthreads();   // half0: aL reads done; half1: prev MFMAs done
        for (int i = tid; i < 2048; i += 256) {
            int r = i >> 5, gc = (i & 31) << 3;
            *(s16x8*)&WLb[r * 264 + gc] = *(const s16x8*)&W2e[(half * 64 + r) * 256 + gc];
        }
        __syncthreads();
#pragma unroll
        for (int lc = 0; lc < 6; ++lc) {
            const int ka = ASRC[lc] * 64, kb = BSRC[lc] * 64;
#pragma unroll
            for (int kk = 0; kk < 64; kk += 32) {
                s16x8 af = *(const s16x8*)&H2[(wv * 16 + frow) * 264 + ka + kk + fcol];
#pragma unroll
                for (int n = 0; n < 4; ++n) {
                    s16x8 bf = *(const s16x8*)&WLb[(n * 16 + frow) * 264 + kb + kk + fcol];
                    acc2[half][n] = __builtin_amdgcn_mfma_f32_16x16x32_bf16(af, bf, acc2[half][n], 0, 0, 0);
                }
            }
        }
    }
    __syncthreads();

    // ---- phase 7: acc2 -> cL (overwrites H2)
#pragma unroll
    for (int half = 0; half < 2; ++half)
#pragma unroll
        for (int n = 0; n < 4; ++n)
#pragma unroll
            for (int r = 0; r < 4; ++r)
                cL[(wv * 16 + rbase + r) * 132 + half * 64 + n * 16 + cidx] = acc2[half][n][r];
    __syncthreads();

    // ---- phase 8: gate + compact coalesced store
    if (valid) {
        int h = rows[t], j = cols[t];
        size_t wbase = (size_t)rs8[h] + j;
        for (int ci = 0; ci < 16; ++ci) {
            int c = cg * 16 + ci;
            float cr  = cL[tl * 132 + c];
            float cii = cL[tl * 132 + 64 + c];
            float xr = Xcr[(size_t)(b * 64 + c) * T128 + t];
            float xi = Xci[(size_t)(b * 64 + c) * T128 + t];
            float r3 = sqrtf(cr * cr + cii * cii);
            float gm = glu_mags[(size_t)c * T + t];
            float gp = glu_phases[(size_t)c * T + t];
            float sg = 1.0f / (1.0f + expf(-(r3 + gm)));
            float ux, uy;
            if (r3 > 0.f) { float ir3 = 1.0f / r3; ux = cr * ir3; uy = cii * ir3; }
            else { ux = 1.f; uy = 0.f; }
            float sp, cp;
            sincosf(gp, &sp, &cp);
            float gx = sg * (ux * cp - uy * sp);
            float gy = sg * (ux * sp + uy * cp);
            size_t base = (size_t)(b * 64 + c) * T8cap + wbase;
            Xgr[base] = __float2bfloat16(xr * gx - xi * gy);
            Xgi[base] = __float2bfloat16(xr * gy + xi * gx);
        }
    }
}

// -------------------------------------------------- depthwise conv + add
__global__ __launch_bounds__(256) void conv_add_kernel(
    const float* __restrict__ y, const float* __restrict__ dw,
    float* __restrict__ out)
{
    int g = blockIdx.x * 256 + threadIdx.x;
    if (g >= Bb * Cc * Hh * Ww) return;
    int w = g % Ww;
    int rem = g / Ww;
    int h = rem % Hh;
    int bc = rem / Hh;
    int c = bc & (Cc - 1);
    const float* yb = y + (size_t)bc * Hh * NI;
    int walt = (w >= Ww / 2) ? (w - Ww / 2) : (w + Ww / 2);
    float acc = yb[h * NI + w];
#pragma unroll
    for (int k = 0; k < 11; ++k) {
        int hp = h + k - 5;
        int hh, ww;
        if (hp < 0)        { hh = -1 - hp;         ww = walt; }
        else if (hp >= Hh) { hh = 2 * Hh - 1 - hp; ww = walt; }
        else               { hh = hp;              ww = w; }
        acc = fmaf(dw[c * 11 + k], yb[hh * NI + ww], acc);
    }
    out[g] = acc;
}

// ------------------------------------------------------------------ launch
extern "C" void kernel_launch(void* const* d_in, const int* in_sizes, int n_in,
                              void* d_out, int out_size, void* d_ws, size_t ws_size,
                              hipStream_t stream)
{
    const float* x      = (const float*)d_in[0];
    const float* mean_r = (const float*)d_in[1];
    const float* mean_i = (const float*)d_in[2];
    const float* stdv   = (const float*)d_in[3];
    const float* mags_r = (const float*)d_in[4];
    const float* mags_i = (const float*)d_in[5];
    const float* bias_r = (const float*)d_in[6];
    const float* bias_i = (const float*)d_in[7];
    const float* w1_r   = (const float*)d_in[8];
    const float* w1_i   = (const float*)d_in[9];
    const float* brelu  = (const float*)d_in[10];
    const float* w2_r   = (const float*)d_in[11];
    const float* w2_i   = (const float*)d_in[12];
    const float* glu_m  = (const float*)d_in[13];
    const float* glu_p  = (const float*)d_in[14];
    const float* dw     = (const float*)d_in[15];
    const int*   rows   = (const int*)d_in[16];
    const int*   cols   = (const int*)d_in[17];
    const int T = in_sizes[16];
    const int T128 = ((T + 127) / 128) * 128;
    const int T8cap = ((T + 7 * Hh) + 127) & ~127;

    char* ws = (char*)d_ws;
    const size_t SApc  = (size_t)CM * KF3 * 2;          // 26,542,080
    const size_t XC_SZ = (size_t)BC * T128 * 4;
    const size_t XG_SZ = (size_t)BC * T8cap * 2;
    const size_t Y_SZ  = (size_t)Mrows * NI * 4;        // 141,557,760
    // [0 .. max(Y, ApAq+Xc)) : fwd-phase Ap,Aq,Xcr,Xci -> later y (all dead by then)
    bf16*  Ap   = (bf16*)ws;
    bf16*  Aq   = (bf16*)(ws + SApc);
    float* Xcr  = (float*)(ws + 2 * SApc);
    float* Xci  = (float*)(ws + 2 * SApc + XC_SZ);
    float* y    = (float*)ws;
    size_t xc_end = 2 * SApc + 2 * XC_SZ;
    size_t xgoff  = (((Y_SZ > xc_end) ? Y_SZ : xc_end) + 255) & ~(size_t)255;
    bf16*  Xgr  = (bf16*)(ws + xgoff);
    bf16*  Xgi  = (bf16*)(ws + xgoff + XG_SZ);
    size_t boff = xgoff + 2 * XG_SZ;
    bf16*  Bce  = (bf16*)(ws + boff);
    bf16*  Bse  = (bf16*)(ws + boff + (size_t)NF * KF3 * 2);
    bf16*  Bti  = (bf16*)(ws + boff + 2 * (size_t)NF * KF3 * 2);
    bf16*  W1e  = (bf16*)(ws + boff + 2 * (size_t)NF * KF3 * 2 + (size_t)NI * KI * 2);
    bf16*  W2e  = W1e + 128 * 256;
    int*   rs   = (int*)(W2e + 128 * 256);
    int*   rs8  = rs + (Hh + 2);

    build_bfwd_kernel<<<(NF * KF3 + 255) / 256, 256, 0, stream>>>(Bce, Bse);
    build_binv_kernel<<<(NI * KI + 255) / 256, 256, 0, stream>>>(Bti);
    build_wext_kernel<<<(2 * 128 * 256 + 255) / 256, 256, 0, stream>>>(
        w1_r, w1_i, w2_r, w2_i, W1e, W2e);
    row_starts_kernel<<<1, 512, 0, stream>>>(rows, T, rs, rs8);

    for (int ch = 0; ch < CHUNKS; ++ch) {
        pack_kernel<<<(CM * KF3 + 255) / 256, 256, 0, stream>>>(
            x + (size_t)ch * CM * Ww, Ap, Aq);
        gemm_fwd_compact_kernel<<<dim3(CM / 128, NF / 128), 256, 0, stream>>>(
            Ap, Bce, Xcr, rs, T128, ch * CM);
        gemm_fwd_compact_kernel<<<dim3(CM / 128, NF / 128), 256, 0, stream>>>(
            Aq, Bse, Xci, rs, T128, ch * CM);
    }

    fill_zero_kernel<<<2048, 256, 0, stream>>>((uint4*)Xgr, (long)(2 * XG_SZ / 16));

    const int nT64 = (T + 63) / 64;
    middle_fused_kernel<<<dim3(nT64, Bb), 256, 0, stream>>>(
        Xcr, Xci, Xgr, Xgi, mean_r, mean_i, stdv, mags_r, mags_i,
        bias_r, bias_i, W1e, W2e, brelu, glu_m, glu_p, rows, cols, rs8,
        T, T128, T8cap);

    gemm_inv_kernel<<<dim3(Mrows / 128, NI / 128), 256, 0, stream>>>(
        Xgr, Xgi, Bti, rs8, y, T8cap);

    conv_add_kernel<<<(Bb * Cc * Hh * Ww + 255) / 256, 256, 0, stream>>>(y, dw, (float*)d_out);
}

// Round 8
// 860.498 us; speedup vs baseline: 1.3072x; 1.0411x over previous
//
#include <hip/hip_runtime.h>
#include <hip/hip_bf16.h>
#include <math.h>

#define Hh 360
#define Ww 720
#define Cc 64
#define Bb 2
#define BC (Bb*Cc)        // 128
#define Mrows (BC*Hh)     // 46080
#define CHUNKS 4
#define CM (Mrows/CHUNKS) // 11520
#define KF3 1152          // fwd K: [hi|lo|hi] blocks of 384
#define NF 384            // fwd N (361 bins padded)
#define KI 768            // inv K: [Re(384) | Im(384)]
#define NI 768            // inv C row stride (720 used)
#define NSTORE_INV 720
#define SCALE 0.037267799624996496f   // 1/sqrt(720)
#define TWO_PI 6.2831853071795864769f

typedef __attribute__((ext_vector_type(8))) short s16x8;
typedef __attribute__((ext_vector_type(4))) float f32x4;
typedef __hip_bfloat16 bf16;

__device__ __forceinline__ void gload_lds16(const void* g, void* l) {
    __builtin_amdgcn_global_load_lds(
        (const __attribute__((address_space(1))) unsigned int*)g,
        (__attribute__((address_space(3))) unsigned int*)l, 16, 0, 0);
}

// ---------------------------------------------------------- B-matrix builds
// Fwd, K-extended: col blocks [0:384)=hi, [384:768)=hi, [768:1152)=lo of
// Bc[j][w] = SCALE*cos(2pi jw/720), Bs[j][w] = -SCALE*sin(2pi jw/720).
__global__ __launch_bounds__(256) void build_bfwd_kernel(bf16* __restrict__ Bc,
                                                         bf16* __restrict__ Bs) {
    int g = blockIdx.x * 256 + threadIdx.x;
    if (g >= NF * KF3) return;
    int wext = g % KF3;
    int j = g / KF3;
    int blk = wext / 384;
    int w = wext - blk * 384;
    float c = 0.f, s = 0.f;
    if (w <= 360 && j <= 360) {
        int idx = (j * w) % Ww;
        float a = (TWO_PI / Ww) * (float)idx;
        float sv, cv;
        sincosf(a, &sv, &cv);
        c = SCALE * cv;
        s = -SCALE * sv;
    }
    bf16 chi = __float2bfloat16(c);
    bf16 shi = __float2bfloat16(s);
    if (blk == 2) {
        Bc[g] = __float2bfloat16(c - __bfloat162float(chi));
        Bs[g] = __float2bfloat16(s - __bfloat162float(shi));
    } else {
        Bc[g] = chi;
        Bs[g] = shi;
    }
}

__global__ __launch_bounds__(256) void build_binv_kernel(bf16* __restrict__ Bi) {
    int g = blockIdx.x * 256 + threadIdx.x;
    if (g >= NI * KI) return;
    int k = g % KI, n = g / KI;
    float v = 0.f;
    if (n < NSTORE_INV) {
        if (k <= 360) {
            int j = k;
            float f = (j == 0 || j == 360) ? 1.f : 2.f;
            int idx = (j * n) % Ww;
            v = SCALE * f * cosf((TWO_PI / Ww) * (float)idx);
        } else if (k >= 384 && k <= 744) {
            int j = k - 384;
            int idx = (j * n) % Ww;
            v = -2.f * SCALE * sinf((TWO_PI / Ww) * (float)idx);
        }
    }
    Bi[g] = __float2bfloat16(v);
}

// W1ext/W2ext: [128 n][256 k] bf16. k<128: hi of M(n,k); k>=128: lo of M(n,k-128).
__global__ __launch_bounds__(256) void build_wext_kernel(
    const float* __restrict__ w1_r, const float* __restrict__ w1_i,
    const float* __restrict__ w2_r, const float* __restrict__ w2_i,
    bf16* __restrict__ W1e, bf16* __restrict__ W2e)
{
    int g = blockIdx.x * 256 + threadIdx.x;
    if (g >= 2 * 128 * 256) return;
    int which = g >> 15;           // 0: W1, 1: W2
    int gg = g & 32767;
    int n = gg >> 8;
    int k = gg & 255;
    int kk = k & 127;
    const float* wr = which ? w2_r : w1_r;
    const float* wi = which ? w2_i : w1_i;
    float v;
    if (n < 64) v = (kk < 64) ? wr[n * 64 + kk] : -wi[n * 64 + kk - 64];
    else { int p = n - 64; v = (kk < 64) ? wi[p * 64 + kk] : wr[p * 64 + kk - 64]; }
    bf16 h = __float2bfloat16(v);
    bf16 out = (k < 128) ? h : __float2bfloat16(v - __bfloat162float(h));
    (which ? W2e : W1e)[gg] = out;
}

// ---------------------------------------- row starts (compact + 8-padded)
__global__ __launch_bounds__(512) void row_starts_kernel(const int* __restrict__ rows,
                                                         int T, int* __restrict__ rs,
                                                         int* __restrict__ rs8) {
    int h = threadIdx.x;
    if (h <= Hh) {
        if (h == Hh) rs[Hh] = T;
        else {
            int lo = 0, hi = T;
            while (lo < hi) {
                int mid = (lo + hi) >> 1;
                if (rows[mid] < h) lo = mid + 1; else hi = mid;
            }
            rs[h] = lo;
        }
    }
    __syncthreads();
    if (threadIdx.x == 0) {
        int acc = 0;
        for (int i = 0; i < Hh; ++i) {
            rs8[i] = acc;
            int cnt = rs[i + 1] - rs[i];
            acc += (cnt + 7) & ~7;
        }
        rs8[Hh] = acc;
    }
}

// --------------------------------------------- pack x chunk -> A_ext (p,q)
// A row layout: [0:384)=hi, [384:768)=lo, [768:1152)=hi.
__global__ __launch_bounds__(256) void pack_kernel(const float* __restrict__ x,
                                                   bf16* __restrict__ Ap,
                                                   bf16* __restrict__ Aq) {
    int g = blockIdx.x * 256 + threadIdx.x;
    if (g >= CM * KF3) return;
    int wext = g % KF3;
    int row = g / KF3;
    int blk = wext / 384;
    int w = wext - blk * 384;
    float p = 0.f, q = 0.f;
    if (w == 0 || w == 360) {
        p = x[(size_t)row * Ww + w];
    } else if (w < 360) {
        float a = x[(size_t)row * Ww + w];
        float b = x[(size_t)row * Ww + (Ww - w)];
        p = a + b;
        q = a - b;
    }
    bf16 phi = __float2bfloat16(p);
    bf16 qhi = __float2bfloat16(q);
    if (blk == 1) {
        Ap[g] = __float2bfloat16(p - __bfloat162float(phi));
        Aq[g] = __float2bfloat16(q - __bfloat162float(qhi));
    } else {
        Ap[g] = phi;
        Aq[g] = qhi;
    }
}

// ----------------------------------------------------------------- zero fill
__global__ __launch_bounds__(256) void fill_zero_kernel(uint4* __restrict__ p, long n) {
    long i = (long)blockIdx.x * 256 + threadIdx.x;
    long stride = (long)gridDim.x * 256;
    uint4 z = make_uint4(0u, 0u, 0u, 0u);
    for (; i < n; i += stride) p[i] = z;
}

// ------------------------------------------- fwd MFMA GEMM, compact epilogue
// blockIdx.z selects (Ap,Bc,Xcr) vs (Aq,Bs,Xci). Body identical to proven r5.
__global__ __launch_bounds__(256) void gemm_fwd_compact_kernel(
    const bf16* __restrict__ Ap, const bf16* __restrict__ Aq,
    const bf16* __restrict__ Bc, const bf16* __restrict__ Bsm,
    float* __restrict__ Xcr, float* __restrict__ Xci,
    const int* __restrict__ rs, int T128, int mbase)
{
    __shared__ __align__(128) bf16 As[128][64];
    __shared__ __align__(128) bf16 Bs[128][64];
    const bf16* A  = blockIdx.z ? Aq : Ap;
    const bf16* Bt = blockIdx.z ? Bsm : Bc;
    float* Xc      = blockIdx.z ? Xci : Xcr;
    const int tid = threadIdx.x;
    const int lane = tid & 63;
    const int wave = tid >> 6;
    const int m0 = blockIdx.x * 128;
    const int n0 = blockIdx.y * 128;
    const int wr = (wave >> 1) * 64;
    const int wc = (wave & 1) * 64;
    const int srow = tid >> 3;
    const int scol = (tid & 7) << 3;
    f32x4 acc[4][4] = {};
    for (int k0 = 0; k0 < KF3; k0 += 64) {
#pragma unroll
        for (int i = 0; i < 4; ++i) {
            const bf16* ga = A  + (size_t)(m0 + i * 32 + srow) * KF3 + k0 + scol;
            const bf16* gb = Bt + (size_t)(n0 + i * 32 + srow) * KF3 + k0 + scol;
            gload_lds16(ga, ((char*)&As[0][0]) + (size_t)(i * 256 + tid) * 16);
            gload_lds16(gb, ((char*)&Bs[0][0]) + (size_t)(i * 256 + tid) * 16);
        }
        __syncthreads();
#pragma unroll
        for (int kk = 0; kk < 64; kk += 32) {
            s16x8 a[4], b[4];
#pragma unroll
            for (int m = 0; m < 4; ++m)
                a[m] = *(const s16x8*)&As[wr + m * 16 + (lane & 15)][kk + (lane >> 4) * 8];
#pragma unroll
            for (int n = 0; n < 4; ++n)
                b[n] = *(const s16x8*)&Bs[wc + n * 16 + (lane & 15)][kk + (lane >> 4) * 8];
#pragma unroll
            for (int m = 0; m < 4; ++m)
#pragma unroll
                for (int n = 0; n < 4; ++n)
                    acc[m][n] = __builtin_amdgcn_mfma_f32_16x16x32_bf16(a[m], b[n], acc[m][n], 0, 0, 0);
        }
        __syncthreads();
    }
    const int rbase = (lane >> 4) * 4;
    const int cidx = lane & 15;
#pragma unroll
    for (int m = 0; m < 4; ++m) {
#pragma unroll
        for (int r = 0; r < 4; ++r) {
            int grow = mbase + m0 + wr + m * 16 + rbase + r;
            int bc = grow / Hh;
            int h = grow - bc * Hh;
            int t0 = rs[h];
            int cnt = rs[h + 1] - t0;
#pragma unroll
            for (int n = 0; n < 4; ++n) {
                int j = n0 + wc + n * 16 + cidx;
                if (j < cnt)
                    Xc[(size_t)bc * T128 + t0 + j] = acc[m][n][r];
            }
        }
    }
}

// --------------------------------- inverse GEMM from compact gated spectrum
__global__ __launch_bounds__(256) void gemm_inv_kernel(
    const bf16* __restrict__ Xgr, const bf16* __restrict__ Xgi,
    const bf16* __restrict__ Bt, const int* __restrict__ rs8,
    float* __restrict__ C, int T8cap)
{
    __shared__ __align__(128) bf16 As[128][64];
    __shared__ __align__(128) bf16 Bs[128][64];
    __shared__ int rsL[Hh + 1];
    const int tid = threadIdx.x;
    for (int i = tid; i <= Hh; i += 256) rsL[i] = rs8[i];
    const int lane = tid & 63;
    const int wave = tid >> 6;
    const int m0 = blockIdx.x * 128;
    const int n0 = blockIdx.y * 128;
    const int wr = (wave >> 1) * 64;
    const int wc = (wave & 1) * 64;
    const int srow = tid >> 3;
    const int scol = (tid & 7) << 3;
    __syncthreads();
    f32x4 acc[4][4] = {};
    for (int k0 = 0; k0 < KI; k0 += 64) {
#pragma unroll
        for (int i = 0; i < 4; ++i)
            gload_lds16(Bt + (size_t)(n0 + i * 32 + srow) * KI + k0 + scol,
                        ((char*)&Bs[0][0]) + (size_t)(i * 256 + tid) * 16);
        {
            int k = k0 + scol;
            int j0 = (k < 384) ? k : k - 384;
            const bf16* base = (k < 384) ? Xgr : Xgi;
#pragma unroll
            for (int i = 0; i < 4; ++i) {
                int grow = m0 + i * 32 + srow;
                int bc = grow / Hh;
                int h = grow - bc * Hh;
                int t0v = rsL[h];
                int cnt8 = rsL[h + 1] - t0v;
                s16x8 v = (s16x8){0, 0, 0, 0, 0, 0, 0, 0};
                if (j0 < cnt8)
                    v = *(const s16x8*)(base + (size_t)bc * T8cap + t0v + j0);
                *(s16x8*)&As[i * 32 + srow][scol] = v;
            }
        }
        __syncthreads();
#pragma unroll
        for (int kk = 0; kk < 64; kk += 32) {
            s16x8 a[4], b[4];
#pragma unroll
            for (int m = 0; m < 4; ++m)
                a[m] = *(const s16x8*)&As[wr + m * 16 + (lane & 15)][kk + (lane >> 4) * 8];
#pragma unroll
            for (int n = 0; n < 4; ++n)
                b[n] = *(const s16x8*)&Bs[wc + n * 16 + (lane & 15)][kk + (lane >> 4) * 8];
#pragma unroll
            for (int m = 0; m < 4; ++m)
#pragma unroll
                for (int n = 0; n < 4; ++n)
                    acc[m][n] = __builtin_amdgcn_mfma_f32_16x16x32_bf16(a[m], b[n], acc[m][n], 0, 0, 0);
        }
        __syncthreads();
    }
    const int rbase = (lane >> 4) * 4;
    const int cidx = lane & 15;
#pragma unroll
    for (int m = 0; m < 4; ++m) {
#pragma unroll
        for (int n = 0; n < 4; ++n) {
            int gcol = n0 + wc + n * 16 + cidx;
            if (gcol < NSTORE_INV) {
#pragma unroll
                for (int r = 0; r < 4; ++r) {
                    int grow = m0 + wr + m * 16 + rbase + r;
                    C[(size_t)grow * NI + gcol] = acc[m][n][r];
                }
            }
        }
    }
}

// ------------------------------------------------------- fused middle stage
__device__ __forceinline__ float gelu_exact(float v) {
    return 0.5f * v * (1.0f + erff(v * 0.7071067811865476f));
}

__global__ __launch_bounds__(256, 2) void middle_fused_kernel(
    const float* __restrict__ Xcr, const float* __restrict__ Xci,
    bf16* __restrict__ Xgr, bf16* __restrict__ Xgi,
    const float* __restrict__ mean_r, const float* __restrict__ mean_i,
    const float* __restrict__ stdv,
    const float* __restrict__ mags_r, const float* __restrict__ mags_i,
    const float* __restrict__ bias_r, const float* __restrict__ bias_i,
    const bf16* __restrict__ W1e, const bf16* __restrict__ W2e,
    const float* __restrict__ brelu_p,
    const float* __restrict__ glu_mags, const float* __restrict__ glu_phases,
    const int* __restrict__ rows, const int* __restrict__ cols,
    const int* __restrict__ rs8,
    int T, int T128, int T8cap)
{
    __shared__ __align__(16) char smemA[64 * 264 * 2];
    __shared__ __align__(16) char smemB[64 * 264 * 2];
    bf16*  H1 = (bf16*)smemA;    // [64][264]
    float* aL = (float*)smemA;   // [64][132]
    bf16*  WLb = (bf16*)smemA;
    float* cL = (float*)smemA;
    bf16*  WLa = (bf16*)smemB;
    bf16*  H2 = (bf16*)smemB;    // [64][264]

    const int tid = threadIdx.x;
    const int b = blockIdx.y;
    const int t0 = blockIdx.x * 64;
    const int tl = tid & 63;
    const int cg = tid >> 6;           // 0..3
    const int t = t0 + tl;
    const bool valid = (t < T);
    const int lane = tid & 63;
    const int wv = tid >> 6;
    const int frow = lane & 15;
    const int fcol = (lane >> 4) * 8;
    constexpr int ASRC[6] = {0, 1, 2, 3, 0, 1};
    constexpr int BSRC[6] = {0, 1, 0, 1, 2, 3};

    // ---- phase 1: normalize -> H1
    {
        float mr = 0.f, mi_ = 0.f, isd = 0.f;
        if (valid) { mr = mean_r[t]; mi_ = mean_i[t]; isd = 1.0f / (1e-12f + stdv[t]); }
        for (int ci = 0; ci < 16; ++ci) {
            int c = cg * 16 + ci;
            float xr = 0.f, xi = 0.f;
            if (valid) {
                xr = Xcr[(size_t)(b * 64 + c) * T128 + t];
                xi = Xci[(size_t)(b * 64 + c) * T128 + t];
            }
            float hr = (xr - mr) * isd;
            float hi = (xi - mi_) * isd;
            float h1r = fmaf(hr, mags_r[c], fmaf(-hi, mags_i[c], bias_r[c]));
            float h1i = fmaf(hr, mags_i[c], fmaf(hi, mags_r[c], bias_i[c]));
            bf16 rh = __float2bfloat16(h1r);
            bf16 ih = __float2bfloat16(h1i);
            H1[tl * 264 + c]       = rh;
            H1[tl * 264 + 64 + c]  = ih;
            H1[tl * 264 + 128 + c] = __float2bfloat16(h1r - __bfloat162float(rh));
            H1[tl * 264 + 192 + c] = __float2bfloat16(h1i - __bfloat162float(ih));
        }
    }
    __syncthreads();

    // ---- GEMM1: acc[half][n], A = H1, B = W1 halves staged in smemB
    f32x4 acc[2][4] = {};
    for (int half = 0; half < 2; ++half) {
        if (half) __syncthreads();
        for (int i = tid; i < 2048; i += 256) {
            int r = i >> 5, gc = (i & 31) << 3;
            *(s16x8*)&WLa[r * 264 + gc] = *(const s16x8*)&W1e[(half * 64 + r) * 256 + gc];
        }
        __syncthreads();
#pragma unroll
        for (int lc = 0; lc < 6; ++lc) {
            const int ka = ASRC[lc] * 64, kb = BSRC[lc] * 64;
#pragma unroll
            for (int kk = 0; kk < 64; kk += 32) {
                s16x8 af = *(const s16x8*)&H1[(wv * 16 + frow) * 264 + ka + kk + fcol];
#pragma unroll
                for (int n = 0; n < 4; ++n) {
                    s16x8 bf = *(const s16x8*)&WLa[(n * 16 + frow) * 264 + kb + kk + fcol];
                    acc[half][n] = __builtin_amdgcn_mfma_f32_16x16x32_bf16(af, bf, acc[half][n], 0, 0, 0);
                }
            }
        }
    }
    __syncthreads();

    // ---- phase 3: acc -> aL (overwrites H1)
    const int rbase = (lane >> 4) * 4;
    const int cidx = lane & 15;
#pragma unroll
    for (int half = 0; half < 2; ++half)
#pragma unroll
        for (int n = 0; n < 4; ++n)
#pragma unroll
            for (int r = 0; r < 4; ++r)
                aL[(wv * 16 + rbase + r) * 132 + half * 64 + n * 16 + cidx] = acc[half][n][r];
    __syncthreads();

    // ---- phase 4: gelu -> H2 (overwrites WLa region)
    {
        const float brelu = brelu_p[0];
        for (int ci = 0; ci < 16; ++ci) {
            int c = cg * 16 + ci;
            float ar = aL[tl * 132 + c];
            float ai = aL[tl * 132 + 64 + c];
            float r = sqrtf(ar * ar + ai * ai);
            float g = gelu_exact(r + brelu);
            float h2r, h2i;
            if (r > 0.f) { float f = g / r; h2r = f * ar; h2i = f * ai; }
            else { h2r = g; h2i = 0.f; }
            bf16 rh = __float2bfloat16(h2r);
            bf16 ih = __float2bfloat16(h2i);
            H2[tl * 264 + c]       = rh;
            H2[tl * 264 + 64 + c]  = ih;
            H2[tl * 264 + 128 + c] = __float2bfloat16(h2r - __bfloat162float(rh));
            H2[tl * 264 + 192 + c] = __float2bfloat16(h2i - __bfloat162float(ih));
        }
    }

    // ---- GEMM2: acc2[half][n], A = H2, B = W2 halves staged in smemA
    f32x4 acc2[2][4] = {};
    for (int half = 0; half < 2; ++half) {
        __syncthreads();
        for (int i = tid; i < 2048; i += 256) {
            int r = i >> 5, gc = (i & 31) << 3;
            *(s16x8*)&WLb[r * 264 + gc] = *(const s16x8*)&W2e[(half * 64 + r) * 256 + gc];
        }
        __syncthreads();
#pragma unroll
        for (int lc = 0; lc < 6; ++lc) {
            const int ka = ASRC[lc] * 64, kb = BSRC[lc] * 64;
#pragma unroll
            for (int kk = 0; kk < 64; kk += 32) {
                s16x8 af = *(const s16x8*)&H2[(wv * 16 + frow) * 264 + ka + kk + fcol];
#pragma unroll
                for (int n = 0; n < 4; ++n) {
                    s16x8 bf = *(const s16x8*)&WLb[(n * 16 + frow) * 264 + kb + kk + fcol];
                    acc2[half][n] = __builtin_amdgcn_mfma_f32_16x16x32_bf16(af, bf, acc2[half][n], 0, 0, 0);
                }
            }
        }
    }
    __syncthreads();

    // ---- phase 7: acc2 -> cL (overwrites smemA)
#pragma unroll
    for (int half = 0; half < 2; ++half)
#pragma unroll
        for (int n = 0; n < 4; ++n)
#pragma unroll
            for (int r = 0; r < 4; ++r)
                cL[(wv * 16 + rbase + r) * 132 + half * 64 + n * 16 + cidx] = acc2[half][n][r];
    __syncthreads();

    // ---- phase 8: gate + compact coalesced store
    if (valid) {
        int h = rows[t], j = cols[t];
        size_t wbase = (size_t)rs8[h] + j;
        for (int ci = 0; ci < 16; ++ci) {
            int c = cg * 16 + ci;
            float cr  = cL[tl * 132 + c];
            float cii = cL[tl * 132 + 64 + c];
            float xr = Xcr[(size_t)(b * 64 + c) * T128 + t];
            float xi = Xci[(size_t)(b * 64 + c) * T128 + t];
            float r3 = sqrtf(cr * cr + cii * cii);
            float gm = glu_mags[(size_t)c * T + t];
            float gp = glu_phases[(size_t)c * T + t];
            float sg = 1.0f / (1.0f + expf(-(r3 + gm)));
            float ux, uy;
            if (r3 > 0.f) { float ir3 = 1.0f / r3; ux = cr * ir3; uy = cii * ir3; }
            else { ux = 1.f; uy = 0.f; }
            float sp, cp;
            sincosf(gp, &sp, &cp);
            float gx = sg * (ux * cp - uy * sp);
            float gy = sg * (ux * sp + uy * cp);
            size_t base = (size_t)(b * 64 + c) * T8cap + wbase;
            Xgr[base] = __float2bfloat16(xr * gx - xi * gy);
            Xgi[base] = __float2bfloat16(xr * gy + xi * gx);
        }
    }
}

// -------------------------------------------------- depthwise conv + add
__global__ __launch_bounds__(256) void conv_add_kernel(
    const float* __restrict__ y, const float* __restrict__ dw,
    float* __restrict__ out)
{
    int g = blockIdx.x * 256 + threadIdx.x;
    if (g >= Bb * Cc * Hh * Ww) return;
    int w = g % Ww;
    int rem = g / Ww;
    int h = rem % Hh;
    int bc = rem / Hh;
    int c = bc & (Cc - 1);
    const float* yb = y + (size_t)bc * Hh * NI;
    int walt = (w >= Ww / 2) ? (w - Ww / 2) : (w + Ww / 2);
    float acc = yb[h * NI + w];
#pragma unroll
    for (int k = 0; k < 11; ++k) {
        int hp = h + k - 5;
        int hh, ww;
        if (hp < 0)        { hh = -1 - hp;         ww = walt; }
        else if (hp >= Hh) { hh = 2 * Hh - 1 - hp; ww = walt; }
        else               { hh = hp;              ww = w; }
        acc = fmaf(dw[c * 11 + k], yb[hh * NI + ww], acc);
    }
    out[g] = acc;
}

// ------------------------------------------------------------------ launch
extern "C" void kernel_launch(void* const* d_in, const int* in_sizes, int n_in,
                              void* d_out, int out_size, void* d_ws, size_t ws_size,
                              hipStream_t stream)
{
    const float* x      = (const float*)d_in[0];
    const float* mean_r = (const float*)d_in[1];
    const float* mean_i = (const float*)d_in[2];
    const float* stdv   = (const float*)d_in[3];
    const float* mags_r = (const float*)d_in[4];
    const float* mags_i = (const float*)d_in[5];
    const float* bias_r = (const float*)d_in[6];
    const float* bias_i = (const float*)d_in[7];
    const float* w1_r   = (const float*)d_in[8];
    const float* w1_i   = (const float*)d_in[9];
    const float* brelu  = (const float*)d_in[10];
    const float* w2_r   = (const float*)d_in[11];
    const float* w2_i   = (const float*)d_in[12];
    const float* glu_m  = (const float*)d_in[13];
    const float* glu_p  = (const float*)d_in[14];
    const float* dw     = (const float*)d_in[15];
    const int*   rows   = (const int*)d_in[16];
    const int*   cols   = (const int*)d_in[17];
    const int T = in_sizes[16];
    const int T128 = ((T + 127) / 128) * 128;
    const int T8cap = ((T + 7 * Hh) + 127) & ~127;

    char* ws = (char*)d_ws;
    const size_t SApc  = (size_t)CM * KF3 * 2;            // 26,542,080
    const size_t XC_SZ = (size_t)BC * T128 * 4;           // ~42.6 MB
    const size_t XG_SZ = (size_t)BC * T8cap * 2;          // ~21.9 MB
    const size_t Y_SZ  = (size_t)Mrows * NI * 4;          // 141,557,760
    bf16*  Ap  = (bf16*)ws;
    bf16*  Aq  = (bf16*)(ws + SApc);
    float* Xcr = (float*)(ws + 2 * SApc);
    float* Xci = (float*)(ws + 2 * SApc + XC_SZ);
    float* y   = (float*)ws;
    size_t xc_end = 2 * SApc + 2 * XC_SZ;
    size_t xgoff  = (((Y_SZ > xc_end) ? Y_SZ : xc_end) + 255) & ~(size_t)255;
    bf16*  Xgr = (bf16*)(ws + xgoff);
    bf16*  Xgi = (bf16*)(ws + xgoff + XG_SZ);
    size_t boff = xgoff + 2 * XG_SZ;
    bf16*  Bce = (bf16*)(ws + boff);
    bf16*  Bse = (bf16*)(ws + boff + (size_t)NF * KF3 * 2);
    bf16*  Bti = (bf16*)(ws + boff + 2 * (size_t)NF * KF3 * 2);
    bf16*  W1e = (bf16*)(ws + boff + 2 * (size_t)NF * KF3 * 2 + (size_t)NI * KI * 2);
    bf16*  W2e = W1e + 32768;
    int*   rs  = (int*)(W2e + 32768);
    int*   rs8 = rs + (Hh + 2);

    build_bfwd_kernel<<<(NF * KF3 + 255) / 256, 256, 0, stream>>>(Bce, Bse);
    build_binv_kernel<<<(NI * KI + 255) / 256, 256, 0, stream>>>(Bti);
    build_wext_kernel<<<(2 * 128 * 256 + 255) / 256, 256, 0, stream>>>(
        w1_r, w1_i, w2_r, w2_i, W1e, W2e);
    row_starts_kernel<<<1, 512, 0, stream>>>(rows, T, rs, rs8);

    for (int ch = 0; ch < CHUNKS; ++ch) {
        pack_kernel<<<(CM * KF3 + 255) / 256, 256, 0, stream>>>(
            x + (size_t)ch * CM * Ww, Ap, Aq);
        gemm_fwd_compact_kernel<<<dim3(CM / 128, NF / 128, 2), 256, 0, stream>>>(
            Ap, Aq, Bce, Bse, Xcr, Xci, rs, T128, ch * CM);
    }

    fill_zero_kernel<<<2048, 256, 0, stream>>>((uint4*)Xgr, (long)(2 * XG_SZ / 16));

    const int nT64 = (T + 63) / 64;
    middle_fused_kernel<<<dim3(nT64, Bb), 256, 0, stream>>>(
        Xcr, Xci, Xgr, Xgi, mean_r, mean_i, stdv, mags_r, mags_i,
        bias_r, bias_i, W1e, W2e, brelu, glu_m, glu_p, rows, cols, rs8,
        T, T128, T8cap);

    gemm_inv_kernel<<<dim3(Mrows / 128, NI / 128), 256, 0, stream>>>(
        Xgr, Xgi, Bti, rs8, y, T8cap);

    conv_add_kernel<<<(Bb * Cc * Hh * Ww + 255) / 256, 256, 0, stream>>>(y, dw, (float*)d_out);
}

// Round 9
// 777.808 us; speedup vs baseline: 1.4461x; 1.1063x over previous
//
#include <hip/hip_runtime.h>
#include <hip/hip_bf16.h>
#include <math.h>

#define Hh 360
#define Ww 720
#define Cc 64
#define Bb 2
#define BC (Bb*Cc)        // 128
#define Mrows (BC*Hh)     // 46080
#define CHUNKS 4
#define CM (Mrows/CHUNKS) // 11520
#define KF3 1152          // fwd K: [hi|lo|hi] blocks of 384
#define NF 384            // fwd N (361 bins padded)
#define KI 768            // inv K: [Re(384) | Im(384)]
#define NI 768            // inv C row stride (720 used)
#define NSTORE_INV 720
#define SCALE 0.037267799624996496f   // 1/sqrt(720)
#define TWO_PI 6.2831853071795864769f

typedef __attribute__((ext_vector_type(8))) short s16x8;
typedef __attribute__((ext_vector_type(4))) float f32x4;
typedef __hip_bfloat16 bf16;

__device__ __forceinline__ void gload_lds16(const void* g, void* l) {
    __builtin_amdgcn_global_load_lds(
        (const __attribute__((address_space(1))) unsigned int*)g,
        (__attribute__((address_space(3))) unsigned int*)l, 16, 0, 0);
}
__device__ __forceinline__ short f2bfs(float v) {
    bf16 h = __float2bfloat16(v); short s; __builtin_memcpy(&s, &h, 2); return s;
}
__device__ __forceinline__ float bfs2f(short s) {
    bf16 h; __builtin_memcpy(&h, &s, 2); return __bfloat162float(h);
}

// ---------------------------------------------------------- B-matrix builds
__global__ __launch_bounds__(256) void build_bfwd_kernel(bf16* __restrict__ Bc,
                                                         bf16* __restrict__ Bs) {
    int g = blockIdx.x * 256 + threadIdx.x;
    if (g >= NF * KF3) return;
    int wext = g % KF3;
    int j = g / KF3;
    int blk = wext / 384;
    int w = wext - blk * 384;
    float c = 0.f, s = 0.f;
    if (w <= 360 && j <= 360) {
        int idx = (j * w) % Ww;
        float a = (TWO_PI / Ww) * (float)idx;
        float sv, cv;
        sincosf(a, &sv, &cv);
        c = SCALE * cv;
        s = -SCALE * sv;
    }
    bf16 chi = __float2bfloat16(c);
    bf16 shi = __float2bfloat16(s);
    if (blk == 2) {
        Bc[g] = __float2bfloat16(c - __bfloat162float(chi));
        Bs[g] = __float2bfloat16(s - __bfloat162float(shi));
    } else {
        Bc[g] = chi;
        Bs[g] = shi;
    }
}

__global__ __launch_bounds__(256) void build_binv_kernel(bf16* __restrict__ Bi) {
    int g = blockIdx.x * 256 + threadIdx.x;
    if (g >= NI * KI) return;
    int k = g % KI, n = g / KI;
    float v = 0.f;
    if (n < NSTORE_INV) {
        if (k <= 360) {
            int j = k;
            float f = (j == 0 || j == 360) ? 1.f : 2.f;
            int idx = (j * n) % Ww;
            v = SCALE * f * cosf((TWO_PI / Ww) * (float)idx);
        } else if (k >= 384 && k <= 744) {
            int j = k - 384;
            int idx = (j * n) % Ww;
            v = -2.f * SCALE * sinf((TWO_PI / Ww) * (float)idx);
        }
    }
    Bi[g] = __float2bfloat16(v);
}

// W fragment-packed: s16x8 index = fid*64 + lane, fid = ((n16*4 + kb)*2 + kh).
// element e of that s16x8 = M(n16*16+frow, kfull), kfull = kb*64+kh*32+fcol+e,
// frow=lane&15, fcol=(lane>>4)*8; kk=kfull&127, islo=kfull>>7.
// M(n,kk): n<64 (Re out): kk<64 ? w_r[n][kk] : -w_i[n][kk-64]
//          n>=64 (Im out, p=n-64): kk<64 ? w_i[p][kk] : w_r[p][kk-64]
__global__ __launch_bounds__(256) void build_wf_kernel(
    const float* __restrict__ w1_r, const float* __restrict__ w1_i,
    const float* __restrict__ w2_r, const float* __restrict__ w2_i,
    bf16* __restrict__ W1f, bf16* __restrict__ W2f)
{
    int g = blockIdx.x * 256 + threadIdx.x;
    if (g >= 2 * 32768) return;
    int which = g >> 15;
    int gg = g & 32767;
    int e = gg & 7, lane = (gg >> 3) & 63, kh = (gg >> 9) & 1;
    int kb = (gg >> 10) & 3, n16 = (gg >> 12) & 7;
    int frow = lane & 15, fcol = (lane >> 4) * 8;
    int n = n16 * 16 + frow;
    int kfull = kb * 64 + kh * 32 + fcol + e;
    int kk = kfull & 127, islo = kfull >> 7;
    const float* wr = which ? w2_r : w1_r;
    const float* wi = which ? w2_i : w1_i;
    float v;
    if (n < 64) v = (kk < 64) ? wr[n * 64 + kk] : -wi[n * 64 + kk - 64];
    else { int p = n - 64; v = (kk < 64) ? wi[p * 64 + kk] : wr[p * 64 + kk - 64]; }
    bf16 h = __float2bfloat16(v);
    bf16 out = islo ? __float2bfloat16(v - __bfloat162float(h)) : h;
    (which ? W2f : W1f)[gg] = out;
}

// ---------------------------------------- row starts (compact + 8-padded)
__global__ __launch_bounds__(512) void row_starts_kernel(const int* __restrict__ rows,
                                                         int T, int* __restrict__ rs,
                                                         int* __restrict__ rs8) {
    int h = threadIdx.x;
    if (h <= Hh) {
        if (h == Hh) rs[Hh] = T;
        else {
            int lo = 0, hi = T;
            while (lo < hi) {
                int mid = (lo + hi) >> 1;
                if (rows[mid] < h) lo = mid + 1; else hi = mid;
            }
            rs[h] = lo;
        }
    }
    __syncthreads();
    if (threadIdx.x == 0) {
        int acc = 0;
        for (int i = 0; i < Hh; ++i) {
            rs8[i] = acc;
            int cnt = rs[i + 1] - rs[i];
            acc += (cnt + 7) & ~7;
        }
        rs8[Hh] = acc;
    }
}

// --------------------------------------------- pack x chunk -> A_ext (p,q)
__global__ __launch_bounds__(256) void pack_kernel(const float* __restrict__ x,
                                                   bf16* __restrict__ Ap,
                                                   bf16* __restrict__ Aq) {
    int g = blockIdx.x * 256 + threadIdx.x;
    if (g >= CM * KF3) return;
    int wext = g % KF3;
    int row = g / KF3;
    int blk = wext / 384;
    int w = wext - blk * 384;
    float p = 0.f, q = 0.f;
    if (w == 0 || w == 360) {
        p = x[(size_t)row * Ww + w];
    } else if (w < 360) {
        float a = x[(size_t)row * Ww + w];
        float b = x[(size_t)row * Ww + (Ww - w)];
        p = a + b;
        q = a - b;
    }
    bf16 phi = __float2bfloat16(p);
    bf16 qhi = __float2bfloat16(q);
    if (blk == 1) {
        Ap[g] = __float2bfloat16(p - __bfloat162float(phi));
        Aq[g] = __float2bfloat16(q - __bfloat162float(qhi));
    } else {
        Ap[g] = phi;
        Aq[g] = qhi;
    }
}

// ----------------------------------------------------------------- zero fill
__global__ __launch_bounds__(256) void fill_zero_kernel(uint4* __restrict__ p, long n) {
    long i = (long)blockIdx.x * 256 + threadIdx.x;
    long stride = (long)gridDim.x * 256;
    uint4 z = make_uint4(0u, 0u, 0u, 0u);
    for (; i < n; i += stride) p[i] = z;
}

// ------------------------------------------- fwd MFMA GEMM, compact epilogue
__global__ __launch_bounds__(256) void gemm_fwd_compact_kernel(
    const bf16* __restrict__ Ap, const bf16* __restrict__ Aq,
    const bf16* __restrict__ Bc, const bf16* __restrict__ Bsm,
    float* __restrict__ Xcr, float* __restrict__ Xci,
    const int* __restrict__ rs, int T128, int mbase)
{
    __shared__ __align__(128) bf16 As[128][64];
    __shared__ __align__(128) bf16 Bs[128][64];
    const bf16* A  = blockIdx.z ? Aq : Ap;
    const bf16* Bt = blockIdx.z ? Bsm : Bc;
    float* Xc      = blockIdx.z ? Xci : Xcr;
    const int tid = threadIdx.x;
    const int lane = tid & 63;
    const int wave = tid >> 6;
    const int m0 = blockIdx.x * 128;
    const int n0 = blockIdx.y * 128;
    const int wr = (wave >> 1) * 64;
    const int wc = (wave & 1) * 64;
    const int srow = tid >> 3;
    const int scol = (tid & 7) << 3;
    f32x4 acc[4][4] = {};
    for (int k0 = 0; k0 < KF3; k0 += 64) {
#pragma unroll
        for (int i = 0; i < 4; ++i) {
            const bf16* ga = A  + (size_t)(m0 + i * 32 + srow) * KF3 + k0 + scol;
            const bf16* gb = Bt + (size_t)(n0 + i * 32 + srow) * KF3 + k0 + scol;
            gload_lds16(ga, ((char*)&As[0][0]) + (size_t)(i * 256 + tid) * 16);
            gload_lds16(gb, ((char*)&Bs[0][0]) + (size_t)(i * 256 + tid) * 16);
        }
        __syncthreads();
#pragma unroll
        for (int kk = 0; kk < 64; kk += 32) {
            s16x8 a[4], b[4];
#pragma unroll
            for (int m = 0; m < 4; ++m)
                a[m] = *(const s16x8*)&As[wr + m * 16 + (lane & 15)][kk + (lane >> 4) * 8];
#pragma unroll
            for (int n = 0; n < 4; ++n)
                b[n] = *(const s16x8*)&Bs[wc + n * 16 + (lane & 15)][kk + (lane >> 4) * 8];
#pragma unroll
            for (int m = 0; m < 4; ++m)
#pragma unroll
                for (int n = 0; n < 4; ++n)
                    acc[m][n] = __builtin_amdgcn_mfma_f32_16x16x32_bf16(a[m], b[n], acc[m][n], 0, 0, 0);
        }
        __syncthreads();
    }
    const int rbase = (lane >> 4) * 4;
    const int cidx = lane & 15;
#pragma unroll
    for (int m = 0; m < 4; ++m) {
#pragma unroll
        for (int r = 0; r < 4; ++r) {
            int grow = mbase + m0 + wr + m * 16 + rbase + r;
            int bc = grow / Hh;
            int h = grow - bc * Hh;
            int t0 = rs[h];
            int cnt = rs[h + 1] - t0;
#pragma unroll
            for (int n = 0; n < 4; ++n) {
                int j = n0 + wc + n * 16 + cidx;
                if (j < cnt)
                    Xc[(size_t)bc * T128 + t0 + j] = acc[m][n][r];
            }
        }
    }
}

// --------------------------------- inverse GEMM from compact gated spectrum
__global__ __launch_bounds__(256) void gemm_inv_kernel(
    const bf16* __restrict__ Xgr, const bf16* __restrict__ Xgi,
    const bf16* __restrict__ Bt, const int* __restrict__ rs8,
    float* __restrict__ C, int T8cap)
{
    __shared__ __align__(128) bf16 As[128][64];
    __shared__ __align__(128) bf16 Bs[128][64];
    __shared__ int rsL[Hh + 1];
    const int tid = threadIdx.x;
    for (int i = tid; i <= Hh; i += 256) rsL[i] = rs8[i];
    const int lane = tid & 63;
    const int wave = tid >> 6;
    const int m0 = blockIdx.x * 128;
    const int n0 = blockIdx.y * 128;
    const int wr = (wave >> 1) * 64;
    const int wc = (wave & 1) * 64;
    const int srow = tid >> 3;
    const int scol = (tid & 7) << 3;
    __syncthreads();
    f32x4 acc[4][4] = {};
    for (int k0 = 0; k0 < KI; k0 += 64) {
#pragma unroll
        for (int i = 0; i < 4; ++i)
            gload_lds16(Bt + (size_t)(n0 + i * 32 + srow) * KI + k0 + scol,
                        ((char*)&Bs[0][0]) + (size_t)(i * 256 + tid) * 16);
        {
            int k = k0 + scol;
            int j0 = (k < 384) ? k : k - 384;
            const bf16* base = (k < 384) ? Xgr : Xgi;
#pragma unroll
            for (int i = 0; i < 4; ++i) {
                int grow = m0 + i * 32 + srow;
                int bc = grow / Hh;
                int h = grow - bc * Hh;
                int t0v = rsL[h];
                int cnt8 = rsL[h + 1] - t0v;
                s16x8 v = (s16x8){0, 0, 0, 0, 0, 0, 0, 0};
                if (j0 < cnt8)
                    v = *(const s16x8*)(base + (size_t)bc * T8cap + t0v + j0);
                *(s16x8*)&As[i * 32 + srow][scol] = v;
            }
        }
        __syncthreads();
#pragma unroll
        for (int kk = 0; kk < 64; kk += 32) {
            s16x8 a[4], b[4];
#pragma unroll
            for (int m = 0; m < 4; ++m)
                a[m] = *(const s16x8*)&As[wr + m * 16 + (lane & 15)][kk + (lane >> 4) * 8];
#pragma unroll
            for (int n = 0; n < 4; ++n)
                b[n] = *(const s16x8*)&Bs[wc + n * 16 + (lane & 15)][kk + (lane >> 4) * 8];
#pragma unroll
            for (int m = 0; m < 4; ++m)
#pragma unroll
                for (int n = 0; n < 4; ++n)
                    acc[m][n] = __builtin_amdgcn_mfma_f32_16x16x32_bf16(a[m], b[n], acc[m][n], 0, 0, 0);
        }
        __syncthreads();
    }
    const int rbase = (lane >> 4) * 4;
    const int cidx = lane & 15;
#pragma unroll
    for (int m = 0; m < 4; ++m) {
#pragma unroll
        for (int n = 0; n < 4; ++n) {
            int gcol = n0 + wc + n * 16 + cidx;
            if (gcol < NSTORE_INV) {
#pragma unroll
                for (int r = 0; r < 4; ++r) {
                    int grow = m0 + wr + m * 16 + rbase + r;
                    C[(size_t)grow * NI + gcol] = acc[m][n][r];
                }
            }
        }
    }
}

// ------------------------------------------------ fused middle stage (v3)
__device__ __forceinline__ float gelu_exact(float v) {
    return 0.5f * v * (1.0f + erff(v * 0.7071067811865476f));
}

__global__ __launch_bounds__(256, 4) void middle_fused_kernel(
    const float* __restrict__ Xcr, const float* __restrict__ Xci,
    bf16* __restrict__ Xgr, bf16* __restrict__ Xgi,
    const float* __restrict__ mean_r, const float* __restrict__ mean_i,
    const float* __restrict__ stdv,
    const float* __restrict__ mags_r, const float* __restrict__ mags_i,
    const float* __restrict__ bias_r, const float* __restrict__ bias_i,
    const bf16* __restrict__ W1f, const bf16* __restrict__ W2f,
    const float* __restrict__ brelu_p,
    const float* __restrict__ glu_mags, const float* __restrict__ glu_phases,
    const int* __restrict__ rows, const int* __restrict__ cols,
    const int* __restrict__ rs8,
    int T, int T128, int T8cap)
{
    __shared__ __align__(16) char smemA[32 * 264 * 2];   // 16,896 B
    __shared__ __align__(16) char smemB[32 * 264 * 2];
    bf16*  H1 = (bf16*)smemA;    // [32][264] hi/lo split input
    float* aL = (float*)smemA;   // [32][132] GEMM1 result
    float* cL = (float*)smemA;   // [32][132] GEMM2 result
    bf16*  H2 = (bf16*)smemB;    // [32][264] gelu output

    const int tid = threadIdx.x;
    const int b = blockIdx.y;
    const int t0 = blockIdx.x * 32;
    const int tl = tid & 31;
    const int cg = tid >> 5;          // 0..7
    const int t = t0 + tl;
    const bool valid = (t < T);
    const int lane = tid & 63;
    const int wv = tid >> 6;          // 0..3
    const int frow = lane & 15;
    const int fcol = (lane >> 4) * 8;
    const s16x8* W1v = (const s16x8*)W1f;
    const s16x8* W2v = (const s16x8*)W2f;
    constexpr int ASRC[6] = {0, 1, 2, 3, 0, 1};
    constexpr int BSRC[6] = {0, 1, 0, 1, 2, 3};

    // ---- phase 1: normalize -> H1 (lane=t, coalesced global reads)
    {
        float mr = 0.f, mi_ = 0.f, isd = 0.f;
        if (valid) { mr = mean_r[t]; mi_ = mean_i[t]; isd = 1.0f / (1e-12f + stdv[t]); }
        s16x8 vhr, vhi, vlr, vli;
#pragma unroll
        for (int ci = 0; ci < 8; ++ci) {
            int c = cg * 8 + ci;
            float xr = 0.f, xi = 0.f;
            if (valid) {
                xr = Xcr[(size_t)(b * 64 + c) * T128 + t];
                xi = Xci[(size_t)(b * 64 + c) * T128 + t];
            }
            float hr = (xr - mr) * isd;
            float hi = (xi - mi_) * isd;
            float h1r = fmaf(hr, mags_r[c], fmaf(-hi, mags_i[c], bias_r[c]));
            float h1i = fmaf(hr, mags_i[c], fmaf(hi, mags_r[c], bias_i[c]));
            short rh = f2bfs(h1r), ih = f2bfs(h1i);
            vhr[ci] = rh; vhi[ci] = ih;
            vlr[ci] = f2bfs(h1r - bfs2f(rh));
            vli[ci] = f2bfs(h1i - bfs2f(ih));
        }
        *(s16x8*)&H1[tl * 264 + cg * 8]       = vhr;
        *(s16x8*)&H1[tl * 264 + 64 + cg * 8]  = vhi;
        *(s16x8*)&H1[tl * 264 + 128 + cg * 8] = vlr;
        *(s16x8*)&H1[tl * 264 + 192 + cg * 8] = vli;
    }
    __syncthreads();

    // ---- GEMM1: A = H1 [32][264], B frags direct from W1f (L2)
    f32x4 acc[2][2] = {};
#pragma unroll
    for (int lc = 0; lc < 6; ++lc) {
        const int ka = ASRC[lc] * 64;
        const int kb = BSRC[lc];
#pragma unroll
        for (int kh = 0; kh < 2; ++kh) {
            s16x8 a0 = *(const s16x8*)&H1[frow * 264 + ka + kh * 32 + fcol];
            s16x8 a1 = *(const s16x8*)&H1[(16 + frow) * 264 + ka + kh * 32 + fcol];
#pragma unroll
            for (int n = 0; n < 2; ++n) {
                s16x8 bfv = W1v[(size_t)((((wv * 2 + n) * 4 + kb) * 2 + kh) * 64 + lane)];
                acc[0][n] = __builtin_amdgcn_mfma_f32_16x16x32_bf16(a0, bfv, acc[0][n], 0, 0, 0);
                acc[1][n] = __builtin_amdgcn_mfma_f32_16x16x32_bf16(a1, bfv, acc[1][n], 0, 0, 0);
            }
        }
    }
    __syncthreads();

    // ---- phase 3: acc -> aL (overwrites H1)
    const int rbase = (lane >> 4) * 4;
    const int cidx = lane & 15;
#pragma unroll
    for (int m = 0; m < 2; ++m)
#pragma unroll
        for (int n = 0; n < 2; ++n)
#pragma unroll
            for (int r = 0; r < 4; ++r)
                aL[(m * 16 + rbase + r) * 132 + wv * 32 + n * 16 + cidx] = acc[m][n][r];
    __syncthreads();

    // ---- phase 4: gelu (lane=t) -> H2
    {
        const float brelu = brelu_p[0];
        f32x4 ar0 = *(const f32x4*)&aL[tl * 132 + cg * 8];
        f32x4 ar1 = *(const f32x4*)&aL[tl * 132 + cg * 8 + 4];
        f32x4 ai0 = *(const f32x4*)&aL[tl * 132 + 64 + cg * 8];
        f32x4 ai1 = *(const f32x4*)&aL[tl * 132 + 64 + cg * 8 + 4];
        s16x8 vhr, vhi, vlr, vli;
#pragma unroll
        for (int ci = 0; ci < 8; ++ci) {
            float ar = (ci < 4) ? ar0[ci & 3] : ar1[ci & 3];
            float ai = (ci < 4) ? ai0[ci & 3] : ai1[ci & 3];
            float r = sqrtf(ar * ar + ai * ai);
            float g = gelu_exact(r + brelu);
            float h2r, h2i;
            if (r > 0.f) { float f = g / r; h2r = f * ar; h2i = f * ai; }
            else { h2r = g; h2i = 0.f; }
            short rh = f2bfs(h2r), ih = f2bfs(h2i);
            vhr[ci] = rh; vhi[ci] = ih;
            vlr[ci] = f2bfs(h2r - bfs2f(rh));
            vli[ci] = f2bfs(h2i - bfs2f(ih));
        }
        *(s16x8*)&H2[tl * 264 + cg * 8]       = vhr;
        *(s16x8*)&H2[tl * 264 + 64 + cg * 8]  = vhi;
        *(s16x8*)&H2[tl * 264 + 128 + cg * 8] = vlr;
        *(s16x8*)&H2[tl * 264 + 192 + cg * 8] = vli;
    }
    __syncthreads();

    // ---- GEMM2: A = H2, B frags from W2f
    f32x4 acc2[2][2] = {};
#pragma unroll
    for (int lc = 0; lc < 6; ++lc) {
        const int ka = ASRC[lc] * 64;
        const int kb = BSRC[lc];
#pragma unroll
        for (int kh = 0; kh < 2; ++kh) {
            s16x8 a0 = *(const s16x8*)&H2[frow * 264 + ka + kh * 32 + fcol];
            s16x8 a1 = *(const s16x8*)&H2[(16 + frow) * 264 + ka + kh * 32 + fcol];
#pragma unroll
            for (int n = 0; n < 2; ++n) {
                s16x8 bfv = W2v[(size_t)((((wv * 2 + n) * 4 + kb) * 2 + kh) * 64 + lane)];
                acc2[0][n] = __builtin_amdgcn_mfma_f32_16x16x32_bf16(a0, bfv, acc2[0][n], 0, 0, 0);
                acc2[1][n] = __builtin_amdgcn_mfma_f32_16x16x32_bf16(a1, bfv, acc2[1][n], 0, 0, 0);
            }
        }
    }
    // cL aliases aL (smemA): all aL reads completed before the barrier above
    // GEMM2; no thread reads smemA during GEMM2.
#pragma unroll
    for (int m = 0; m < 2; ++m)
#pragma unroll
        for (int n = 0; n < 2; ++n)
#pragma unroll
            for (int r = 0; r < 4; ++r)
                cL[(m * 16 + rbase + r) * 132 + wv * 32 + n * 16 + cidx] = acc2[m][n][r];
    __syncthreads();

    // ---- phase 8: gate + compact coalesced store (lane=t)
    if (valid) {
        int h = rows[t], j = cols[t];
        size_t wbase = (size_t)rs8[h] + j;
        f32x4 cr0 = *(const f32x4*)&cL[tl * 132 + cg * 8];
        f32x4 cr1 = *(const f32x4*)&cL[tl * 132 + cg * 8 + 4];
        f32x4 ci0 = *(const f32x4*)&cL[tl * 132 + 64 + cg * 8];
        f32x4 ci1 = *(const f32x4*)&cL[tl * 132 + 64 + cg * 8 + 4];
#pragma unroll
        for (int ci = 0; ci < 8; ++ci) {
            int c = cg * 8 + ci;
            float cr  = (ci < 4) ? cr0[ci & 3] : cr1[ci & 3];
            float cii = (ci < 4) ? ci0[ci & 3] : ci1[ci & 3];
            float xr = Xcr[(size_t)(b * 64 + c) * T128 + t];
            float xi = Xci[(size_t)(b * 64 + c) * T128 + t];
            float r3 = sqrtf(cr * cr + cii * cii);
            float gm = glu_mags[(size_t)c * T + t];
            float gp = glu_phases[(size_t)c * T + t];
            float sg = 1.0f / (1.0f + expf(-(r3 + gm)));
            float ux, uy;
            if (r3 > 0.f) { float ir3 = 1.0f / r3; ux = cr * ir3; uy = cii * ir3; }
            else { ux = 1.f; uy = 0.f; }
            float sp, cp;
            sincosf(gp, &sp, &cp);
            float gx = sg * (ux * cp - uy * sp);
            float gy = sg * (ux * sp + uy * cp);
            size_t base = (size_t)(b * 64 + c) * T8cap + wbase;
            Xgr[base] = __float2bfloat16(xr * gx - xi * gy);
            Xgi[base] = __float2bfloat16(xr * gy + xi * gx);
        }
    }
}

// -------------------------------------------------- depthwise conv + add
__global__ __launch_bounds__(256) void conv_add_kernel(
    const float* __restrict__ y, const float* __restrict__ dw,
    float* __restrict__ out)
{
    int g = blockIdx.x * 256 + threadIdx.x;
    if (g >= Bb * Cc * Hh * Ww) return;
    int w = g % Ww;
    int rem = g / Ww;
    int h = rem % Hh;
    int bc = rem / Hh;
    int c = bc & (Cc - 1);
    const float* yb = y + (size_t)bc * Hh * NI;
    int walt = (w >= Ww / 2) ? (w - Ww / 2) : (w + Ww / 2);
    float acc = yb[h * NI + w];
#pragma unroll
    for (int k = 0; k < 11; ++k) {
        int hp = h + k - 5;
        int hh, ww;
        if (hp < 0)        { hh = -1 - hp;         ww = walt; }
        else if (hp >= Hh) { hh = 2 * Hh - 1 - hp; ww = walt; }
        else               { hh = hp;              ww = w; }
        acc = fmaf(dw[c * 11 + k], yb[hh * NI + ww], acc);
    }
    out[g] = acc;
}

// ------------------------------------------------------------------ launch
extern "C" void kernel_launch(void* const* d_in, const int* in_sizes, int n_in,
                              void* d_out, int out_size, void* d_ws, size_t ws_size,
                              hipStream_t stream)
{
    const float* x      = (const float*)d_in[0];
    const float* mean_r = (const float*)d_in[1];
    const float* mean_i = (const float*)d_in[2];
    const float* stdv   = (const float*)d_in[3];
    const float* mags_r = (const float*)d_in[4];
    const float* mags_i = (const float*)d_in[5];
    const float* bias_r = (const float*)d_in[6];
    const float* bias_i = (const float*)d_in[7];
    const float* w1_r   = (const float*)d_in[8];
    const float* w1_i   = (const float*)d_in[9];
    const float* brelu  = (const float*)d_in[10];
    const float* w2_r   = (const float*)d_in[11];
    const float* w2_i   = (const float*)d_in[12];
    const float* glu_m  = (const float*)d_in[13];
    const float* glu_p  = (const float*)d_in[14];
    const float* dw     = (const float*)d_in[15];
    const int*   rows   = (const int*)d_in[16];
    const int*   cols   = (const int*)d_in[17];
    const int T = in_sizes[16];
    const int T128 = ((T + 127) / 128) * 128;
    const int T8cap = ((T + 7 * Hh) + 127) & ~127;

    char* ws = (char*)d_ws;
    const size_t SApc  = (size_t)CM * KF3 * 2;            // 26,542,080
    const size_t XC_SZ = (size_t)BC * T128 * 4;           // ~42.6 MB
    const size_t XG_SZ = (size_t)BC * T8cap * 2;          // ~21.9 MB
    const size_t Y_SZ  = (size_t)Mrows * NI * 4;          // 141,557,760
    bf16*  Ap  = (bf16*)ws;
    bf16*  Aq  = (bf16*)(ws + SApc);
    float* Xcr = (float*)(ws + 2 * SApc);
    float* Xci = (float*)(ws + 2 * SApc + XC_SZ);
    float* y   = (float*)ws;
    size_t xc_end = 2 * SApc + 2 * XC_SZ;
    size_t xgoff  = (((Y_SZ > xc_end) ? Y_SZ : xc_end) + 255) & ~(size_t)255;
    bf16*  Xgr = (bf16*)(ws + xgoff);
    bf16*  Xgi = (bf16*)(ws + xgoff + XG_SZ);
    size_t boff = xgoff + 2 * XG_SZ;
    bf16*  Bce = (bf16*)(ws + boff);
    bf16*  Bse = (bf16*)(ws + boff + (size_t)NF * KF3 * 2);
    bf16*  Bti = (bf16*)(ws + boff + 2 * (size_t)NF * KF3 * 2);
    bf16*  W1f = (bf16*)(ws + boff + 2 * (size_t)NF * KF3 * 2 + (size_t)NI * KI * 2);
    bf16*  W2f = W1f + 32768;
    int*   rs  = (int*)(W2f + 32768);
    int*   rs8 = rs + (Hh + 2);

    build_bfwd_kernel<<<(NF * KF3 + 255) / 256, 256, 0, stream>>>(Bce, Bse);
    build_binv_kernel<<<(NI * KI + 255) / 256, 256, 0, stream>>>(Bti);
    build_wf_kernel<<<(2 * 32768 + 255) / 256, 256, 0, stream>>>(
        w1_r, w1_i, w2_r, w2_i, W1f, W2f);
    row_starts_kernel<<<1, 512, 0, stream>>>(rows, T, rs, rs8);

    for (int ch = 0; ch < CHUNKS; ++ch) {
        pack_kernel<<<(CM * KF3 + 255) / 256, 256, 0, stream>>>(
            x + (size_t)ch * CM * Ww, Ap, Aq);
        gemm_fwd_compact_kernel<<<dim3(CM / 128, NF / 128, 2), 256, 0, stream>>>(
            Ap, Aq, Bce, Bse, Xcr, Xci, rs, T128, ch * CM);
    }

    fill_zero_kernel<<<2048, 256, 0, stream>>>((uint4*)Xgr, (long)(2 * XG_SZ / 16));

    const int nT32 = (T + 31) / 32;
    middle_fused_kernel<<<dim3(nT32, Bb), 256, 0, stream>>>(
        Xcr, Xci, Xgr, Xgi, mean_r, mean_i, stdv, mags_r, mags_i,
        bias_r, bias_i, W1f, W2f, brelu, glu_m, glu_p, rows, cols, rs8,
        T, T128, T8cap);

    gemm_inv_kernel<<<dim3(Mrows / 128, NI / 128), 256, 0, stream>>>(
        Xgr, Xgi, Bti, rs8, y, T8cap);

    conv_add_kernel<<<(Bb * Cc * Hh * Ww + 255) / 256, 256, 0, stream>>>(y, dw, (float*)d_out);
}

// Round 10
// 732.024 us; speedup vs baseline: 1.5366x; 1.0625x over previous
//
#include <hip/hip_runtime.h>
#include <hip/hip_bf16.h>
#include <math.h>

#define Hh 360
#define Ww 720
#define Cc 64
#define Bb 2
#define BC (Bb*Cc)        // 128
#define Mrows (BC*Hh)     // 46080
#define CHUNKS 4
#define CM (Mrows/CHUNKS) // 11520
#define KF3 1152          // fwd K: [hi|lo|hi] blocks of 384
#define NF 384            // fwd N (361 bins padded)
#define KI 768            // inv K: [Re(384) | Im(384)]
#define NI 768            // inv C row stride (720 used)
#define NSTORE_INV 720
#define SCALE 0.037267799624996496f   // 1/sqrt(720)
#define TWO_PI 6.2831853071795864769f

typedef __attribute__((ext_vector_type(8))) short s16x8;
typedef __attribute__((ext_vector_type(4))) float f32x4;
typedef __hip_bfloat16 bf16;

__device__ __forceinline__ void gload_lds16(const void* g, void* l) {
    __builtin_amdgcn_global_load_lds(
        (const __attribute__((address_space(1))) unsigned int*)g,
        (__attribute__((address_space(3))) unsigned int*)l, 16, 0, 0);
}
__device__ __forceinline__ short f2bfs(float v) {
    bf16 h = __float2bfloat16(v); short s; __builtin_memcpy(&s, &h, 2); return s;
}
__device__ __forceinline__ float bfs2f(short s) {
    bf16 h; __builtin_memcpy(&h, &s, 2); return __bfloat162float(h);
}

// ---------------------------------------------------------- B-matrix builds
__global__ __launch_bounds__(256) void build_bfwd_kernel(bf16* __restrict__ Bc,
                                                         bf16* __restrict__ Bs) {
    int g = blockIdx.x * 256 + threadIdx.x;
    if (g >= NF * KF3) return;
    int wext = g % KF3;
    int j = g / KF3;
    int blk = wext / 384;
    int w = wext - blk * 384;
    float c = 0.f, s = 0.f;
    if (w <= 360 && j <= 360) {
        int idx = (j * w) % Ww;
        float a = (TWO_PI / Ww) * (float)idx;
        float sv, cv;
        sincosf(a, &sv, &cv);
        c = SCALE * cv;
        s = -SCALE * sv;
    }
    bf16 chi = __float2bfloat16(c);
    bf16 shi = __float2bfloat16(s);
    if (blk == 2) {
        Bc[g] = __float2bfloat16(c - __bfloat162float(chi));
        Bs[g] = __float2bfloat16(s - __bfloat162float(shi));
    } else {
        Bc[g] = chi;
        Bs[g] = shi;
    }
}

__global__ __launch_bounds__(256) void build_binv_kernel(bf16* __restrict__ Bi) {
    int g = blockIdx.x * 256 + threadIdx.x;
    if (g >= NI * KI) return;
    int k = g % KI, n = g / KI;
    float v = 0.f;
    if (n < NSTORE_INV) {
        if (k <= 360) {
            int j = k;
            float f = (j == 0 || j == 360) ? 1.f : 2.f;
            int idx = (j * n) % Ww;
            v = SCALE * f * cosf((TWO_PI / Ww) * (float)idx);
        } else if (k >= 384 && k <= 744) {
            int j = k - 384;
            int idx = (j * n) % Ww;
            v = -2.f * SCALE * sinf((TWO_PI / Ww) * (float)idx);
        }
    }
    Bi[g] = __float2bfloat16(v);
}

// W fragment-packed: s16x8 index = fid*64 + lane, fid = ((n16*4 + kb)*2 + kh).
__global__ __launch_bounds__(256) void build_wf_kernel(
    const float* __restrict__ w1_r, const float* __restrict__ w1_i,
    const float* __restrict__ w2_r, const float* __restrict__ w2_i,
    bf16* __restrict__ W1f, bf16* __restrict__ W2f)
{
    int g = blockIdx.x * 256 + threadIdx.x;
    if (g >= 2 * 32768) return;
    int which = g >> 15;
    int gg = g & 32767;
    int e = gg & 7, lane = (gg >> 3) & 63, kh = (gg >> 9) & 1;
    int kb = (gg >> 10) & 3, n16 = (gg >> 12) & 7;
    int frow = lane & 15, fcol = (lane >> 4) * 8;
    int n = n16 * 16 + frow;
    int kfull = kb * 64 + kh * 32 + fcol + e;
    int kk = kfull & 127, islo = kfull >> 7;
    const float* wr = which ? w2_r : w1_r;
    const float* wi = which ? w2_i : w1_i;
    float v;
    if (n < 64) v = (kk < 64) ? wr[n * 64 + kk] : -wi[n * 64 + kk - 64];
    else { int p = n - 64; v = (kk < 64) ? wi[p * 64 + kk] : wr[p * 64 + kk - 64]; }
    bf16 h = __float2bfloat16(v);
    bf16 out = islo ? __float2bfloat16(v - __bfloat162float(h)) : h;
    (which ? W2f : W1f)[gg] = out;
}

// ---------------------------------------- row starts (compact + 8-padded)
__global__ __launch_bounds__(512) void row_starts_kernel(const int* __restrict__ rows,
                                                         int T, int* __restrict__ rs,
                                                         int* __restrict__ rs8) {
    int h = threadIdx.x;
    if (h <= Hh) {
        if (h == Hh) rs[Hh] = T;
        else {
            int lo = 0, hi = T;
            while (lo < hi) {
                int mid = (lo + hi) >> 1;
                if (rows[mid] < h) lo = mid + 1; else hi = mid;
            }
            rs[h] = lo;
        }
    }
    __syncthreads();
    if (threadIdx.x == 0) {
        int acc = 0;
        for (int i = 0; i < Hh; ++i) {
            rs8[i] = acc;
            int cnt = rs[i + 1] - rs[i];
            acc += (cnt + 7) & ~7;
        }
        rs8[Hh] = acc;
    }
}

// --------------------------------------------- pack x chunk -> A_ext (p,q)
__global__ __launch_bounds__(256) void pack_kernel(const float* __restrict__ x,
                                                   bf16* __restrict__ Ap,
                                                   bf16* __restrict__ Aq) {
    int g = blockIdx.x * 256 + threadIdx.x;
    if (g >= CM * KF3) return;
    int wext = g % KF3;
    int row = g / KF3;
    int blk = wext / 384;
    int w = wext - blk * 384;
    float p = 0.f, q = 0.f;
    if (w == 0 || w == 360) {
        p = x[(size_t)row * Ww + w];
    } else if (w < 360) {
        float a = x[(size_t)row * Ww + w];
        float b = x[(size_t)row * Ww + (Ww - w)];
        p = a + b;
        q = a - b;
    }
    bf16 phi = __float2bfloat16(p);
    bf16 qhi = __float2bfloat16(q);
    if (blk == 1) {
        Ap[g] = __float2bfloat16(p - __bfloat162float(phi));
        Aq[g] = __float2bfloat16(q - __bfloat162float(qhi));
    } else {
        Ap[g] = phi;
        Aq[g] = qhi;
    }
}

// ----------------------------------------------------------------- zero fill
__global__ __launch_bounds__(256) void fill_zero_kernel(uint4* __restrict__ p, long n) {
    long i = (long)blockIdx.x * 256 + threadIdx.x;
    long stride = (long)gridDim.x * 256;
    uint4 z = make_uint4(0u, 0u, 0u, 0u);
    for (; i < n; i += stride) p[i] = z;
}

// ------------------------------------------- fwd MFMA GEMM, compact epilogue
__global__ __launch_bounds__(256) void gemm_fwd_compact_kernel(
    const bf16* __restrict__ Ap, const bf16* __restrict__ Aq,
    const bf16* __restrict__ Bc, const bf16* __restrict__ Bsm,
    float* __restrict__ Xcr, float* __restrict__ Xci,
    const int* __restrict__ rs, int T128, int mbase)
{
    __shared__ __align__(128) bf16 As[128][64];
    __shared__ __align__(128) bf16 Bs[128][64];
    const bf16* A  = blockIdx.z ? Aq : Ap;
    const bf16* Bt = blockIdx.z ? Bsm : Bc;
    float* Xc      = blockIdx.z ? Xci : Xcr;
    const int tid = threadIdx.x;
    const int lane = tid & 63;
    const int wave = tid >> 6;
    const int m0 = blockIdx.x * 128;
    const int n0 = blockIdx.y * 128;
    const int wr = (wave >> 1) * 64;
    const int wc = (wave & 1) * 64;
    const int srow = tid >> 3;
    const int scol = (tid & 7) << 3;
    f32x4 acc[4][4] = {};
    for (int k0 = 0; k0 < KF3; k0 += 64) {
#pragma unroll
        for (int i = 0; i < 4; ++i) {
            const bf16* ga = A  + (size_t)(m0 + i * 32 + srow) * KF3 + k0 + scol;
            const bf16* gb = Bt + (size_t)(n0 + i * 32 + srow) * KF3 + k0 + scol;
            gload_lds16(ga, ((char*)&As[0][0]) + (size_t)(i * 256 + tid) * 16);
            gload_lds16(gb, ((char*)&Bs[0][0]) + (size_t)(i * 256 + tid) * 16);
        }
        __syncthreads();
#pragma unroll
        for (int kk = 0; kk < 64; kk += 32) {
            s16x8 a[4], b[4];
#pragma unroll
            for (int m = 0; m < 4; ++m)
                a[m] = *(const s16x8*)&As[wr + m * 16 + (lane & 15)][kk + (lane >> 4) * 8];
#pragma unroll
            for (int n = 0; n < 4; ++n)
                b[n] = *(const s16x8*)&Bs[wc + n * 16 + (lane & 15)][kk + (lane >> 4) * 8];
#pragma unroll
            for (int m = 0; m < 4; ++m)
#pragma unroll
                for (int n = 0; n < 4; ++n)
                    acc[m][n] = __builtin_amdgcn_mfma_f32_16x16x32_bf16(a[m], b[n], acc[m][n], 0, 0, 0);
        }
        __syncthreads();
    }
    const int rbase = (lane >> 4) * 4;
    const int cidx = lane & 15;
#pragma unroll
    for (int m = 0; m < 4; ++m) {
#pragma unroll
        for (int r = 0; r < 4; ++r) {
            int grow = mbase + m0 + wr + m * 16 + rbase + r;
            int bc = grow / Hh;
            int h = grow - bc * Hh;
            int t0 = rs[h];
            int cnt = rs[h + 1] - t0;
#pragma unroll
            for (int n = 0; n < 4; ++n) {
                int j = n0 + wc + n * 16 + cidx;
                if (j < cnt)
                    Xc[(size_t)bc * T128 + t0 + j] = acc[m][n][r];
            }
        }
    }
}

// --------------------------------- inverse GEMM from compact gated spectrum
__global__ __launch_bounds__(256) void gemm_inv_kernel(
    const bf16* __restrict__ Xgr, const bf16* __restrict__ Xgi,
    const bf16* __restrict__ Bt, const int* __restrict__ rs8,
    float* __restrict__ C, int T8cap)
{
    __shared__ __align__(128) bf16 As[128][64];
    __shared__ __align__(128) bf16 Bs[128][64];
    __shared__ int rsL[Hh + 1];
    const int tid = threadIdx.x;
    for (int i = tid; i <= Hh; i += 256) rsL[i] = rs8[i];
    const int lane = tid & 63;
    const int wave = tid >> 6;
    const int m0 = blockIdx.x * 128;
    const int n0 = blockIdx.y * 128;
    const int wr = (wave >> 1) * 64;
    const int wc = (wave & 1) * 64;
    const int srow = tid >> 3;
    const int scol = (tid & 7) << 3;
    __syncthreads();
    f32x4 acc[4][4] = {};
    for (int k0 = 0; k0 < KI; k0 += 64) {
#pragma unroll
        for (int i = 0; i < 4; ++i)
            gload_lds16(Bt + (size_t)(n0 + i * 32 + srow) * KI + k0 + scol,
                        ((char*)&Bs[0][0]) + (size_t)(i * 256 + tid) * 16);
        {
            int k = k0 + scol;
            int j0 = (k < 384) ? k : k - 384;
            const bf16* base = (k < 384) ? Xgr : Xgi;
#pragma unroll
            for (int i = 0; i < 4; ++i) {
                int grow = m0 + i * 32 + srow;
                int bc = grow / Hh;
                int h = grow - bc * Hh;
                int t0v = rsL[h];
                int cnt8 = rsL[h + 1] - t0v;
                s16x8 v = (s16x8){0, 0, 0, 0, 0, 0, 0, 0};
                if (j0 < cnt8)
                    v = *(const s16x8*)(base + (size_t)bc * T8cap + t0v + j0);
                *(s16x8*)&As[i * 32 + srow][scol] = v;
            }
        }
        __syncthreads();
#pragma unroll
        for (int kk = 0; kk < 64; kk += 32) {
            s16x8 a[4], b[4];
#pragma unroll
            for (int m = 0; m < 4; ++m)
                a[m] = *(const s16x8*)&As[wr + m * 16 + (lane & 15)][kk + (lane >> 4) * 8];
#pragma unroll
            for (int n = 0; n < 4; ++n)
                b[n] = *(const s16x8*)&Bs[wc + n * 16 + (lane & 15)][kk + (lane >> 4) * 8];
#pragma unroll
            for (int m = 0; m < 4; ++m)
#pragma unroll
                for (int n = 0; n < 4; ++n)
                    acc[m][n] = __builtin_amdgcn_mfma_f32_16x16x32_bf16(a[m], b[n], acc[m][n], 0, 0, 0);
        }
        __syncthreads();
    }
    const int rbase = (lane >> 4) * 4;
    const int cidx = lane & 15;
#pragma unroll
    for (int m = 0; m < 4; ++m) {
#pragma unroll
        for (int n = 0; n < 4; ++n) {
            int gcol = n0 + wc + n * 16 + cidx;
            if (gcol < NSTORE_INV) {
#pragma unroll
                for (int r = 0; r < 4; ++r) {
                    int grow = m0 + wr + m * 16 + rbase + r;
                    C[(size_t)grow * NI + gcol] = acc[m][n][r];
                }
            }
        }
    }
}

// ------------------------------------------------ fused middle stage (v3)
__device__ __forceinline__ float gelu_exact(float v) {
    return 0.5f * v * (1.0f + erff(v * 0.7071067811865476f));
}

__global__ __launch_bounds__(256, 4) void middle_fused_kernel(
    const float* __restrict__ Xcr, const float* __restrict__ Xci,
    bf16* __restrict__ Xgr, bf16* __restrict__ Xgi,
    const float* __restrict__ mean_r, const float* __restrict__ mean_i,
    const float* __restrict__ stdv,
    const float* __restrict__ mags_r, const float* __restrict__ mags_i,
    const float* __restrict__ bias_r, const float* __restrict__ bias_i,
    const bf16* __restrict__ W1f, const bf16* __restrict__ W2f,
    const float* __restrict__ brelu_p,
    const float* __restrict__ glu_mags, const float* __restrict__ glu_phases,
    const int* __restrict__ rows, const int* __restrict__ cols,
    const int* __restrict__ rs8,
    int T, int T128, int T8cap)
{
    __shared__ __align__(16) char smemA[32 * 264 * 2];   // 16,896 B
    __shared__ __align__(16) char smemB[32 * 264 * 2];
    bf16*  H1 = (bf16*)smemA;    // [32][264] hi/lo split input
    float* aL = (float*)smemA;   // [32][132] GEMM1 result
    float* cL = (float*)smemA;   // [32][132] GEMM2 result
    bf16*  H2 = (bf16*)smemB;    // [32][264] gelu output

    const int tid = threadIdx.x;
    const int b = blockIdx.y;
    const int t0 = blockIdx.x * 32;
    const int tl = tid & 31;
    const int cg = tid >> 5;          // 0..7
    const int t = t0 + tl;
    const bool valid = (t < T);
    const int lane = tid & 63;
    const int wv = tid >> 6;          // 0..3
    const int frow = lane & 15;
    const int fcol = (lane >> 4) * 8;
    const s16x8* W1v = (const s16x8*)W1f;
    const s16x8* W2v = (const s16x8*)W2f;
    constexpr int ASRC[6] = {0, 1, 2, 3, 0, 1};
    constexpr int BSRC[6] = {0, 1, 0, 1, 2, 3};

    // ---- phase 1: normalize -> H1 (lane=t, coalesced global reads)
    {
        float mr = 0.f, mi_ = 0.f, isd = 0.f;
        if (valid) { mr = mean_r[t]; mi_ = mean_i[t]; isd = 1.0f / (1e-12f + stdv[t]); }
        s16x8 vhr, vhi, vlr, vli;
#pragma unroll
        for (int ci = 0; ci < 8; ++ci) {
            int c = cg * 8 + ci;
            float xr = 0.f, xi = 0.f;
            if (valid) {
                xr = Xcr[(size_t)(b * 64 + c) * T128 + t];
                xi = Xci[(size_t)(b * 64 + c) * T128 + t];
            }
            float hr = (xr - mr) * isd;
            float hi = (xi - mi_) * isd;
            float h1r = fmaf(hr, mags_r[c], fmaf(-hi, mags_i[c], bias_r[c]));
            float h1i = fmaf(hr, mags_i[c], fmaf(hi, mags_r[c], bias_i[c]));
            short rh = f2bfs(h1r), ih = f2bfs(h1i);
            vhr[ci] = rh; vhi[ci] = ih;
            vlr[ci] = f2bfs(h1r - bfs2f(rh));
            vli[ci] = f2bfs(h1i - bfs2f(ih));
        }
        *(s16x8*)&H1[tl * 264 + cg * 8]       = vhr;
        *(s16x8*)&H1[tl * 264 + 64 + cg * 8]  = vhi;
        *(s16x8*)&H1[tl * 264 + 128 + cg * 8] = vlr;
        *(s16x8*)&H1[tl * 264 + 192 + cg * 8] = vli;
    }
    __syncthreads();

    // ---- GEMM1: A = H1 [32][264], B frags direct from W1f (L2)
    f32x4 acc[2][2] = {};
#pragma unroll
    for (int lc = 0; lc < 6; ++lc) {
        const int ka = ASRC[lc] * 64;
        const int kb = BSRC[lc];
#pragma unroll
        for (int kh = 0; kh < 2; ++kh) {
            s16x8 a0 = *(const s16x8*)&H1[frow * 264 + ka + kh * 32 + fcol];
            s16x8 a1 = *(const s16x8*)&H1[(16 + frow) * 264 + ka + kh * 32 + fcol];
#pragma unroll
            for (int n = 0; n < 2; ++n) {
                s16x8 bfv = W1v[(size_t)((((wv * 2 + n) * 4 + kb) * 2 + kh) * 64 + lane)];
                acc[0][n] = __builtin_amdgcn_mfma_f32_16x16x32_bf16(a0, bfv, acc[0][n], 0, 0, 0);
                acc[1][n] = __builtin_amdgcn_mfma_f32_16x16x32_bf16(a1, bfv, acc[1][n], 0, 0, 0);
            }
        }
    }
    __syncthreads();

    // ---- phase 3: acc -> aL (overwrites H1)
    const int rbase = (lane >> 4) * 4;
    const int cidx = lane & 15;
#pragma unroll
    for (int m = 0; m < 2; ++m)
#pragma unroll
        for (int n = 0; n < 2; ++n)
#pragma unroll
            for (int r = 0; r < 4; ++r)
                aL[(m * 16 + rbase + r) * 132 + wv * 32 + n * 16 + cidx] = acc[m][n][r];
    __syncthreads();

    // ---- phase 4: gelu (lane=t) -> H2
    {
        const float brelu = brelu_p[0];
        f32x4 ar0 = *(const f32x4*)&aL[tl * 132 + cg * 8];
        f32x4 ar1 = *(const f32x4*)&aL[tl * 132 + cg * 8 + 4];
        f32x4 ai0 = *(const f32x4*)&aL[tl * 132 + 64 + cg * 8];
        f32x4 ai1 = *(const f32x4*)&aL[tl * 132 + 64 + cg * 8 + 4];
        s16x8 vhr, vhi, vlr, vli;
#pragma unroll
        for (int ci = 0; ci < 8; ++ci) {
            float ar = (ci < 4) ? ar0[ci & 3] : ar1[ci & 3];
            float ai = (ci < 4) ? ai0[ci & 3] : ai1[ci & 3];
            float r = sqrtf(ar * ar + ai * ai);
            float g = gelu_exact(r + brelu);
            float h2r, h2i;
            if (r > 0.f) { float f = g / r; h2r = f * ar; h2i = f * ai; }
            else { h2r = g; h2i = 0.f; }
            short rh = f2bfs(h2r), ih = f2bfs(h2i);
            vhr[ci] = rh; vhi[ci] = ih;
            vlr[ci] = f2bfs(h2r - bfs2f(rh));
            vli[ci] = f2bfs(h2i - bfs2f(ih));
        }
        *(s16x8*)&H2[tl * 264 + cg * 8]       = vhr;
        *(s16x8*)&H2[tl * 264 + 64 + cg * 8]  = vhi;
        *(s16x8*)&H2[tl * 264 + 128 + cg * 8] = vlr;
        *(s16x8*)&H2[tl * 264 + 192 + cg * 8] = vli;
    }
    __syncthreads();

    // ---- GEMM2: A = H2, B frags from W2f
    f32x4 acc2[2][2] = {};
#pragma unroll
    for (int lc = 0; lc < 6; ++lc) {
        const int ka = ASRC[lc] * 64;
        const int kb = BSRC[lc];
#pragma unroll
        for (int kh = 0; kh < 2; ++kh) {
            s16x8 a0 = *(const s16x8*)&H2[frow * 264 + ka + kh * 32 + fcol];
            s16x8 a1 = *(const s16x8*)&H2[(16 + frow) * 264 + ka + kh * 32 + fcol];
#pragma unroll
            for (int n = 0; n < 2; ++n) {
                s16x8 bfv = W2v[(size_t)((((wv * 2 + n) * 4 + kb) * 2 + kh) * 64 + lane)];
                acc2[0][n] = __builtin_amdgcn_mfma_f32_16x16x32_bf16(a0, bfv, acc2[0][n], 0, 0, 0);
                acc2[1][n] = __builtin_amdgcn_mfma_f32_16x16x32_bf16(a1, bfv, acc2[1][n], 0, 0, 0);
            }
        }
    }
    // cL aliases aL (smemA): all aL reads completed before the barrier above
    // GEMM2; no thread reads smemA during GEMM2.
#pragma unroll
    for (int m = 0; m < 2; ++m)
#pragma unroll
        for (int n = 0; n < 2; ++n)
#pragma unroll
            for (int r = 0; r < 4; ++r)
                cL[(m * 16 + rbase + r) * 132 + wv * 32 + n * 16 + cidx] = acc2[m][n][r];
    __syncthreads();

    // ---- phase 8: gate + compact coalesced store (lane=t)
    if (valid) {
        int h = rows[t], j = cols[t];
        size_t wbase = (size_t)rs8[h] + j;
        f32x4 cr0 = *(const f32x4*)&cL[tl * 132 + cg * 8];
        f32x4 cr1 = *(const f32x4*)&cL[tl * 132 + cg * 8 + 4];
        f32x4 ci0 = *(const f32x4*)&cL[tl * 132 + 64 + cg * 8];
        f32x4 ci1 = *(const f32x4*)&cL[tl * 132 + 64 + cg * 8 + 4];
#pragma unroll
        for (int ci = 0; ci < 8; ++ci) {
            int c = cg * 8 + ci;
            float cr  = (ci < 4) ? cr0[ci & 3] : cr1[ci & 3];
            float cii = (ci < 4) ? ci0[ci & 3] : ci1[ci & 3];
            float xr = Xcr[(size_t)(b * 64 + c) * T128 + t];
            float xi = Xci[(size_t)(b * 64 + c) * T128 + t];
            float r3 = sqrtf(cr * cr + cii * cii);
            float gm = glu_mags[(size_t)c * T + t];
            float gp = glu_phases[(size_t)c * T + t];
            float sg = 1.0f / (1.0f + expf(-(r3 + gm)));
            float ux, uy;
            if (r3 > 0.f) { float ir3 = 1.0f / r3; ux = cr * ir3; uy = cii * ir3; }
            else { ux = 1.f; uy = 0.f; }
            float sp, cp;
            sincosf(gp, &sp, &cp);
            float gx = sg * (ux * cp - uy * sp);
            float gy = sg * (ux * sp + uy * cp);
            size_t base = (size_t)(b * 64 + c) * T8cap + wbase;
            Xgr[base] = __float2bfloat16(xr * gx - xi * gy);
            Xgi[base] = __float2bfloat16(xr * gy + xi * gx);
        }
    }
}

// ------------------------- depthwise conv + add (float4 + XCD-chunk swizzle)
__global__ __launch_bounds__(256) void conv_add_kernel(
    const float* __restrict__ y, const float* __restrict__ dw,
    float* __restrict__ out)
{
    // grid covers Bb*Cc*Hh*180 float4 groups; nb divisible by 8 (32400).
    const int nb = gridDim.x;
    const int chunk = nb >> 3;
    const int orig = blockIdx.x;
    const int swz = (orig & 7) * chunk + (orig >> 3);   // bijective: nb % 8 == 0
    int g = swz * 256 + threadIdx.x;
    int w4 = g % 180;
    int rem = g / 180;
    int h = rem % Hh;
    int bc = rem / Hh;
    int c = bc & (Cc - 1);
    int w = w4 * 4;
    const float* yb = y + (size_t)bc * Hh * NI;
    int walt = (w >= Ww / 2) ? (w - Ww / 2) : (w + Ww / 2);
    float4 acc = *(const float4*)&yb[h * NI + w];
#pragma unroll
    for (int k = 0; k < 11; ++k) {
        int hp = h + k - 5;
        int hh, ww;
        if (hp < 0)        { hh = -1 - hp;         ww = walt; }
        else if (hp >= Hh) { hh = 2 * Hh - 1 - hp; ww = walt; }
        else               { hh = hp;              ww = w; }
        float4 v = *(const float4*)&yb[hh * NI + ww];
        float dwk = dw[c * 11 + k];
        acc.x = fmaf(dwk, v.x, acc.x);
        acc.y = fmaf(dwk, v.y, acc.y);
        acc.z = fmaf(dwk, v.z, acc.z);
        acc.w = fmaf(dwk, v.w, acc.w);
    }
    *(float4*)&out[((size_t)bc * Hh + h) * Ww + w] = acc;
}

// ------------------------------------------------------------------ launch
extern "C" void kernel_launch(void* const* d_in, const int* in_sizes, int n_in,
                              void* d_out, int out_size, void* d_ws, size_t ws_size,
                              hipStream_t stream)
{
    const float* x      = (const float*)d_in[0];
    const float* mean_r = (const float*)d_in[1];
    const float* mean_i = (const float*)d_in[2];
    const float* stdv   = (const float*)d_in[3];
    const float* mags_r = (const float*)d_in[4];
    const float* mags_i = (const float*)d_in[5];
    const float* bias_r = (const float*)d_in[6];
    const float* bias_i = (const float*)d_in[7];
    const float* w1_r   = (const float*)d_in[8];
    const float* w1_i   = (const float*)d_in[9];
    const float* brelu  = (const float*)d_in[10];
    const float* w2_r   = (const float*)d_in[11];
    const float* w2_i   = (const float*)d_in[12];
    const float* glu_m  = (const float*)d_in[13];
    const float* glu_p  = (const float*)d_in[14];
    const float* dw     = (const float*)d_in[15];
    const int*   rows   = (const int*)d_in[16];
    const int*   cols   = (const int*)d_in[17];
    const int T = in_sizes[16];
    const int T128 = ((T + 127) / 128) * 128;
    const int T8cap = ((T + 7 * Hh) + 127) & ~127;

    char* ws = (char*)d_ws;
    const size_t SApc  = (size_t)CM * KF3 * 2;            // 26,542,080
    const size_t XC_SZ = (size_t)BC * T128 * 4;           // ~42.6 MB
    const size_t XG_SZ = (size_t)BC * T8cap * 2;          // ~21.9 MB
    const size_t Y_SZ  = (size_t)Mrows * NI * 4;          // 141,557,760
    bf16*  Ap  = (bf16*)ws;
    bf16*  Aq  = (bf16*)(ws + SApc);
    float* Xcr = (float*)(ws + 2 * SApc);
    float* Xci = (float*)(ws + 2 * SApc + XC_SZ);
    float* y   = (float*)ws;
    size_t xc_end = 2 * SApc + 2 * XC_SZ;
    size_t xgoff  = (((Y_SZ > xc_end) ? Y_SZ : xc_end) + 255) & ~(size_t)255;
    bf16*  Xgr = (bf16*)(ws + xgoff);
    bf16*  Xgi = (bf16*)(ws + xgoff + XG_SZ);
    size_t boff = xgoff + 2 * XG_SZ;
    bf16*  Bce = (bf16*)(ws + boff);
    bf16*  Bse = (bf16*)(ws + boff + (size_t)NF * KF3 * 2);
    bf16*  Bti = (bf16*)(ws + boff + 2 * (size_t)NF * KF3 * 2);
    bf16*  W1f = (bf16*)(ws + boff + 2 * (size_t)NF * KF3 * 2 + (size_t)NI * KI * 2);
    bf16*  W2f = W1f + 32768;
    int*   rs  = (int*)(W2f + 32768);
    int*   rs8 = rs + (Hh + 2);

    build_bfwd_kernel<<<(NF * KF3 + 255) / 256, 256, 0, stream>>>(Bce, Bse);
    build_binv_kernel<<<(NI * KI + 255) / 256, 256, 0, stream>>>(Bti);
    build_wf_kernel<<<(2 * 32768 + 255) / 256, 256, 0, stream>>>(
        w1_r, w1_i, w2_r, w2_i, W1f, W2f);
    row_starts_kernel<<<1, 512, 0, stream>>>(rows, T, rs, rs8);

    for (int ch = 0; ch < CHUNKS; ++ch) {
        pack_kernel<<<(CM * KF3 + 255) / 256, 256, 0, stream>>>(
            x + (size_t)ch * CM * Ww, Ap, Aq);
        gemm_fwd_compact_kernel<<<dim3(CM / 128, NF / 128, 2), 256, 0, stream>>>(
            Ap, Aq, Bce, Bse, Xcr, Xci, rs, T128, ch * CM);
    }

    fill_zero_kernel<<<2048, 256, 0, stream>>>((uint4*)Xgr, (long)(2 * XG_SZ / 16));

    const int nT32 = (T + 31) / 32;
    middle_fused_kernel<<<dim3(nT32, Bb), 256, 0, stream>>>(
        Xcr, Xci, Xgr, Xgi, mean_r, mean_i, stdv, mags_r, mags_i,
        bias_r, bias_i, W1f, W2f, brelu, glu_m, glu_p, rows, cols, rs8,
        T, T128, T8cap);

    gemm_inv_kernel<<<dim3(Mrows / 128, NI / 128), 256, 0, stream>>>(
        Xgr, Xgi, Bti, rs8, y, T8cap);

    // Bb*Cc*Hh*180 float4 groups / 256 = 32,400 blocks (divisible by 8)
    conv_add_kernel<<<(Bb * Cc * Hh * 180) / 256, 256, 0, stream>>>(y, dw, (float*)d_out);
}

// Round 13
// 680.370 us; speedup vs baseline: 1.6532x; 1.0759x over previous
//
#include <hip/hip_runtime.h>
#include <hip/hip_bf16.h>
#include <math.h>

#define Hh 360
#define Ww 720
#define Cc 64
#define Bb 2
#define BC (Bb*Cc)        // 128
#define Mrows (BC*Hh)     // 46080
#define CHUNKS 2
#define CM (Mrows/CHUNKS) // 23040
#define KF3 1152          // fwd K: [hi|lo|hi] blocks of 384
#define NF 384            // fwd N (361 bins padded)
#define KI 768            // inv K: [Re(384) | Im(384)]
#define NI 768            // inv C row stride (720 used)
#define NSTORE_INV 720
#define SCALE 0.037267799624996496f   // 1/sqrt(720)
#define TWO_PI 6.2831853071795864769f

typedef __attribute__((ext_vector_type(8))) short s16x8;
typedef __attribute__((ext_vector_type(4))) float f32x4;
typedef __hip_bfloat16 bf16;

__device__ __forceinline__ void gload_lds16(const void* g, void* l) {
    __builtin_amdgcn_global_load_lds(
        (const __attribute__((address_space(1))) unsigned int*)g,
        (__attribute__((address_space(3))) unsigned int*)l, 16, 0, 0);
}
__device__ __forceinline__ short f2bfs(float v) {
    bf16 h = __float2bfloat16(v); short s; __builtin_memcpy(&s, &h, 2); return s;
}
__device__ __forceinline__ float bfs2f(short s) {
    bf16 h; __builtin_memcpy(&h, &s, 2); return __bfloat162float(h);
}

// ---------------------------------------------------------- B-matrix builds
__global__ __launch_bounds__(256) void build_bfwd_kernel(bf16* __restrict__ Bc,
                                                         bf16* __restrict__ Bs) {
    int g = blockIdx.x * 256 + threadIdx.x;
    if (g >= NF * KF3) return;
    int wext = g % KF3;
    int j = g / KF3;
    int blk = wext / 384;
    int w = wext - blk * 384;
    float c = 0.f, s = 0.f;
    if (w <= 360 && j <= 360) {
        int idx = (j * w) % Ww;
        float a = (TWO_PI / Ww) * (float)idx;
        float sv, cv;
        sincosf(a, &sv, &cv);
        c = SCALE * cv;
        s = -SCALE * sv;
    }
    bf16 chi = __float2bfloat16(c);
    bf16 shi = __float2bfloat16(s);
    if (blk == 2) {
        Bc[g] = __float2bfloat16(c - __bfloat162float(chi));
        Bs[g] = __float2bfloat16(s - __bfloat162float(shi));
    } else {
        Bc[g] = chi;
        Bs[g] = shi;
    }
}

__global__ __launch_bounds__(256) void build_binv_kernel(bf16* __restrict__ Bi) {
    int g = blockIdx.x * 256 + threadIdx.x;
    if (g >= NI * KI) return;
    int k = g % KI, n = g / KI;
    float v = 0.f;
    if (n < NSTORE_INV) {
        if (k <= 360) {
            int j = k;
            float f = (j == 0 || j == 360) ? 1.f : 2.f;
            int idx = (j * n) % Ww;
            v = SCALE * f * cosf((TWO_PI / Ww) * (float)idx);
        } else if (k >= 384 && k <= 744) {
            int j = k - 384;
            int idx = (j * n) % Ww;
            v = -2.f * SCALE * sinf((TWO_PI / Ww) * (float)idx);
        }
    }
    Bi[g] = __float2bfloat16(v);
}

// W fragment-packed: s16x8 index = fid*64 + lane, fid = ((n16*4 + kb)*2 + kh).
__global__ __launch_bounds__(256) void build_wf_kernel(
    const float* __restrict__ w1_r, const float* __restrict__ w1_i,
    const float* __restrict__ w2_r, const float* __restrict__ w2_i,
    bf16* __restrict__ W1f, bf16* __restrict__ W2f)
{
    int g = blockIdx.x * 256 + threadIdx.x;
    if (g >= 2 * 32768) return;
    int which = g >> 15;
    int gg = g & 32767;
    int e = gg & 7, lane = (gg >> 3) & 63, kh = (gg >> 9) & 1;
    int kb = (gg >> 10) & 3, n16 = (gg >> 12) & 7;
    int frow = lane & 15, fcol = (lane >> 4) * 8;
    int n = n16 * 16 + frow;
    int kfull = kb * 64 + kh * 32 + fcol + e;
    int kk = kfull & 127, islo = kfull >> 7;
    const float* wr = which ? w2_r : w1_r;
    const float* wi = which ? w2_i : w1_i;
    float v;
    if (n < 64) v = (kk < 64) ? wr[n * 64 + kk] : -wi[n * 64 + kk - 64];
    else { int p = n - 64; v = (kk < 64) ? wi[p * 64 + kk] : wr[p * 64 + kk - 64]; }
    bf16 h = __float2bfloat16(v);
    bf16 out = islo ? __float2bfloat16(v - __bfloat162float(h)) : h;
    (which ? W2f : W1f)[gg] = out;
}

// ---------------------------------------- row starts (compact + 8-padded)
__global__ __launch_bounds__(512) void row_starts_kernel(const int* __restrict__ rows,
                                                         int T, int* __restrict__ rs,
                                                         int* __restrict__ rs8) {
    int h = threadIdx.x;
    if (h <= Hh) {
        if (h == Hh) rs[Hh] = T;
        else {
            int lo = 0, hi = T;
            while (lo < hi) {
                int mid = (lo + hi) >> 1;
                if (rows[mid] < h) lo = mid + 1; else hi = mid;
            }
            rs[h] = lo;
        }
    }
    __syncthreads();
    if (threadIdx.x == 0) {
        int acc = 0;
        for (int i = 0; i < Hh; ++i) {
            rs8[i] = acc;
            int cnt = rs[i + 1] - rs[i];
            acc += (cnt + 7) & ~7;
        }
        rs8[Hh] = acc;
    }
}

// --------------------------------------------- pack x chunk -> A_ext (p,q)
// A row layout: [0:384)=hi, [384:768)=lo, [768:1152)=hi.
__global__ __launch_bounds__(256) void pack_kernel(const float* __restrict__ x,
                                                   bf16* __restrict__ Ap,
                                                   bf16* __restrict__ Aq) {
    int g = blockIdx.x * 256 + threadIdx.x;
    if (g >= CM * KF3) return;
    int wext = g % KF3;
    int row = g / KF3;
    int blk = wext / 384;
    int w = wext - blk * 384;
    float p = 0.f, q = 0.f;
    if (w == 0 || w == 360) {
        p = x[(size_t)row * Ww + w];
    } else if (w < 360) {
        float a = x[(size_t)row * Ww + w];
        float b = x[(size_t)row * Ww + (Ww - w)];
        p = a + b;
        q = a - b;
    }
    bf16 phi = __float2bfloat16(p);
    bf16 qhi = __float2bfloat16(q);
    if (blk == 1) {
        Ap[g] = __float2bfloat16(p - __bfloat162float(phi));
        Aq[g] = __float2bfloat16(q - __bfloat162float(qhi));
    } else {
        Ap[g] = phi;
        Aq[g] = qhi;
    }
}

// ----------------------------------------------------------------- zero fill
__global__ __launch_bounds__(256) void fill_zero_kernel(uint4* __restrict__ p, long n) {
    long i = (long)blockIdx.x * 256 + threadIdx.x;
    long stride = (long)gridDim.x * 256;
    uint4 z = make_uint4(0u, 0u, 0u, 0u);
    for (; i < n; i += stride) p[i] = z;
}

// ------------------------------------------- fwd MFMA GEMM, compact epilogue
__global__ __launch_bounds__(256) void gemm_fwd_compact_kernel(
    const bf16* __restrict__ Ap, const bf16* __restrict__ Aq,
    const bf16* __restrict__ Bc, const bf16* __restrict__ Bsm,
    float* __restrict__ Xcr, float* __restrict__ Xci,
    const int* __restrict__ rs, int T128, int mbase)
{
    __shared__ __align__(128) bf16 As[128][64];
    __shared__ __align__(128) bf16 Bs[128][64];
    const bf16* A  = blockIdx.z ? Aq : Ap;
    const bf16* Bt = blockIdx.z ? Bsm : Bc;
    float* Xc      = blockIdx.z ? Xci : Xcr;
    const int tid = threadIdx.x;
    const int lane = tid & 63;
    const int wave = tid >> 6;
    const int m0 = blockIdx.x * 128;
    const int n0 = blockIdx.y * 128;
    const int wr = (wave >> 1) * 64;
    const int wc = (wave & 1) * 64;
    const int srow = tid >> 3;
    const int scol = (tid & 7) << 3;
    f32x4 acc[4][4] = {};
    for (int k0 = 0; k0 < KF3; k0 += 64) {
#pragma unroll
        for (int i = 0; i < 4; ++i) {
            const bf16* ga = A  + (size_t)(m0 + i * 32 + srow) * KF3 + k0 + scol;
            const bf16* gb = Bt + (size_t)(n0 + i * 32 + srow) * KF3 + k0 + scol;
            gload_lds16(ga, ((char*)&As[0][0]) + (size_t)(i * 256 + tid) * 16);
            gload_lds16(gb, ((char*)&Bs[0][0]) + (size_t)(i * 256 + tid) * 16);
        }
        __syncthreads();
#pragma unroll
        for (int kk = 0; kk < 64; kk += 32) {
            s16x8 a[4], b[4];
#pragma unroll
            for (int m = 0; m < 4; ++m)
                a[m] = *(const s16x8*)&As[wr + m * 16 + (lane & 15)][kk + (lane >> 4) * 8];
#pragma unroll
            for (int n = 0; n < 4; ++n)
                b[n] = *(const s16x8*)&Bs[wc + n * 16 + (lane & 15)][kk + (lane >> 4) * 8];
#pragma unroll
            for (int m = 0; m < 4; ++m)
#pragma unroll
                for (int n = 0; n < 4; ++n)
                    acc[m][n] = __builtin_amdgcn_mfma_f32_16x16x32_bf16(a[m], b[n], acc[m][n], 0, 0, 0);
        }
        __syncthreads();
    }
    const int rbase = (lane >> 4) * 4;
    const int cidx = lane & 15;
#pragma unroll
    for (int m = 0; m < 4; ++m) {
#pragma unroll
        for (int r = 0; r < 4; ++r) {
            int grow = mbase + m0 + wr + m * 16 + rbase + r;
            int bc = grow / Hh;
            int h = grow - bc * Hh;
            int t0 = rs[h];
            int cnt = rs[h + 1] - t0;
#pragma unroll
            for (int n = 0; n < 4; ++n) {
                int j = n0 + wc + n * 16 + cidx;
                if (j < cnt)
                    Xc[(size_t)bc * T128 + t0 + j] = acc[m][n][r];
            }
        }
    }
}

// --------------------------------- inverse GEMM from compact gated spectrum
__global__ __launch_bounds__(256) void gemm_inv_kernel(
    const bf16* __restrict__ Xgr, const bf16* __restrict__ Xgi,
    const bf16* __restrict__ Bt, const int* __restrict__ rs8,
    float* __restrict__ C, int T8cap)
{
    __shared__ __align__(128) bf16 As[128][64];
    __shared__ __align__(128) bf16 Bs[128][64];
    __shared__ int rsL[Hh + 1];
    const int tid = threadIdx.x;
    for (int i = tid; i <= Hh; i += 256) rsL[i] = rs8[i];
    const int lane = tid & 63;
    const int wave = tid >> 6;
    const int m0 = blockIdx.x * 128;
    const int n0 = blockIdx.y * 128;
    const int wr = (wave >> 1) * 64;
    const int wc = (wave & 1) * 64;
    const int srow = tid >> 3;
    const int scol = (tid & 7) << 3;
    __syncthreads();
    f32x4 acc[4][4] = {};
    for (int k0 = 0; k0 < KI; k0 += 64) {
#pragma unroll
        for (int i = 0; i < 4; ++i)
            gload_lds16(Bt + (size_t)(n0 + i * 32 + srow) * KI + k0 + scol,
                        ((char*)&Bs[0][0]) + (size_t)(i * 256 + tid) * 16);
        {
            int k = k0 + scol;
            int j0 = (k < 384) ? k : k - 384;
            const bf16* base = (k < 384) ? Xgr : Xgi;
#pragma unroll
            for (int i = 0; i < 4; ++i) {
                int grow = m0 + i * 32 + srow;
                int bc = grow / Hh;
                int h = grow - bc * Hh;
                int t0v = rsL[h];
                int cnt8 = rsL[h + 1] - t0v;
                s16x8 v = (s16x8){0, 0, 0, 0, 0, 0, 0, 0};
                if (j0 < cnt8)
                    v = *(const s16x8*)(base + (size_t)bc * T8cap + t0v + j0);
                *(s16x8*)&As[i * 32 + srow][scol] = v;
            }
        }
        __syncthreads();
#pragma unroll
        for (int kk = 0; kk < 64; kk += 32) {
            s16x8 a[4], b[4];
#pragma unroll
            for (int m = 0; m < 4; ++m)
                a[m] = *(const s16x8*)&As[wr + m * 16 + (lane & 15)][kk + (lane >> 4) * 8];
#pragma unroll
            for (int n = 0; n < 4; ++n)
                b[n] = *(const s16x8*)&Bs[wc + n * 16 + (lane & 15)][kk + (lane >> 4) * 8];
#pragma unroll
            for (int m = 0; m < 4; ++m)
#pragma unroll
                for (int n = 0; n < 4; ++n)
                    acc[m][n] = __builtin_amdgcn_mfma_f32_16x16x32_bf16(a[m], b[n], acc[m][n], 0, 0, 0);
        }
        __syncthreads();
    }
    const int rbase = (lane >> 4) * 4;
    const int cidx = lane & 15;
#pragma unroll
    for (int m = 0; m < 4; ++m) {
#pragma unroll
        for (int n = 0; n < 4; ++n) {
            int gcol = n0 + wc + n * 16 + cidx;
            if (gcol < NSTORE_INV) {
#pragma unroll
                for (int r = 0; r < 4; ++r) {
                    int grow = m0 + wr + m * 16 + rbase + r;
                    C[(size_t)grow * NI + gcol] = acc[m][n][r];
                }
            }
        }
    }
}

// ------------------------------------------------ fused middle stage (v3)
// VERBATIM green round-10 middle (no register cache, libm exp/sincos).
__device__ __forceinline__ float gelu_exact(float v) {
    return 0.5f * v * (1.0f + erff(v * 0.7071067811865476f));
}

__global__ __launch_bounds__(256, 4) void middle_fused_kernel(
    const float* __restrict__ Xcr, const float* __restrict__ Xci,
    bf16* __restrict__ Xgr, bf16* __restrict__ Xgi,
    const float* __restrict__ mean_r, const float* __restrict__ mean_i,
    const float* __restrict__ stdv,
    const float* __restrict__ mags_r, const float* __restrict__ mags_i,
    const float* __restrict__ bias_r, const float* __restrict__ bias_i,
    const bf16* __restrict__ W1f, const bf16* __restrict__ W2f,
    const float* __restrict__ brelu_p,
    const float* __restrict__ glu_mags, const float* __restrict__ glu_phases,
    const int* __restrict__ rows, const int* __restrict__ cols,
    const int* __restrict__ rs8,
    int T, int T128, int T8cap)
{
    __shared__ __align__(16) char smemA[32 * 264 * 2];   // 16,896 B
    __shared__ __align__(16) char smemB[32 * 264 * 2];
    bf16*  H1 = (bf16*)smemA;    // [32][264] hi/lo split input
    float* aL = (float*)smemA;   // [32][132] GEMM1 result
    float* cL = (float*)smemA;   // [32][132] GEMM2 result
    bf16*  H2 = (bf16*)smemB;    // [32][264] gelu output

    const int tid = threadIdx.x;
    const int b = blockIdx.y;
    const int t0 = blockIdx.x * 32;
    const int tl = tid & 31;
    const int cg = tid >> 5;          // 0..7
    const int t = t0 + tl;
    const bool valid = (t < T);
    const int lane = tid & 63;
    const int wv = tid >> 6;          // 0..3
    const int frow = lane & 15;
    const int fcol = (lane >> 4) * 8;
    const s16x8* W1v = (const s16x8*)W1f;
    const s16x8* W2v = (const s16x8*)W2f;
    constexpr int ASRC[6] = {0, 1, 2, 3, 0, 1};
    constexpr int BSRC[6] = {0, 1, 0, 1, 2, 3};

    // ---- phase 1: normalize -> H1 (lane=t, coalesced global reads)
    {
        float mr = 0.f, mi_ = 0.f, isd = 0.f;
        if (valid) { mr = mean_r[t]; mi_ = mean_i[t]; isd = 1.0f / (1e-12f + stdv[t]); }
        s16x8 vhr, vhi, vlr, vli;
#pragma unroll
        for (int ci = 0; ci < 8; ++ci) {
            int c = cg * 8 + ci;
            float xr = 0.f, xi = 0.f;
            if (valid) {
                xr = Xcr[(size_t)(b * 64 + c) * T128 + t];
                xi = Xci[(size_t)(b * 64 + c) * T128 + t];
            }
            float hr = (xr - mr) * isd;
            float hi = (xi - mi_) * isd;
            float h1r = fmaf(hr, mags_r[c], fmaf(-hi, mags_i[c], bias_r[c]));
            float h1i = fmaf(hr, mags_i[c], fmaf(hi, mags_r[c], bias_i[c]));
            short rh = f2bfs(h1r), ih = f2bfs(h1i);
            vhr[ci] = rh; vhi[ci] = ih;
            vlr[ci] = f2bfs(h1r - bfs2f(rh));
            vli[ci] = f2bfs(h1i - bfs2f(ih));
        }
        *(s16x8*)&H1[tl * 264 + cg * 8]       = vhr;
        *(s16x8*)&H1[tl * 264 + 64 + cg * 8]  = vhi;
        *(s16x8*)&H1[tl * 264 + 128 + cg * 8] = vlr;
        *(s16x8*)&H1[tl * 264 + 192 + cg * 8] = vli;
    }
    __syncthreads();

    // ---- GEMM1: A = H1 [32][264], B frags direct from W1f (L2)
    f32x4 acc[2][2] = {};
#pragma unroll
    for (int lc = 0; lc < 6; ++lc) {
        const int ka = ASRC[lc] * 64;
        const int kb = BSRC[lc];
#pragma unroll
        for (int kh = 0; kh < 2; ++kh) {
            s16x8 a0 = *(const s16x8*)&H1[frow * 264 + ka + kh * 32 + fcol];
            s16x8 a1 = *(const s16x8*)&H1[(16 + frow) * 264 + ka + kh * 32 + fcol];
#pragma unroll
            for (int n = 0; n < 2; ++n) {
                s16x8 bfv = W1v[(size_t)((((wv * 2 + n) * 4 + kb) * 2 + kh) * 64 + lane)];
                acc[0][n] = __builtin_amdgcn_mfma_f32_16x16x32_bf16(a0, bfv, acc[0][n], 0, 0, 0);
                acc[1][n] = __builtin_amdgcn_mfma_f32_16x16x32_bf16(a1, bfv, acc[1][n], 0, 0, 0);
            }
        }
    }
    __syncthreads();

    // ---- phase 3: acc -> aL (overwrites H1)
    const int rbase = (lane >> 4) * 4;
    const int cidx = lane & 15;
#pragma unroll
    for (int m = 0; m < 2; ++m)
#pragma unroll
        for (int n = 0; n < 2; ++n)
#pragma unroll
            for (int r = 0; r < 4; ++r)
                aL[(m * 16 + rbase + r) * 132 + wv * 32 + n * 16 + cidx] = acc[m][n][r];
    __syncthreads();

    // ---- phase 4: gelu (lane=t) -> H2
    {
        const float brelu = brelu_p[0];
        f32x4 ar0 = *(const f32x4*)&aL[tl * 132 + cg * 8];
        f32x4 ar1 = *(const f32x4*)&aL[tl * 132 + cg * 8 + 4];
        f32x4 ai0 = *(const f32x4*)&aL[tl * 132 + 64 + cg * 8];
        f32x4 ai1 = *(const f32x4*)&aL[tl * 132 + 64 + cg * 8 + 4];
        s16x8 vhr, vhi, vlr, vli;
#pragma unroll
        for (int ci = 0; ci < 8; ++ci) {
            float ar = (ci < 4) ? ar0[ci & 3] : ar1[ci & 3];
            float ai = (ci < 4) ? ai0[ci & 3] : ai1[ci & 3];
            float r = sqrtf(ar * ar + ai * ai);
            float g = gelu_exact(r + brelu);
            float h2r, h2i;
            if (r > 0.f) { float f = g / r; h2r = f * ar; h2i = f * ai; }
            else { h2r = g; h2i = 0.f; }
            short rh = f2bfs(h2r), ih = f2bfs(h2i);
            vhr[ci] = rh; vhi[ci] = ih;
            vlr[ci] = f2bfs(h2r - bfs2f(rh));
            vli[ci] = f2bfs(h2i - bfs2f(ih));
        }
        *(s16x8*)&H2[tl * 264 + cg * 8]       = vhr;
        *(s16x8*)&H2[tl * 264 + 64 + cg * 8]  = vhi;
        *(s16x8*)&H2[tl * 264 + 128 + cg * 8] = vlr;
        *(s16x8*)&H2[tl * 264 + 192 + cg * 8] = vli;
    }
    __syncthreads();

    // ---- GEMM2: A = H2, B frags from W2f
    f32x4 acc2[2][2] = {};
#pragma unroll
    for (int lc = 0; lc < 6; ++lc) {
        const int ka = ASRC[lc] * 64;
        const int kb = BSRC[lc];
#pragma unroll
        for (int kh = 0; kh < 2; ++kh) {
            s16x8 a0 = *(const s16x8*)&H2[frow * 264 + ka + kh * 32 + fcol];
            s16x8 a1 = *(const s16x8*)&H2[(16 + frow) * 264 + ka + kh * 32 + fcol];
#pragma unroll
            for (int n = 0; n < 2; ++n) {
                s16x8 bfv = W2v[(size_t)((((wv * 2 + n) * 4 + kb) * 2 + kh) * 64 + lane)];
                acc2[0][n] = __builtin_amdgcn_mfma_f32_16x16x32_bf16(a0, bfv, acc2[0][n], 0, 0, 0);
                acc2[1][n] = __builtin_amdgcn_mfma_f32_16x16x32_bf16(a1, bfv, acc2[1][n], 0, 0, 0);
            }
        }
    }
    // cL aliases aL (smemA): all aL reads completed before the barrier above
    // GEMM2; no thread reads smemA during GEMM2.
#pragma unroll
    for (int m = 0; m < 2; ++m)
#pragma unroll
        for (int n = 0; n < 2; ++n)
#pragma unroll
            for (int r = 0; r < 4; ++r)
                cL[(m * 16 + rbase + r) * 132 + wv * 32 + n * 16 + cidx] = acc2[m][n][r];
    __syncthreads();

    // ---- phase 8: gate + compact coalesced store (lane=t)
    if (valid) {
        int h = rows[t], j = cols[t];
        size_t wbase = (size_t)rs8[h] + j;
        f32x4 cr0 = *(const f32x4*)&cL[tl * 132 + cg * 8];
        f32x4 cr1 = *(const f32x4*)&cL[tl * 132 + cg * 8 + 4];
        f32x4 ci0 = *(const f32x4*)&cL[tl * 132 + 64 + cg * 8];
        f32x4 ci1 = *(const f32x4*)&cL[tl * 132 + 64 + cg * 8 + 4];
#pragma unroll
        for (int ci = 0; ci < 8; ++ci) {
            int c = cg * 8 + ci;
            float cr  = (ci < 4) ? cr0[ci & 3] : cr1[ci & 3];
            float cii = (ci < 4) ? ci0[ci & 3] : ci1[ci & 3];
            float xr = Xcr[(size_t)(b * 64 + c) * T128 + t];
            float xi = Xci[(size_t)(b * 64 + c) * T128 + t];
            float r3 = sqrtf(cr * cr + cii * cii);
            float gm = glu_mags[(size_t)c * T + t];
            float gp = glu_phases[(size_t)c * T + t];
            float sg = 1.0f / (1.0f + expf(-(r3 + gm)));
            float ux, uy;
            if (r3 > 0.f) { float ir3 = 1.0f / r3; ux = cr * ir3; uy = cii * ir3; }
            else { ux = 1.f; uy = 0.f; }
            float sp, cp;
            sincosf(gp, &sp, &cp);
            float gx = sg * (ux * cp - uy * sp);
            float gy = sg * (ux * sp + uy * cp);
            size_t base = (size_t)(b * 64 + c) * T8cap + wbase;
            Xgr[base] = __float2bfloat16(xr * gx - xi * gy);
            Xgi[base] = __float2bfloat16(xr * gy + xi * gx);
        }
    }
}

// ------------------------- depthwise conv + add (float4 + XCD-chunk swizzle)
__global__ __launch_bounds__(256) void conv_add_kernel(
    const float* __restrict__ y, const float* __restrict__ dw,
    float* __restrict__ out)
{
    const int nb = gridDim.x;
    const int chunk = nb >> 3;
    const int orig = blockIdx.x;
    const int swz = (orig & 7) * chunk + (orig >> 3);   // bijective: nb % 8 == 0
    int g = swz * 256 + threadIdx.x;
    int w4 = g % 180;
    int rem = g / 180;
    int h = rem % Hh;
    int bc = rem / Hh;
    int c = bc & (Cc - 1);
    int w = w4 * 4;
    const float* yb = y + (size_t)bc * Hh * NI;
    int walt = (w >= Ww / 2) ? (w - Ww / 2) : (w + Ww / 2);
    float4 acc = *(const float4*)&yb[h * NI + w];
#pragma unroll
    for (int k = 0; k < 11; ++k) {
        int hp = h + k - 5;
        int hh, ww;
        if (hp < 0)        { hh = -1 - hp;         ww = walt; }
        else if (hp >= Hh) { hh = 2 * Hh - 1 - hp; ww = walt; }
        else               { hh = hp;              ww = w; }
        float4 v = *(const float4*)&yb[hh * NI + ww];
        float dwk = dw[c * 11 + k];
        acc.x = fmaf(dwk, v.x, acc.x);
        acc.y = fmaf(dwk, v.y, acc.y);
        acc.z = fmaf(dwk, v.z, acc.z);
        acc.w = fmaf(dwk, v.w, acc.w);
    }
    *(float4*)&out[((size_t)bc * Hh + h) * Ww + w] = acc;
}

// ------------------------------------------------------------------ launch
extern "C" void kernel_launch(void* const* d_in, const int* in_sizes, int n_in,
                              void* d_out, int out_size, void* d_ws, size_t ws_size,
                              hipStream_t stream)
{
    const float* x      = (const float*)d_in[0];
    const float* mean_r = (const float*)d_in[1];
    const float* mean_i = (const float*)d_in[2];
    const float* stdv   = (const float*)d_in[3];
    const float* mags_r = (const float*)d_in[4];
    const float* mags_i = (const float*)d_in[5];
    const float* bias_r = (const float*)d_in[6];
    const float* bias_i = (const float*)d_in[7];
    const float* w1_r   = (const float*)d_in[8];
    const float* w1_i   = (const float*)d_in[9];
    const float* brelu  = (const float*)d_in[10];
    const float* w2_r   = (const float*)d_in[11];
    const float* w2_i   = (const float*)d_in[12];
    const float* glu_m  = (const float*)d_in[13];
    const float* glu_p  = (const float*)d_in[14];
    const float* dw     = (const float*)d_in[15];
    const int*   rows   = (const int*)d_in[16];
    const int*   cols   = (const int*)d_in[17];
    const int T = in_sizes[16];
    const int T128 = ((T + 127) / 128) * 128;
    const int T8cap = ((T + 7 * Hh) + 127) & ~127;

    char* ws = (char*)d_ws;
    const size_t SApc  = (size_t)CM * KF3 * 2;            // 53,084,160
    const size_t XC_SZ = (size_t)BC * T128 * 4;           // ~42.7 MB
    const size_t XG_SZ = (size_t)BC * T8cap * 2;          // ~22.0 MB
    const size_t Y_SZ  = (size_t)Mrows * NI * 4;          // 141,557,760
    // Lifetimes (stream-ordered):
    //   fwd:    Ap/Aq [0, 2*SApc)  write Xcr/Xci [2*SApc, 2*SApc+2*XC)
    //   fill:   Xg [0, 2*XG)            (Ap/Aq dead)
    //   middle: read Xc, write Xg       (disjoint)
    //   inv:    read Xg, write y [2*XG, 2*XG+Y)   (Xc dead; y disjoint from Xg)
    //   conv:   read y
    //   builds at [2*SApc+2*XC, ...)    (above everything, ~191.5M..194.6M)
    bf16*  Ap  = (bf16*)ws;
    bf16*  Aq  = (bf16*)(ws + SApc);
    float* Xcr = (float*)(ws + 2 * SApc);
    float* Xci = (float*)(ws + 2 * SApc + XC_SZ);
    bf16*  Xgr = (bf16*)ws;
    bf16*  Xgi = (bf16*)(ws + XG_SZ);
    float* y   = (float*)(ws + 2 * XG_SZ);
    size_t boff = 2 * SApc + 2 * XC_SZ;                   // ~191.5 MB
    bf16*  Bce = (bf16*)(ws + boff);
    bf16*  Bse = (bf16*)(ws + boff + (size_t)NF * KF3 * 2);
    bf16*  Bti = (bf16*)(ws + boff + 2 * (size_t)NF * KF3 * 2);
    bf16*  W1f = (bf16*)(ws + boff + 2 * (size_t)NF * KF3 * 2 + (size_t)NI * KI * 2);
    bf16*  W2f = W1f + 32768;
    int*   rs  = (int*)(W2f + 32768);
    int*   rs8 = rs + (Hh + 2);

    build_bfwd_kernel<<<(NF * KF3 + 255) / 256, 256, 0, stream>>>(Bce, Bse);
    build_binv_kernel<<<(NI * KI + 255) / 256, 256, 0, stream>>>(Bti);
    build_wf_kernel<<<(2 * 32768 + 255) / 256, 256, 0, stream>>>(
        w1_r, w1_i, w2_r, w2_i, W1f, W2f);
    row_starts_kernel<<<1, 512, 0, stream>>>(rows, T, rs, rs8);

    for (int ch = 0; ch < CHUNKS; ++ch) {
        pack_kernel<<<(CM * KF3 + 255) / 256, 256, 0, stream>>>(
            x + (size_t)ch * CM * Ww, Ap, Aq);
        gemm_fwd_compact_kernel<<<dim3(CM / 128, NF / 128, 2), 256, 0, stream>>>(
            Ap, Aq, Bce, Bse, Xcr, Xci, rs, T128, ch * CM);
    }

    fill_zero_kernel<<<2048, 256, 0, stream>>>((uint4*)Xgr, (long)(2 * XG_SZ / 16));

    const int nT32 = (T + 31) / 32;
    middle_fused_kernel<<<dim3(nT32, Bb), 256, 0, stream>>>(
        Xcr, Xci, Xgr, Xgi, mean_r, mean_i, stdv, mags_r, mags_i,
        bias_r, bias_i, W1f, W2f, brelu, glu_m, glu_p, rows, cols, rs8,
        T, T128, T8cap);

    gemm_inv_kernel<<<dim3(Mrows / 128, NI / 128), 256, 0, stream>>>(
        Xgr, Xgi, Bti, rs8, y, T8cap);

    conv_add_kernel<<<(Bb * Cc * Hh * 180) / 256, 256, 0, stream>>>(y, dw, (float*)d_out);
}

// Round 14
// 652.382 us; speedup vs baseline: 1.7241x; 1.0429x over previous
//
#include <hip/hip_runtime.h>
#include <hip/hip_bf16.h>
#include <math.h>

#define Hh 360
#define Ww 720
#define Cc 64
#define Bb 2
#define BC (Bb*Cc)        // 128
#define Mrows (BC*Hh)     // 46080
#define CHUNKS 2
#define CM (Mrows/CHUNKS) // 23040
#define KF3 1152          // fwd K: [hi|lo|hi] blocks of 384
#define NF 384            // fwd N (361 bins padded)
#define KI 768            // inv K: [Re(384) | Im(384)]
#define NI 768            // inv C row stride (720 used)
#define NSTORE_INV 720
#define SCALE 0.037267799624996496f   // 1/sqrt(720)
#define TWO_PI 6.2831853071795864769f

typedef __attribute__((ext_vector_type(8))) short s16x8;
typedef __attribute__((ext_vector_type(4))) float f32x4;
typedef __hip_bfloat16 bf16;

__device__ __forceinline__ void gload_lds16(const void* g, void* l) {
    __builtin_amdgcn_global_load_lds(
        (const __attribute__((address_space(1))) unsigned int*)g,
        (__attribute__((address_space(3))) unsigned int*)l, 16, 0, 0);
}
__device__ __forceinline__ short f2bfs(float v) {
    bf16 h = __float2bfloat16(v); short s; __builtin_memcpy(&s, &h, 2); return s;
}
__device__ __forceinline__ float bfs2f(short s) {
    bf16 h; __builtin_memcpy(&h, &s, 2); return __bfloat162float(h);
}

// ---------------------------------------------------------- B-matrix builds
__global__ __launch_bounds__(256) void build_bfwd_kernel(bf16* __restrict__ Bc,
                                                         bf16* __restrict__ Bs) {
    int g = blockIdx.x * 256 + threadIdx.x;
    if (g >= NF * KF3) return;
    int wext = g % KF3;
    int j = g / KF3;
    int blk = wext / 384;
    int w = wext - blk * 384;
    float c = 0.f, s = 0.f;
    if (w <= 360 && j <= 360) {
        int idx = (j * w) % Ww;
        float a = (TWO_PI / Ww) * (float)idx;
        float sv, cv;
        sincosf(a, &sv, &cv);
        c = SCALE * cv;
        s = -SCALE * sv;
    }
    bf16 chi = __float2bfloat16(c);
    bf16 shi = __float2bfloat16(s);
    if (blk == 2) {
        Bc[g] = __float2bfloat16(c - __bfloat162float(chi));
        Bs[g] = __float2bfloat16(s - __bfloat162float(shi));
    } else {
        Bc[g] = chi;
        Bs[g] = shi;
    }
}

__global__ __launch_bounds__(256) void build_binv_kernel(bf16* __restrict__ Bi) {
    int g = blockIdx.x * 256 + threadIdx.x;
    if (g >= NI * KI) return;
    int k = g % KI, n = g / KI;
    float v = 0.f;
    if (n < NSTORE_INV) {
        if (k <= 360) {
            int j = k;
            float f = (j == 0 || j == 360) ? 1.f : 2.f;
            int idx = (j * n) % Ww;
            v = SCALE * f * cosf((TWO_PI / Ww) * (float)idx);
        } else if (k >= 384 && k <= 744) {
            int j = k - 384;
            int idx = (j * n) % Ww;
            v = -2.f * SCALE * sinf((TWO_PI / Ww) * (float)idx);
        }
    }
    Bi[g] = __float2bfloat16(v);
}

// W fragment-packed: s16x8 index = fid*64 + lane, fid = ((n16*4 + kb)*2 + kh).
__global__ __launch_bounds__(256) void build_wf_kernel(
    const float* __restrict__ w1_r, const float* __restrict__ w1_i,
    const float* __restrict__ w2_r, const float* __restrict__ w2_i,
    bf16* __restrict__ W1f, bf16* __restrict__ W2f)
{
    int g = blockIdx.x * 256 + threadIdx.x;
    if (g >= 2 * 32768) return;
    int which = g >> 15;
    int gg = g & 32767;
    int e = gg & 7, lane = (gg >> 3) & 63, kh = (gg >> 9) & 1;
    int kb = (gg >> 10) & 3, n16 = (gg >> 12) & 7;
    int frow = lane & 15, fcol = (lane >> 4) * 8;
    int n = n16 * 16 + frow;
    int kfull = kb * 64 + kh * 32 + fcol + e;
    int kk = kfull & 127, islo = kfull >> 7;
    const float* wr = which ? w2_r : w1_r;
    const float* wi = which ? w2_i : w1_i;
    float v;
    if (n < 64) v = (kk < 64) ? wr[n * 64 + kk] : -wi[n * 64 + kk - 64];
    else { int p = n - 64; v = (kk < 64) ? wi[p * 64 + kk] : wr[p * 64 + kk - 64]; }
    bf16 h = __float2bfloat16(v);
    bf16 out = islo ? __float2bfloat16(v - __bfloat162float(h)) : h;
    (which ? W2f : W1f)[gg] = out;
}

// ---------------------------------------- row starts (compact + 8-padded)
__global__ __launch_bounds__(512) void row_starts_kernel(const int* __restrict__ rows,
                                                         int T, int* __restrict__ rs,
                                                         int* __restrict__ rs8) {
    int h = threadIdx.x;
    if (h <= Hh) {
        if (h == Hh) rs[Hh] = T;
        else {
            int lo = 0, hi = T;
            while (lo < hi) {
                int mid = (lo + hi) >> 1;
                if (rows[mid] < h) lo = mid + 1; else hi = mid;
            }
            rs[h] = lo;
        }
    }
    __syncthreads();
    if (threadIdx.x == 0) {
        int acc = 0;
        for (int i = 0; i < Hh; ++i) {
            rs8[i] = acc;
            int cnt = rs[i + 1] - rs[i];
            acc += (cnt + 7) & ~7;
        }
        rs8[Hh] = acc;
    }
}

// --------------------------------------------- pack x chunk -> A_ext (p,q)
// A row layout: [0:384)=hi, [384:768)=lo, [768:1152)=hi.
__global__ __launch_bounds__(256) void pack_kernel(const float* __restrict__ x,
                                                   bf16* __restrict__ Ap,
                                                   bf16* __restrict__ Aq) {
    int g = blockIdx.x * 256 + threadIdx.x;
    if (g >= CM * KF3) return;
    int wext = g % KF3;
    int row = g / KF3;
    int blk = wext / 384;
    int w = wext - blk * 384;
    float p = 0.f, q = 0.f;
    if (w == 0 || w == 360) {
        p = x[(size_t)row * Ww + w];
    } else if (w < 360) {
        float a = x[(size_t)row * Ww + w];
        float b = x[(size_t)row * Ww + (Ww - w)];
        p = a + b;
        q = a - b;
    }
    bf16 phi = __float2bfloat16(p);
    bf16 qhi = __float2bfloat16(q);
    if (blk == 1) {
        Ap[g] = __float2bfloat16(p - __bfloat162float(phi));
        Aq[g] = __float2bfloat16(q - __bfloat162float(qhi));
    } else {
        Ap[g] = phi;
        Aq[g] = qhi;
    }
}

// ----------------------------------------------------------------- zero fill
__global__ __launch_bounds__(256) void fill_zero_kernel(uint4* __restrict__ p, long n) {
    long i = (long)blockIdx.x * 256 + threadIdx.x;
    long stride = (long)gridDim.x * 256;
    uint4 z = make_uint4(0u, 0u, 0u, 0u);
    for (; i < n; i += stride) p[i] = z;
}

// ------------------------------------------- fwd MFMA GEMM, compact epilogue
__global__ __launch_bounds__(256) void gemm_fwd_compact_kernel(
    const bf16* __restrict__ Ap, const bf16* __restrict__ Aq,
    const bf16* __restrict__ Bc, const bf16* __restrict__ Bsm,
    float* __restrict__ Xcr, float* __restrict__ Xci,
    const int* __restrict__ rs, int T128, int mbase)
{
    __shared__ __align__(128) bf16 As[128][64];
    __shared__ __align__(128) bf16 Bs[128][64];
    const bf16* A  = blockIdx.z ? Aq : Ap;
    const bf16* Bt = blockIdx.z ? Bsm : Bc;
    float* Xc      = blockIdx.z ? Xci : Xcr;
    const int tid = threadIdx.x;
    const int lane = tid & 63;
    const int wave = tid >> 6;
    const int m0 = blockIdx.x * 128;
    const int n0 = blockIdx.y * 128;
    const int wr = (wave >> 1) * 64;
    const int wc = (wave & 1) * 64;
    const int srow = tid >> 3;
    const int scol = (tid & 7) << 3;
    f32x4 acc[4][4] = {};
    for (int k0 = 0; k0 < KF3; k0 += 64) {
#pragma unroll
        for (int i = 0; i < 4; ++i) {
            const bf16* ga = A  + (size_t)(m0 + i * 32 + srow) * KF3 + k0 + scol;
            const bf16* gb = Bt + (size_t)(n0 + i * 32 + srow) * KF3 + k0 + scol;
            gload_lds16(ga, ((char*)&As[0][0]) + (size_t)(i * 256 + tid) * 16);
            gload_lds16(gb, ((char*)&Bs[0][0]) + (size_t)(i * 256 + tid) * 16);
        }
        __syncthreads();
#pragma unroll
        for (int kk = 0; kk < 64; kk += 32) {
            s16x8 a[4], b[4];
#pragma unroll
            for (int m = 0; m < 4; ++m)
                a[m] = *(const s16x8*)&As[wr + m * 16 + (lane & 15)][kk + (lane >> 4) * 8];
#pragma unroll
            for (int n = 0; n < 4; ++n)
                b[n] = *(const s16x8*)&Bs[wc + n * 16 + (lane & 15)][kk + (lane >> 4) * 8];
#pragma unroll
            for (int m = 0; m < 4; ++m)
#pragma unroll
                for (int n = 0; n < 4; ++n)
                    acc[m][n] = __builtin_amdgcn_mfma_f32_16x16x32_bf16(a[m], b[n], acc[m][n], 0, 0, 0);
        }
        __syncthreads();
    }
    const int rbase = (lane >> 4) * 4;
    const int cidx = lane & 15;
#pragma unroll
    for (int m = 0; m < 4; ++m) {
#pragma unroll
        for (int r = 0; r < 4; ++r) {
            int grow = mbase + m0 + wr + m * 16 + rbase + r;
            int bc = grow / Hh;
            int h = grow - bc * Hh;
            int t0 = rs[h];
            int cnt = rs[h + 1] - t0;
#pragma unroll
            for (int n = 0; n < 4; ++n) {
                int j = n0 + wc + n * 16 + cidx;
                if (j < cnt)
                    Xc[(size_t)bc * T128 + t0 + j] = acc[m][n][r];
            }
        }
    }
}

// --------------------------------- inverse GEMM from compact gated spectrum
// C (y) stored as bf16 now.
__global__ __launch_bounds__(256) void gemm_inv_kernel(
    const bf16* __restrict__ Xgr, const bf16* __restrict__ Xgi,
    const bf16* __restrict__ Bt, const int* __restrict__ rs8,
    bf16* __restrict__ C, int T8cap)
{
    __shared__ __align__(128) bf16 As[128][64];
    __shared__ __align__(128) bf16 Bs[128][64];
    __shared__ int rsL[Hh + 1];
    const int tid = threadIdx.x;
    for (int i = tid; i <= Hh; i += 256) rsL[i] = rs8[i];
    const int lane = tid & 63;
    const int wave = tid >> 6;
    const int m0 = blockIdx.x * 128;
    const int n0 = blockIdx.y * 128;
    const int wr = (wave >> 1) * 64;
    const int wc = (wave & 1) * 64;
    const int srow = tid >> 3;
    const int scol = (tid & 7) << 3;
    __syncthreads();
    f32x4 acc[4][4] = {};
    for (int k0 = 0; k0 < KI; k0 += 64) {
#pragma unroll
        for (int i = 0; i < 4; ++i)
            gload_lds16(Bt + (size_t)(n0 + i * 32 + srow) * KI + k0 + scol,
                        ((char*)&Bs[0][0]) + (size_t)(i * 256 + tid) * 16);
        {
            int k = k0 + scol;
            int j0 = (k < 384) ? k : k - 384;
            const bf16* base = (k < 384) ? Xgr : Xgi;
#pragma unroll
            for (int i = 0; i < 4; ++i) {
                int grow = m0 + i * 32 + srow;
                int bc = grow / Hh;
                int h = grow - bc * Hh;
                int t0v = rsL[h];
                int cnt8 = rsL[h + 1] - t0v;
                s16x8 v = (s16x8){0, 0, 0, 0, 0, 0, 0, 0};
                if (j0 < cnt8)
                    v = *(const s16x8*)(base + (size_t)bc * T8cap + t0v + j0);
                *(s16x8*)&As[i * 32 + srow][scol] = v;
            }
        }
        __syncthreads();
#pragma unroll
        for (int kk = 0; kk < 64; kk += 32) {
            s16x8 a[4], b[4];
#pragma unroll
            for (int m = 0; m < 4; ++m)
                a[m] = *(const s16x8*)&As[wr + m * 16 + (lane & 15)][kk + (lane >> 4) * 8];
#pragma unroll
            for (int n = 0; n < 4; ++n)
                b[n] = *(const s16x8*)&Bs[wc + n * 16 + (lane & 15)][kk + (lane >> 4) * 8];
#pragma unroll
            for (int m = 0; m < 4; ++m)
#pragma unroll
                for (int n = 0; n < 4; ++n)
                    acc[m][n] = __builtin_amdgcn_mfma_f32_16x16x32_bf16(a[m], b[n], acc[m][n], 0, 0, 0);
        }
        __syncthreads();
    }
    const int rbase = (lane >> 4) * 4;
    const int cidx = lane & 15;
#pragma unroll
    for (int m = 0; m < 4; ++m) {
#pragma unroll
        for (int n = 0; n < 4; ++n) {
            int gcol = n0 + wc + n * 16 + cidx;
            if (gcol < NSTORE_INV) {
#pragma unroll
                for (int r = 0; r < 4; ++r) {
                    int grow = m0 + wr + m * 16 + rbase + r;
                    C[(size_t)grow * NI + gcol] = __float2bfloat16(acc[m][n][r]);
                }
            }
        }
    }
}

// ------------------------------------------------ fused middle stage (v3)
// VERBATIM green round-10/13 middle.
__device__ __forceinline__ float gelu_exact(float v) {
    return 0.5f * v * (1.0f + erff(v * 0.7071067811865476f));
}

__global__ __launch_bounds__(256, 4) void middle_fused_kernel(
    const float* __restrict__ Xcr, const float* __restrict__ Xci,
    bf16* __restrict__ Xgr, bf16* __restrict__ Xgi,
    const float* __restrict__ mean_r, const float* __restrict__ mean_i,
    const float* __restrict__ stdv,
    const float* __restrict__ mags_r, const float* __restrict__ mags_i,
    const float* __restrict__ bias_r, const float* __restrict__ bias_i,
    const bf16* __restrict__ W1f, const bf16* __restrict__ W2f,
    const float* __restrict__ brelu_p,
    const float* __restrict__ glu_mags, const float* __restrict__ glu_phases,
    const int* __restrict__ rows, const int* __restrict__ cols,
    const int* __restrict__ rs8,
    int T, int T128, int T8cap)
{
    __shared__ __align__(16) char smemA[32 * 264 * 2];   // 16,896 B
    __shared__ __align__(16) char smemB[32 * 264 * 2];
    bf16*  H1 = (bf16*)smemA;    // [32][264] hi/lo split input
    float* aL = (float*)smemA;   // [32][132] GEMM1 result
    float* cL = (float*)smemA;   // [32][132] GEMM2 result
    bf16*  H2 = (bf16*)smemB;    // [32][264] gelu output

    const int tid = threadIdx.x;
    const int b = blockIdx.y;
    const int t0 = blockIdx.x * 32;
    const int tl = tid & 31;
    const int cg = tid >> 5;          // 0..7
    const int t = t0 + tl;
    const bool valid = (t < T);
    const int lane = tid & 63;
    const int wv = tid >> 6;          // 0..3
    const int frow = lane & 15;
    const int fcol = (lane >> 4) * 8;
    const s16x8* W1v = (const s16x8*)W1f;
    const s16x8* W2v = (const s16x8*)W2f;
    constexpr int ASRC[6] = {0, 1, 2, 3, 0, 1};
    constexpr int BSRC[6] = {0, 1, 0, 1, 2, 3};

    // ---- phase 1: normalize -> H1 (lane=t, coalesced global reads)
    {
        float mr = 0.f, mi_ = 0.f, isd = 0.f;
        if (valid) { mr = mean_r[t]; mi_ = mean_i[t]; isd = 1.0f / (1e-12f + stdv[t]); }
        s16x8 vhr, vhi, vlr, vli;
#pragma unroll
        for (int ci = 0; ci < 8; ++ci) {
            int c = cg * 8 + ci;
            float xr = 0.f, xi = 0.f;
            if (valid) {
                xr = Xcr[(size_t)(b * 64 + c) * T128 + t];
                xi = Xci[(size_t)(b * 64 + c) * T128 + t];
            }
            float hr = (xr - mr) * isd;
            float hi = (xi - mi_) * isd;
            float h1r = fmaf(hr, mags_r[c], fmaf(-hi, mags_i[c], bias_r[c]));
            float h1i = fmaf(hr, mags_i[c], fmaf(hi, mags_r[c], bias_i[c]));
            short rh = f2bfs(h1r), ih = f2bfs(h1i);
            vhr[ci] = rh; vhi[ci] = ih;
            vlr[ci] = f2bfs(h1r - bfs2f(rh));
            vli[ci] = f2bfs(h1i - bfs2f(ih));
        }
        *(s16x8*)&H1[tl * 264 + cg * 8]       = vhr;
        *(s16x8*)&H1[tl * 264 + 64 + cg * 8]  = vhi;
        *(s16x8*)&H1[tl * 264 + 128 + cg * 8] = vlr;
        *(s16x8*)&H1[tl * 264 + 192 + cg * 8] = vli;
    }
    __syncthreads();

    // ---- GEMM1: A = H1 [32][264], B frags direct from W1f (L2)
    f32x4 acc[2][2] = {};
#pragma unroll
    for (int lc = 0; lc < 6; ++lc) {
        const int ka = ASRC[lc] * 64;
        const int kb = BSRC[lc];
#pragma unroll
        for (int kh = 0; kh < 2; ++kh) {
            s16x8 a0 = *(const s16x8*)&H1[frow * 264 + ka + kh * 32 + fcol];
            s16x8 a1 = *(const s16x8*)&H1[(16 + frow) * 264 + ka + kh * 32 + fcol];
#pragma unroll
            for (int n = 0; n < 2; ++n) {
                s16x8 bfv = W1v[(size_t)((((wv * 2 + n) * 4 + kb) * 2 + kh) * 64 + lane)];
                acc[0][n] = __builtin_amdgcn_mfma_f32_16x16x32_bf16(a0, bfv, acc[0][n], 0, 0, 0);
                acc[1][n] = __builtin_amdgcn_mfma_f32_16x16x32_bf16(a1, bfv, acc[1][n], 0, 0, 0);
            }
        }
    }
    __syncthreads();

    // ---- phase 3: acc -> aL (overwrites H1)
    const int rbase = (lane >> 4) * 4;
    const int cidx = lane & 15;
#pragma unroll
    for (int m = 0; m < 2; ++m)
#pragma unroll
        for (int n = 0; n < 2; ++n)
#pragma unroll
            for (int r = 0; r < 4; ++r)
                aL[(m * 16 + rbase + r) * 132 + wv * 32 + n * 16 + cidx] = acc[m][n][r];
    __syncthreads();

    // ---- phase 4: gelu (lane=t) -> H2
    {
        const float brelu = brelu_p[0];
        f32x4 ar0 = *(const f32x4*)&aL[tl * 132 + cg * 8];
        f32x4 ar1 = *(const f32x4*)&aL[tl * 132 + cg * 8 + 4];
        f32x4 ai0 = *(const f32x4*)&aL[tl * 132 + 64 + cg * 8];
        f32x4 ai1 = *(const f32x4*)&aL[tl * 132 + 64 + cg * 8 + 4];
        s16x8 vhr, vhi, vlr, vli;
#pragma unroll
        for (int ci = 0; ci < 8; ++ci) {
            float ar = (ci < 4) ? ar0[ci & 3] : ar1[ci & 3];
            float ai = (ci < 4) ? ai0[ci & 3] : ai1[ci & 3];
            float r = sqrtf(ar * ar + ai * ai);
            float g = gelu_exact(r + brelu);
            float h2r, h2i;
            if (r > 0.f) { float f = g / r; h2r = f * ar; h2i = f * ai; }
            else { h2r = g; h2i = 0.f; }
            short rh = f2bfs(h2r), ih = f2bfs(h2i);
            vhr[ci] = rh; vhi[ci] = ih;
            vlr[ci] = f2bfs(h2r - bfs2f(rh));
            vli[ci] = f2bfs(h2i - bfs2f(ih));
        }
        *(s16x8*)&H2[tl * 264 + cg * 8]       = vhr;
        *(s16x8*)&H2[tl * 264 + 64 + cg * 8]  = vhi;
        *(s16x8*)&H2[tl * 264 + 128 + cg * 8] = vlr;
        *(s16x8*)&H2[tl * 264 + 192 + cg * 8] = vli;
    }
    __syncthreads();

    // ---- GEMM2: A = H2, B frags from W2f
    f32x4 acc2[2][2] = {};
#pragma unroll
    for (int lc = 0; lc < 6; ++lc) {
        const int ka = ASRC[lc] * 64;
        const int kb = BSRC[lc];
#pragma unroll
        for (int kh = 0; kh < 2; ++kh) {
            s16x8 a0 = *(const s16x8*)&H2[frow * 264 + ka + kh * 32 + fcol];
            s16x8 a1 = *(const s16x8*)&H2[(16 + frow) * 264 + ka + kh * 32 + fcol];
#pragma unroll
            for (int n = 0; n < 2; ++n) {
                s16x8 bfv = W2v[(size_t)((((wv * 2 + n) * 4 + kb) * 2 + kh) * 64 + lane)];
                acc2[0][n] = __builtin_amdgcn_mfma_f32_16x16x32_bf16(a0, bfv, acc2[0][n], 0, 0, 0);
                acc2[1][n] = __builtin_amdgcn_mfma_f32_16x16x32_bf16(a1, bfv, acc2[1][n], 0, 0, 0);
            }
        }
    }
    // cL aliases aL (smemA): all aL reads completed before the barrier above
    // GEMM2; no thread reads smemA during GEMM2.
#pragma unroll
    for (int m = 0; m < 2; ++m)
#pragma unroll
        for (int n = 0; n < 2; ++n)
#pragma unroll
            for (int r = 0; r < 4; ++r)
                cL[(m * 16 + rbase + r) * 132 + wv * 32 + n * 16 + cidx] = acc2[m][n][r];
    __syncthreads();

    // ---- phase 8: gate + compact coalesced store (lane=t)
    if (valid) {
        int h = rows[t], j = cols[t];
        size_t wbase = (size_t)rs8[h] + j;
        f32x4 cr0 = *(const f32x4*)&cL[tl * 132 + cg * 8];
        f32x4 cr1 = *(const f32x4*)&cL[tl * 132 + cg * 8 + 4];
        f32x4 ci0 = *(const f32x4*)&cL[tl * 132 + 64 + cg * 8];
        f32x4 ci1 = *(const f32x4*)&cL[tl * 132 + 64 + cg * 8 + 4];
#pragma unroll
        for (int ci = 0; ci < 8; ++ci) {
            int c = cg * 8 + ci;
            float cr  = (ci < 4) ? cr0[ci & 3] : cr1[ci & 3];
            float cii = (ci < 4) ? ci0[ci & 3] : ci1[ci & 3];
            float xr = Xcr[(size_t)(b * 64 + c) * T128 + t];
            float xi = Xci[(size_t)(b * 64 + c) * T128 + t];
            float r3 = sqrtf(cr * cr + cii * cii);
            float gm = glu_mags[(size_t)c * T + t];
            float gp = glu_phases[(size_t)c * T + t];
            float sg = 1.0f / (1.0f + expf(-(r3 + gm)));
            float ux, uy;
            if (r3 > 0.f) { float ir3 = 1.0f / r3; ux = cr * ir3; uy = cii * ir3; }
            else { ux = 1.f; uy = 0.f; }
            float sp, cp;
            sincosf(gp, &sp, &cp);
            float gx = sg * (ux * cp - uy * sp);
            float gy = sg * (ux * sp + uy * cp);
            size_t base = (size_t)(b * 64 + c) * T8cap + wbase;
            Xgr[base] = __float2bfloat16(xr * gx - xi * gy);
            Xgi[base] = __float2bfloat16(xr * gy + xi * gx);
        }
    }
}

// --------------- depthwise conv + add (bf16 y, 8-wide, XCD-chunk swizzle)
__global__ __launch_bounds__(256) void conv_add_kernel(
    const bf16* __restrict__ y, const float* __restrict__ dw,
    float* __restrict__ out)
{
    const int nb = gridDim.x;
    const int chunk = nb >> 3;
    const int orig = blockIdx.x;
    const int swz = (orig & 7) * chunk + (orig >> 3);   // bijective: nb % 8 == 0
    int g = swz * 256 + threadIdx.x;
    int w8 = g % 90;
    int rem = g / 90;
    int h = rem % Hh;
    int bc = rem / Hh;
    int c = bc & (Cc - 1);
    int w = w8 * 8;
    const bf16* yb = y + (size_t)bc * Hh * NI;
    int walt = (w >= Ww / 2) ? (w - Ww / 2) : (w + Ww / 2);
    float acc[8];
    {
        s16x8 v0 = *(const s16x8*)&yb[h * NI + w];
#pragma unroll
        for (int e = 0; e < 8; ++e) acc[e] = bfs2f(v0[e]);
    }
#pragma unroll
    for (int k = 0; k < 11; ++k) {
        int hp = h + k - 5;
        int hh, ww;
        if (hp < 0)        { hh = -1 - hp;         ww = walt; }
        else if (hp >= Hh) { hh = 2 * Hh - 1 - hp; ww = walt; }
        else               { hh = hp;              ww = w; }
        s16x8 v = *(const s16x8*)&yb[hh * NI + ww];
        float dwk = dw[c * 11 + k];
#pragma unroll
        for (int e = 0; e < 8; ++e)
            acc[e] = fmaf(dwk, bfs2f(v[e]), acc[e]);
    }
    float* ob = &out[((size_t)bc * Hh + h) * Ww + w];
    *(float4*)&ob[0] = make_float4(acc[0], acc[1], acc[2], acc[3]);
    *(float4*)&ob[4] = make_float4(acc[4], acc[5], acc[6], acc[7]);
}

// ------------------------------------------------------------------ launch
extern "C" void kernel_launch(void* const* d_in, const int* in_sizes, int n_in,
                              void* d_out, int out_size, void* d_ws, size_t ws_size,
                              hipStream_t stream)
{
    const float* x      = (const float*)d_in[0];
    const float* mean_r = (const float*)d_in[1];
    const float* mean_i = (const float*)d_in[2];
    const float* stdv   = (const float*)d_in[3];
    const float* mags_r = (const float*)d_in[4];
    const float* mags_i = (const float*)d_in[5];
    const float* bias_r = (const float*)d_in[6];
    const float* bias_i = (const float*)d_in[7];
    const float* w1_r   = (const float*)d_in[8];
    const float* w1_i   = (const float*)d_in[9];
    const float* brelu  = (const float*)d_in[10];
    const float* w2_r   = (const float*)d_in[11];
    const float* w2_i   = (const float*)d_in[12];
    const float* glu_m  = (const float*)d_in[13];
    const float* glu_p  = (const float*)d_in[14];
    const float* dw     = (const float*)d_in[15];
    const int*   rows   = (const int*)d_in[16];
    const int*   cols   = (const int*)d_in[17];
    const int T = in_sizes[16];
    const int T128 = ((T + 127) / 128) * 128;
    const int T8cap = ((T + 7 * Hh) + 127) & ~127;

    char* ws = (char*)d_ws;
    const size_t SApc  = (size_t)CM * KF3 * 2;            // 53,084,160
    const size_t XC_SZ = (size_t)BC * T128 * 4;           // ~42.7 MB
    const size_t XG_SZ = (size_t)BC * T8cap * 2;          // ~22.0 MB
    const size_t Y_SZ  = (size_t)Mrows * NI * 2;          // 70,778,880 (bf16)
    // Lifetimes (stream-ordered):
    //   fwd:    Ap/Aq [0, 2*SApc)  write Xcr/Xci [2*SApc, 2*SApc+2*XC)
    //   fill:   Xg [0, 2*XG)            (Ap/Aq dead)
    //   middle: read Xc, write Xg       (disjoint)
    //   inv:    read Xg, write y [2*XG, 2*XG+Y)  (~44M..115M; Xc dead)
    //   conv:   read y
    //   builds at [2*SApc+2*XC, ...)    (~191.5M..194.6M)
    bf16*  Ap  = (bf16*)ws;
    bf16*  Aq  = (bf16*)(ws + SApc);
    float* Xcr = (float*)(ws + 2 * SApc);
    float* Xci = (float*)(ws + 2 * SApc + XC_SZ);
    bf16*  Xgr = (bf16*)ws;
    bf16*  Xgi = (bf16*)(ws + XG_SZ);
    bf16*  y   = (bf16*)(ws + 2 * XG_SZ);
    size_t boff = 2 * SApc + 2 * XC_SZ;                   // ~191.5 MB
    bf16*  Bce = (bf16*)(ws + boff);
    bf16*  Bse = (bf16*)(ws + boff + (size_t)NF * KF3 * 2);
    bf16*  Bti = (bf16*)(ws + boff + 2 * (size_t)NF * KF3 * 2);
    bf16*  W1f = (bf16*)(ws + boff + 2 * (size_t)NF * KF3 * 2 + (size_t)NI * KI * 2);
    bf16*  W2f = W1f + 32768;
    int*   rs  = (int*)(W2f + 32768);
    int*   rs8 = rs + (Hh + 2);

    build_bfwd_kernel<<<(NF * KF3 + 255) / 256, 256, 0, stream>>>(Bce, Bse);
    build_binv_kernel<<<(NI * KI + 255) / 256, 256, 0, stream>>>(Bti);
    build_wf_kernel<<<(2 * 32768 + 255) / 256, 256, 0, stream>>>(
        w1_r, w1_i, w2_r, w2_i, W1f, W2f);
    row_starts_kernel<<<1, 512, 0, stream>>>(rows, T, rs, rs8);

    for (int ch = 0; ch < CHUNKS; ++ch) {
        pack_kernel<<<(CM * KF3 + 255) / 256, 256, 0, stream>>>(
            x + (size_t)ch * CM * Ww, Ap, Aq);
        gemm_fwd_compact_kernel<<<dim3(CM / 128, NF / 128, 2), 256, 0, stream>>>(
            Ap, Aq, Bce, Bse, Xcr, Xci, rs, T128, ch * CM);
    }

    fill_zero_kernel<<<2048, 256, 0, stream>>>((uint4*)Xgr, (long)(2 * XG_SZ / 16));

    const int nT32 = (T + 31) / 32;
    middle_fused_kernel<<<dim3(nT32, Bb), 256, 0, stream>>>(
        Xcr, Xci, Xgr, Xgi, mean_r, mean_i, stdv, mags_r, mags_i,
        bias_r, bias_i, W1f, W2f, brelu, glu_m, glu_p, rows, cols, rs8,
        T, T128, T8cap);

    gemm_inv_kernel<<<dim3(Mrows / 128, NI / 128), 256, 0, stream>>>(
        Xgr, Xgi, Bti, rs8, y, T8cap);

    // Bb*Cc*Hh*90 groups of 8 / 256 = 16,200 blocks (divisible by 8)
    conv_add_kernel<<<(Bb * Cc * Hh * 90) / 256, 256, 0, stream>>>(y, dw, (float*)d_out);
}

// Round 15
// 590.377 us; speedup vs baseline: 1.9052x; 1.1050x over previous
//
#include <hip/hip_runtime.h>
#include <hip/hip_bf16.h>
#include <math.h>

#define Hh 360
#define Ww 720
#define Cc 64
#define Bb 2
#define BC (Bb*Cc)        // 128
#define Mrows (BC*Hh)     // 46080
#define CHUNKS 2
#define CM (Mrows/CHUNKS) // 23040
#define HPC (Hh/CHUNKS)   // 180 latitudes per chunk
#define KF3 1152          // fwd K: [hi|lo|hi] blocks of 384
#define NF 384            // fwd N (361 bins padded)
#define KI 768            // inv K: [Re(384) | Im(384)]
#define NI 768            // inv C row stride (720 used)
#define NSTORE_INV 720
#define SCALE 0.037267799624996496f   // 1/sqrt(720)
#define TWO_PI 6.2831853071795864769f

typedef __attribute__((ext_vector_type(8))) short s16x8;
typedef __attribute__((ext_vector_type(4))) float f32x4;
typedef __hip_bfloat16 bf16;

__device__ __forceinline__ void gload_lds16(const void* g, void* l) {
    __builtin_amdgcn_global_load_lds(
        (const __attribute__((address_space(1))) unsigned int*)g,
        (__attribute__((address_space(3))) unsigned int*)l, 16, 0, 0);
}
__device__ __forceinline__ short f2bfs(float v) {
    bf16 h = __float2bfloat16(v); short s; __builtin_memcpy(&s, &h, 2); return s;
}
__device__ __forceinline__ float bfs2f(short s) {
    bf16 h; __builtin_memcpy(&h, &s, 2); return __bfloat162float(h);
}

// ---------------------------------------------------------- B-matrix builds
__global__ __launch_bounds__(256) void build_bfwd_kernel(bf16* __restrict__ Bc,
                                                         bf16* __restrict__ Bs) {
    int g = blockIdx.x * 256 + threadIdx.x;
    if (g >= NF * KF3) return;
    int wext = g % KF3;
    int j = g / KF3;
    int blk = wext / 384;
    int w = wext - blk * 384;
    float c = 0.f, s = 0.f;
    if (w <= 360 && j <= 360) {
        int idx = (j * w) % Ww;
        float a = (TWO_PI / Ww) * (float)idx;
        float sv, cv;
        sincosf(a, &sv, &cv);
        c = SCALE * cv;
        s = -SCALE * sv;
    }
    bf16 chi = __float2bfloat16(c);
    bf16 shi = __float2bfloat16(s);
    if (blk == 2) {
        Bc[g] = __float2bfloat16(c - __bfloat162float(chi));
        Bs[g] = __float2bfloat16(s - __bfloat162float(shi));
    } else {
        Bc[g] = chi;
        Bs[g] = shi;
    }
}

__global__ __launch_bounds__(256) void build_binv_kernel(bf16* __restrict__ Bi) {
    int g = blockIdx.x * 256 + threadIdx.x;
    if (g >= NI * KI) return;
    int k = g % KI, n = g / KI;
    float v = 0.f;
    if (n < NSTORE_INV) {
        if (k <= 360) {
            int j = k;
            float f = (j == 0 || j == 360) ? 1.f : 2.f;
            int idx = (j * n) % Ww;
            v = SCALE * f * cosf((TWO_PI / Ww) * (float)idx);
        } else if (k >= 384 && k <= 744) {
            int j = k - 384;
            int idx = (j * n) % Ww;
            v = -2.f * SCALE * sinf((TWO_PI / Ww) * (float)idx);
        }
    }
    Bi[g] = __float2bfloat16(v);
}

// W fragment-packed: s16x8 index = fid*64 + lane, fid = ((n16*4 + kb)*2 + kh).
__global__ __launch_bounds__(256) void build_wf_kernel(
    const float* __restrict__ w1_r, const float* __restrict__ w1_i,
    const float* __restrict__ w2_r, const float* __restrict__ w2_i,
    bf16* __restrict__ W1f, bf16* __restrict__ W2f)
{
    int g = blockIdx.x * 256 + threadIdx.x;
    if (g >= 2 * 32768) return;
    int which = g >> 15;
    int gg = g & 32767;
    int e = gg & 7, lane = (gg >> 3) & 63, kh = (gg >> 9) & 1;
    int kb = (gg >> 10) & 3, n16 = (gg >> 12) & 7;
    int frow = lane & 15, fcol = (lane >> 4) * 8;
    int n = n16 * 16 + frow;
    int kfull = kb * 64 + kh * 32 + fcol + e;
    int kk = kfull & 127, islo = kfull >> 7;
    const float* wr = which ? w2_r : w1_r;
    const float* wi = which ? w2_i : w1_i;
    float v;
    if (n < 64) v = (kk < 64) ? wr[n * 64 + kk] : -wi[n * 64 + kk - 64];
    else { int p = n - 64; v = (kk < 64) ? wi[p * 64 + kk] : wr[p * 64 + kk - 64]; }
    bf16 h = __float2bfloat16(v);
    bf16 out = islo ? __float2bfloat16(v - __bfloat162float(h)) : h;
    (which ? W2f : W1f)[gg] = out;
}

// ---------------------------------------- row starts (compact + 8-padded)
__global__ __launch_bounds__(512) void row_starts_kernel(const int* __restrict__ rows,
                                                         int T, int* __restrict__ rs,
                                                         int* __restrict__ rs8) {
    int h = threadIdx.x;
    if (h <= Hh) {
        if (h == Hh) rs[Hh] = T;
        else {
            int lo = 0, hi = T;
            while (lo < hi) {
                int mid = (lo + hi) >> 1;
                if (rows[mid] < h) lo = mid + 1; else hi = mid;
            }
            rs[h] = lo;
        }
    }
    __syncthreads();
    if (threadIdx.x == 0) {
        int acc = 0;
        for (int i = 0; i < Hh; ++i) {
            rs8[i] = acc;
            int cnt = rs[i + 1] - rs[i];
            acc += (cnt + 7) & ~7;
        }
        rs8[Hh] = acc;
    }
}

// -------------------------------- pack x chunk -> A_ext (p,q), h-major rows
// Local row r = hl*128 + bc  (h = hbase + hl).  A row layout: [hi|lo|hi].
__global__ __launch_bounds__(256) void pack_kernel(const float* __restrict__ x,
                                                   bf16* __restrict__ Ap,
                                                   bf16* __restrict__ Aq,
                                                   int hbase) {
    int g = blockIdx.x * 256 + threadIdx.x;
    if (g >= CM * KF3) return;
    int wext = g % KF3;
    int r = g / KF3;
    int hl = r >> 7;
    int bc = r & 127;
    const float* xrow = x + ((size_t)bc * Hh + hbase + hl) * Ww;
    int blk = wext / 384;
    int w = wext - blk * 384;
    float p = 0.f, q = 0.f;
    if (w == 0 || w == 360) {
        p = xrow[w];
    } else if (w < 360) {
        float a = xrow[w];
        float b = xrow[Ww - w];
        p = a + b;
        q = a - b;
    }
    bf16 phi = __float2bfloat16(p);
    bf16 qhi = __float2bfloat16(q);
    if (blk == 1) {
        Ap[g] = __float2bfloat16(p - __bfloat162float(phi));
        Aq[g] = __float2bfloat16(q - __bfloat162float(qhi));
    } else {
        Ap[g] = phi;
        Aq[g] = qhi;
    }
}

// ----------------------------------------------------------------- zero fill
__global__ __launch_bounds__(256) void fill_zero_kernel(uint4* __restrict__ p, long n) {
    long i = (long)blockIdx.x * 256 + threadIdx.x;
    long stride = (long)gridDim.x * 256;
    uint4 z = make_uint4(0u, 0u, 0u, 0u);
    for (; i < n; i += stride) p[i] = z;
}

// ------------------- fwd MFMA GEMM, h-uniform tiles + early exit + compact C
__global__ __launch_bounds__(256) void gemm_fwd_compact_kernel(
    const bf16* __restrict__ Ap, const bf16* __restrict__ Aq,
    const bf16* __restrict__ Bc, const bf16* __restrict__ Bsm,
    float* __restrict__ Xcr, float* __restrict__ Xci,
    const int* __restrict__ rs, int T128, int hbase)
{
    __shared__ __align__(128) bf16 As[128][64];
    __shared__ __align__(128) bf16 Bs[128][64];
    const int h = hbase + blockIdx.x;       // one latitude per m-tile
    const int t0 = rs[h];
    const int cnt = rs[h + 1] - t0;
    const int n0 = blockIdx.y * 128;
    if (n0 >= cnt) return;                   // tile stores nothing: dead work
    const bf16* A  = blockIdx.z ? Aq : Ap;
    const bf16* Bt = blockIdx.z ? Bsm : Bc;
    float* Xc      = blockIdx.z ? Xci : Xcr;
    const int tid = threadIdx.x;
    const int lane = tid & 63;
    const int wave = tid >> 6;
    const int m0 = blockIdx.x * 128;
    const int wr = (wave >> 1) * 64;
    const int wc = (wave & 1) * 64;
    const int srow = tid >> 3;
    const int scol = (tid & 7) << 3;
    f32x4 acc[4][4] = {};
    for (int k0 = 0; k0 < KF3; k0 += 64) {
#pragma unroll
        for (int i = 0; i < 4; ++i) {
            const bf16* ga = A  + (size_t)(m0 + i * 32 + srow) * KF3 + k0 + scol;
            const bf16* gb = Bt + (size_t)(n0 + i * 32 + srow) * KF3 + k0 + scol;
            gload_lds16(ga, ((char*)&As[0][0]) + (size_t)(i * 256 + tid) * 16);
            gload_lds16(gb, ((char*)&Bs[0][0]) + (size_t)(i * 256 + tid) * 16);
        }
        __syncthreads();
#pragma unroll
        for (int kk = 0; kk < 64; kk += 32) {
            s16x8 a[4], b[4];
#pragma unroll
            for (int m = 0; m < 4; ++m)
                a[m] = *(const s16x8*)&As[wr + m * 16 + (lane & 15)][kk + (lane >> 4) * 8];
#pragma unroll
            for (int n = 0; n < 4; ++n)
                b[n] = *(const s16x8*)&Bs[wc + n * 16 + (lane & 15)][kk + (lane >> 4) * 8];
#pragma unroll
            for (int m = 0; m < 4; ++m)
#pragma unroll
                for (int n = 0; n < 4; ++n)
                    acc[m][n] = __builtin_amdgcn_mfma_f32_16x16x32_bf16(a[m], b[n], acc[m][n], 0, 0, 0);
        }
        __syncthreads();
    }
    const int rbase = (lane >> 4) * 4;
    const int cidx = lane & 15;
#pragma unroll
    for (int m = 0; m < 4; ++m) {
#pragma unroll
        for (int r = 0; r < 4; ++r) {
            int bc = wr + m * 16 + rbase + r;   // local row within h-tile
#pragma unroll
            for (int n = 0; n < 4; ++n) {
                int j = n0 + wc + n * 16 + cidx;
                if (j < cnt)
                    Xc[(size_t)bc * T128 + t0 + j] = acc[m][n][r];
            }
        }
    }
}

// --------------------------------- inverse GEMM from compact gated spectrum
// C (y) stored as bf16.
__global__ __launch_bounds__(256) void gemm_inv_kernel(
    const bf16* __restrict__ Xgr, const bf16* __restrict__ Xgi,
    const bf16* __restrict__ Bt, const int* __restrict__ rs8,
    bf16* __restrict__ C, int T8cap)
{
    __shared__ __align__(128) bf16 As[128][64];
    __shared__ __align__(128) bf16 Bs[128][64];
    __shared__ int rsL[Hh + 1];
    const int tid = threadIdx.x;
    for (int i = tid; i <= Hh; i += 256) rsL[i] = rs8[i];
    const int lane = tid & 63;
    const int wave = tid >> 6;
    const int m0 = blockIdx.x * 128;
    const int n0 = blockIdx.y * 128;
    const int wr = (wave >> 1) * 64;
    const int wc = (wave & 1) * 64;
    const int srow = tid >> 3;
    const int scol = (tid & 7) << 3;
    __syncthreads();
    f32x4 acc[4][4] = {};
    for (int k0 = 0; k0 < KI; k0 += 64) {
#pragma unroll
        for (int i = 0; i < 4; ++i)
            gload_lds16(Bt + (size_t)(n0 + i * 32 + srow) * KI + k0 + scol,
                        ((char*)&Bs[0][0]) + (size_t)(i * 256 + tid) * 16);
        {
            int k = k0 + scol;
            int j0 = (k < 384) ? k : k - 384;
            const bf16* base = (k < 384) ? Xgr : Xgi;
#pragma unroll
            for (int i = 0; i < 4; ++i) {
                int grow = m0 + i * 32 + srow;
                int bc = grow / Hh;
                int h = grow - bc * Hh;
                int t0v = rsL[h];
                int cnt8 = rsL[h + 1] - t0v;
                s16x8 v = (s16x8){0, 0, 0, 0, 0, 0, 0, 0};
                if (j0 < cnt8)
                    v = *(const s16x8*)(base + (size_t)bc * T8cap + t0v + j0);
                *(s16x8*)&As[i * 32 + srow][scol] = v;
            }
        }
        __syncthreads();
#pragma unroll
        for (int kk = 0; kk < 64; kk += 32) {
            s16x8 a[4], b[4];
#pragma unroll
            for (int m = 0; m < 4; ++m)
                a[m] = *(const s16x8*)&As[wr + m * 16 + (lane & 15)][kk + (lane >> 4) * 8];
#pragma unroll
            for (int n = 0; n < 4; ++n)
                b[n] = *(const s16x8*)&Bs[wc + n * 16 + (lane & 15)][kk + (lane >> 4) * 8];
#pragma unroll
            for (int m = 0; m < 4; ++m)
#pragma unroll
                for (int n = 0; n < 4; ++n)
                    acc[m][n] = __builtin_amdgcn_mfma_f32_16x16x32_bf16(a[m], b[n], acc[m][n], 0, 0, 0);
        }
        __syncthreads();
    }
    const int rbase = (lane >> 4) * 4;
    const int cidx = lane & 15;
#pragma unroll
    for (int m = 0; m < 4; ++m) {
#pragma unroll
        for (int n = 0; n < 4; ++n) {
            int gcol = n0 + wc + n * 16 + cidx;
            if (gcol < NSTORE_INV) {
#pragma unroll
                for (int r = 0; r < 4; ++r) {
                    int grow = m0 + wr + m * 16 + rbase + r;
                    C[(size_t)grow * NI + gcol] = __float2bfloat16(acc[m][n][r]);
                }
            }
        }
    }
}

// ------------------------------------------------ fused middle stage (v3)
// VERBATIM green round-10/13/14 middle.
__device__ __forceinline__ float gelu_exact(float v) {
    return 0.5f * v * (1.0f + erff(v * 0.7071067811865476f));
}

__global__ __launch_bounds__(256, 4) void middle_fused_kernel(
    const float* __restrict__ Xcr, const float* __restrict__ Xci,
    bf16* __restrict__ Xgr, bf16* __restrict__ Xgi,
    const float* __restrict__ mean_r, const float* __restrict__ mean_i,
    const float* __restrict__ stdv,
    const float* __restrict__ mags_r, const float* __restrict__ mags_i,
    const float* __restrict__ bias_r, const float* __restrict__ bias_i,
    const bf16* __restrict__ W1f, const bf16* __restrict__ W2f,
    const float* __restrict__ brelu_p,
    const float* __restrict__ glu_mags, const float* __restrict__ glu_phases,
    const int* __restrict__ rows, const int* __restrict__ cols,
    const int* __restrict__ rs8,
    int T, int T128, int T8cap)
{
    __shared__ __align__(16) char smemA[32 * 264 * 2];   // 16,896 B
    __shared__ __align__(16) char smemB[32 * 264 * 2];
    bf16*  H1 = (bf16*)smemA;    // [32][264] hi/lo split input
    float* aL = (float*)smemA;   // [32][132] GEMM1 result
    float* cL = (float*)smemA;   // [32][132] GEMM2 result
    bf16*  H2 = (bf16*)smemB;    // [32][264] gelu output

    const int tid = threadIdx.x;
    const int b = blockIdx.y;
    const int t0 = blockIdx.x * 32;
    const int tl = tid & 31;
    const int cg = tid >> 5;          // 0..7
    const int t = t0 + tl;
    const bool valid = (t < T);
    const int lane = tid & 63;
    const int wv = tid >> 6;          // 0..3
    const int frow = lane & 15;
    const int fcol = (lane >> 4) * 8;
    const s16x8* W1v = (const s16x8*)W1f;
    const s16x8* W2v = (const s16x8*)W2f;
    constexpr int ASRC[6] = {0, 1, 2, 3, 0, 1};
    constexpr int BSRC[6] = {0, 1, 0, 1, 2, 3};

    // ---- phase 1: normalize -> H1 (lane=t, coalesced global reads)
    {
        float mr = 0.f, mi_ = 0.f, isd = 0.f;
        if (valid) { mr = mean_r[t]; mi_ = mean_i[t]; isd = 1.0f / (1e-12f + stdv[t]); }
        s16x8 vhr, vhi, vlr, vli;
#pragma unroll
        for (int ci = 0; ci < 8; ++ci) {
            int c = cg * 8 + ci;
            float xr = 0.f, xi = 0.f;
            if (valid) {
                xr = Xcr[(size_t)(b * 64 + c) * T128 + t];
                xi = Xci[(size_t)(b * 64 + c) * T128 + t];
            }
            float hr = (xr - mr) * isd;
            float hi = (xi - mi_) * isd;
            float h1r = fmaf(hr, mags_r[c], fmaf(-hi, mags_i[c], bias_r[c]));
            float h1i = fmaf(hr, mags_i[c], fmaf(hi, mags_r[c], bias_i[c]));
            short rh = f2bfs(h1r), ih = f2bfs(h1i);
            vhr[ci] = rh; vhi[ci] = ih;
            vlr[ci] = f2bfs(h1r - bfs2f(rh));
            vli[ci] = f2bfs(h1i - bfs2f(ih));
        }
        *(s16x8*)&H1[tl * 264 + cg * 8]       = vhr;
        *(s16x8*)&H1[tl * 264 + 64 + cg * 8]  = vhi;
        *(s16x8*)&H1[tl * 264 + 128 + cg * 8] = vlr;
        *(s16x8*)&H1[tl * 264 + 192 + cg * 8] = vli;
    }
    __syncthreads();

    // ---- GEMM1: A = H1 [32][264], B frags direct from W1f (L2)
    f32x4 acc[2][2] = {};
#pragma unroll
    for (int lc = 0; lc < 6; ++lc) {
        const int ka = ASRC[lc] * 64;
        const int kb = BSRC[lc];
#pragma unroll
        for (int kh = 0; kh < 2; ++kh) {
            s16x8 a0 = *(const s16x8*)&H1[frow * 264 + ka + kh * 32 + fcol];
            s16x8 a1 = *(const s16x8*)&H1[(16 + frow) * 264 + ka + kh * 32 + fcol];
#pragma unroll
            for (int n = 0; n < 2; ++n) {
                s16x8 bfv = W1v[(size_t)((((wv * 2 + n) * 4 + kb) * 2 + kh) * 64 + lane)];
                acc[0][n] = __builtin_amdgcn_mfma_f32_16x16x32_bf16(a0, bfv, acc[0][n], 0, 0, 0);
                acc[1][n] = __builtin_amdgcn_mfma_f32_16x16x32_bf16(a1, bfv, acc[1][n], 0, 0, 0);
            }
        }
    }
    __syncthreads();

    // ---- phase 3: acc -> aL (overwrites H1)
    const int rbase = (lane >> 4) * 4;
    const int cidx = lane & 15;
#pragma unroll
    for (int m = 0; m < 2; ++m)
#pragma unroll
        for (int n = 0; n < 2; ++n)
#pragma unroll
            for (int r = 0; r < 4; ++r)
                aL[(m * 16 + rbase + r) * 132 + wv * 32 + n * 16 + cidx] = acc[m][n][r];
    __syncthreads();

    // ---- phase 4: gelu (lane=t) -> H2
    {
        const float brelu = brelu_p[0];
        f32x4 ar0 = *(const f32x4*)&aL[tl * 132 + cg * 8];
        f32x4 ar1 = *(const f32x4*)&aL[tl * 132 + cg * 8 + 4];
        f32x4 ai0 = *(const f32x4*)&aL[tl * 132 + 64 + cg * 8];
        f32x4 ai1 = *(const f32x4*)&aL[tl * 132 + 64 + cg * 8 + 4];
        s16x8 vhr, vhi, vlr, vli;
#pragma unroll
        for (int ci = 0; ci < 8; ++ci) {
            float ar = (ci < 4) ? ar0[ci & 3] : ar1[ci & 3];
            float ai = (ci < 4) ? ai0[ci & 3] : ai1[ci & 3];
            float r = sqrtf(ar * ar + ai * ai);
            float g = gelu_exact(r + brelu);
            float h2r, h2i;
            if (r > 0.f) { float f = g / r; h2r = f * ar; h2i = f * ai; }
            else { h2r = g; h2i = 0.f; }
            short rh = f2bfs(h2r), ih = f2bfs(h2i);
            vhr[ci] = rh; vhi[ci] = ih;
            vlr[ci] = f2bfs(h2r - bfs2f(rh));
            vli[ci] = f2bfs(h2i - bfs2f(ih));
        }
        *(s16x8*)&H2[tl * 264 + cg * 8]       = vhr;
        *(s16x8*)&H2[tl * 264 + 64 + cg * 8]  = vhi;
        *(s16x8*)&H2[tl * 264 + 128 + cg * 8] = vlr;
        *(s16x8*)&H2[tl * 264 + 192 + cg * 8] = vli;
    }
    __syncthreads();

    // ---- GEMM2: A = H2, B frags from W2f
    f32x4 acc2[2][2] = {};
#pragma unroll
    for (int lc = 0; lc < 6; ++lc) {
        const int ka = ASRC[lc] * 64;
        const int kb = BSRC[lc];
#pragma unroll
        for (int kh = 0; kh < 2; ++kh) {
            s16x8 a0 = *(const s16x8*)&H2[frow * 264 + ka + kh * 32 + fcol];
            s16x8 a1 = *(const s16x8*)&H2[(16 + frow) * 264 + ka + kh * 32 + fcol];
#pragma unroll
            for (int n = 0; n < 2; ++n) {
                s16x8 bfv = W2v[(size_t)((((wv * 2 + n) * 4 + kb) * 2 + kh) * 64 + lane)];
                acc2[0][n] = __builtin_amdgcn_mfma_f32_16x16x32_bf16(a0, bfv, acc2[0][n], 0, 0, 0);
                acc2[1][n] = __builtin_amdgcn_mfma_f32_16x16x32_bf16(a1, bfv, acc2[1][n], 0, 0, 0);
            }
        }
    }
    // cL aliases aL (smemA): all aL reads completed before the barrier above
    // GEMM2; no thread reads smemA during GEMM2.
#pragma unroll
    for (int m = 0; m < 2; ++m)
#pragma unroll
        for (int n = 0; n < 2; ++n)
#pragma unroll
            for (int r = 0; r < 4; ++r)
                cL[(m * 16 + rbase + r) * 132 + wv * 32 + n * 16 + cidx] = acc2[m][n][r];
    __syncthreads();

    // ---- phase 8: gate + compact coalesced store (lane=t)
    if (valid) {
        int h = rows[t], j = cols[t];
        size_t wbase = (size_t)rs8[h] + j;
        f32x4 cr0 = *(const f32x4*)&cL[tl * 132 + cg * 8];
        f32x4 cr1 = *(const f32x4*)&cL[tl * 132 + cg * 8 + 4];
        f32x4 ci0 = *(const f32x4*)&cL[tl * 132 + 64 + cg * 8];
        f32x4 ci1 = *(const f32x4*)&cL[tl * 132 + 64 + cg * 8 + 4];
#pragma unroll
        for (int ci = 0; ci < 8; ++ci) {
            int c = cg * 8 + ci;
            float cr  = (ci < 4) ? cr0[ci & 3] : cr1[ci & 3];
            float cii = (ci < 4) ? ci0[ci & 3] : ci1[ci & 3];
            float xr = Xcr[(size_t)(b * 64 + c) * T128 + t];
            float xi = Xci[(size_t)(b * 64 + c) * T128 + t];
            float r3 = sqrtf(cr * cr + cii * cii);
            float gm = glu_mags[(size_t)c * T + t];
            float gp = glu_phases[(size_t)c * T + t];
            float sg = 1.0f / (1.0f + expf(-(r3 + gm)));
            float ux, uy;
            if (r3 > 0.f) { float ir3 = 1.0f / r3; ux = cr * ir3; uy = cii * ir3; }
            else { ux = 1.f; uy = 0.f; }
            float sp, cp;
            sincosf(gp, &sp, &cp);
            float gx = sg * (ux * cp - uy * sp);
            float gy = sg * (ux * sp + uy * cp);
            size_t base = (size_t)(b * 64 + c) * T8cap + wbase;
            Xgr[base] = __float2bfloat16(xr * gx - xi * gy);
            Xgi[base] = __float2bfloat16(xr * gy + xi * gx);
        }
    }
}

// --------------- depthwise conv + add (bf16 y, 8-wide, XCD-chunk swizzle)
__global__ __launch_bounds__(256) void conv_add_kernel(
    const bf16* __restrict__ y, const float* __restrict__ dw,
    float* __restrict__ out)
{
    const int nb = gridDim.x;
    const int chunk = nb >> 3;
    const int orig = blockIdx.x;
    const int swz = (orig & 7) * chunk + (orig >> 3);   // bijective: nb % 8 == 0
    int g = swz * 256 + threadIdx.x;
    int w8 = g % 90;
    int rem = g / 90;
    int h = rem % Hh;
    int bc = rem / Hh;
    int c = bc & (Cc - 1);
    int w = w8 * 8;
    const bf16* yb = y + (size_t)bc * Hh * NI;
    int walt = (w >= Ww / 2) ? (w - Ww / 2) : (w + Ww / 2);
    float acc[8];
    {
        s16x8 v0 = *(const s16x8*)&yb[h * NI + w];
#pragma unroll
        for (int e = 0; e < 8; ++e) acc[e] = bfs2f(v0[e]);
    }
#pragma unroll
    for (int k = 0; k < 11; ++k) {
        int hp = h + k - 5;
        int hh, ww;
        if (hp < 0)        { hh = -1 - hp;         ww = walt; }
        else if (hp >= Hh) { hh = 2 * Hh - 1 - hp; ww = walt; }
        else               { hh = hp;              ww = w; }
        s16x8 v = *(const s16x8*)&yb[hh * NI + ww];
        float dwk = dw[c * 11 + k];
#pragma unroll
        for (int e = 0; e < 8; ++e)
            acc[e] = fmaf(dwk, bfs2f(v[e]), acc[e]);
    }
    float* ob = &out[((size_t)bc * Hh + h) * Ww + w];
    *(float4*)&ob[0] = make_float4(acc[0], acc[1], acc[2], acc[3]);
    *(float4*)&ob[4] = make_float4(acc[4], acc[5], acc[6], acc[7]);
}

// ------------------------------------------------------------------ launch
extern "C" void kernel_launch(void* const* d_in, const int* in_sizes, int n_in,
                              void* d_out, int out_size, void* d_ws, size_t ws_size,
                              hipStream_t stream)
{
    const float* x      = (const float*)d_in[0];
    const float* mean_r = (const float*)d_in[1];
    const float* mean_i = (const float*)d_in[2];
    const float* stdv   = (const float*)d_in[3];
    const float* mags_r = (const float*)d_in[4];
    const float* mags_i = (const float*)d_in[5];
    const float* bias_r = (const float*)d_in[6];
    const float* bias_i = (const float*)d_in[7];
    const float* w1_r   = (const float*)d_in[8];
    const float* w1_i   = (const float*)d_in[9];
    const float* brelu  = (const float*)d_in[10];
    const float* w2_r   = (const float*)d_in[11];
    const float* w2_i   = (const float*)d_in[12];
    const float* glu_m  = (const float*)d_in[13];
    const float* glu_p  = (const float*)d_in[14];
    const float* dw     = (const float*)d_in[15];
    const int*   rows   = (const int*)d_in[16];
    const int*   cols   = (const int*)d_in[17];
    const int T = in_sizes[16];
    const int T128 = ((T + 127) / 128) * 128;
    const int T8cap = ((T + 7 * Hh) + 127) & ~127;

    char* ws = (char*)d_ws;
    const size_t SApc  = (size_t)CM * KF3 * 2;            // 53,084,160
    const size_t XC_SZ = (size_t)BC * T128 * 4;           // ~42.7 MB
    const size_t XG_SZ = (size_t)BC * T8cap * 2;          // ~22.0 MB
    // Lifetimes (stream-ordered), identical to green r14:
    bf16*  Ap  = (bf16*)ws;
    bf16*  Aq  = (bf16*)(ws + SApc);
    float* Xcr = (float*)(ws + 2 * SApc);
    float* Xci = (float*)(ws + 2 * SApc + XC_SZ);
    bf16*  Xgr = (bf16*)ws;
    bf16*  Xgi = (bf16*)(ws + XG_SZ);
    bf16*  y   = (bf16*)(ws + 2 * XG_SZ);
    size_t boff = 2 * SApc + 2 * XC_SZ;                   // ~191.5 MB
    bf16*  Bce = (bf16*)(ws + boff);
    bf16*  Bse = (bf16*)(ws + boff + (size_t)NF * KF3 * 2);
    bf16*  Bti = (bf16*)(ws + boff + 2 * (size_t)NF * KF3 * 2);
    bf16*  W1f = (bf16*)(ws + boff + 2 * (size_t)NF * KF3 * 2 + (size_t)NI * KI * 2);
    bf16*  W2f = W1f + 32768;
    int*   rs  = (int*)(W2f + 32768);
    int*   rs8 = rs + (Hh + 2);

    build_bfwd_kernel<<<(NF * KF3 + 255) / 256, 256, 0, stream>>>(Bce, Bse);
    build_binv_kernel<<<(NI * KI + 255) / 256, 256, 0, stream>>>(Bti);
    build_wf_kernel<<<(2 * 32768 + 255) / 256, 256, 0, stream>>>(
        w1_r, w1_i, w2_r, w2_i, W1f, W2f);
    row_starts_kernel<<<1, 512, 0, stream>>>(rows, T, rs, rs8);

    for (int ch = 0; ch < CHUNKS; ++ch) {
        pack_kernel<<<(CM * KF3 + 255) / 256, 256, 0, stream>>>(
            x, Ap, Aq, ch * HPC);
        gemm_fwd_compact_kernel<<<dim3(CM / 128, NF / 128, 2), 256, 0, stream>>>(
            Ap, Aq, Bce, Bse, Xcr, Xci, rs, T128, ch * HPC);
    }

    fill_zero_kernel<<<2048, 256, 0, stream>>>((uint4*)Xgr, (long)(2 * XG_SZ / 16));

    const int nT32 = (T + 31) / 32;
    middle_fused_kernel<<<dim3(nT32, Bb), 256, 0, stream>>>(
        Xcr, Xci, Xgr, Xgi, mean_r, mean_i, stdv, mags_r, mags_i,
        bias_r, bias_i, W1f, W2f, brelu, glu_m, glu_p, rows, cols, rs8,
        T, T128, T8cap);

    gemm_inv_kernel<<<dim3(Mrows / 128, NI / 128), 256, 0, stream>>>(
        Xgr, Xgi, Bti, rs8, y, T8cap);

    conv_add_kernel<<<(Bb * Cc * Hh * 90) / 256, 256, 0, stream>>>(y, dw, (float*)d_out);
}

// Round 16
// 581.776 us; speedup vs baseline: 1.9334x; 1.0148x over previous
//
#include <hip/hip_runtime.h>
#include <hip/hip_bf16.h>
#include <math.h>

#define Hh 360
#define Ww 720
#define Cc 64
#define Bb 2
#define BC (Bb*Cc)        // 128
#define Mrows (BC*Hh)     // 46080
#define CHUNKS 2
#define CM (Mrows/CHUNKS) // 23040
#define HPC (Hh/CHUNKS)   // 180 latitudes per chunk
#define KF3 1152          // fwd K: [hi|lo|hi] blocks of 384
#define NF 384            // fwd N (361 bins padded)
#define KI 768            // inv K: [Re(384) | Im(384)]
#define NI 768            // inv C row stride (720 used)
#define NSTORE_INV 720
#define SCALE 0.037267799624996496f   // 1/sqrt(720)
#define TWO_PI 6.2831853071795864769f

typedef __attribute__((ext_vector_type(8))) short s16x8;
typedef __attribute__((ext_vector_type(4))) float f32x4;
typedef __hip_bfloat16 bf16;

__device__ __forceinline__ void gload_lds16(const void* g, void* l) {
    __builtin_amdgcn_global_load_lds(
        (const __attribute__((address_space(1))) unsigned int*)g,
        (__attribute__((address_space(3))) unsigned int*)l, 16, 0, 0);
}
__device__ __forceinline__ short f2bfs(float v) {
    bf16 h = __float2bfloat16(v); short s; __builtin_memcpy(&s, &h, 2); return s;
}
__device__ __forceinline__ float bfs2f(short s) {
    bf16 h; __builtin_memcpy(&h, &s, 2); return __bfloat162float(h);
}

// ---------------------------------------------------------- B-matrix builds
__global__ __launch_bounds__(256) void build_bfwd_kernel(bf16* __restrict__ Bc,
                                                         bf16* __restrict__ Bs) {
    int g = blockIdx.x * 256 + threadIdx.x;
    if (g >= NF * KF3) return;
    int wext = g % KF3;
    int j = g / KF3;
    int blk = wext / 384;
    int w = wext - blk * 384;
    float c = 0.f, s = 0.f;
    if (w <= 360 && j <= 360) {
        int idx = (j * w) % Ww;
        float a = (TWO_PI / Ww) * (float)idx;
        float sv, cv;
        sincosf(a, &sv, &cv);
        c = SCALE * cv;
        s = -SCALE * sv;
    }
    bf16 chi = __float2bfloat16(c);
    bf16 shi = __float2bfloat16(s);
    if (blk == 2) {
        Bc[g] = __float2bfloat16(c - __bfloat162float(chi));
        Bs[g] = __float2bfloat16(s - __bfloat162float(shi));
    } else {
        Bc[g] = chi;
        Bs[g] = shi;
    }
}

__global__ __launch_bounds__(256) void build_binv_kernel(bf16* __restrict__ Bi) {
    int g = blockIdx.x * 256 + threadIdx.x;
    if (g >= NI * KI) return;
    int k = g % KI, n = g / KI;
    float v = 0.f;
    if (n < NSTORE_INV) {
        if (k <= 360) {
            int j = k;
            float f = (j == 0 || j == 360) ? 1.f : 2.f;
            int idx = (j * n) % Ww;
            v = SCALE * f * cosf((TWO_PI / Ww) * (float)idx);
        } else if (k >= 384 && k <= 744) {
            int j = k - 384;
            int idx = (j * n) % Ww;
            v = -2.f * SCALE * sinf((TWO_PI / Ww) * (float)idx);
        }
    }
    Bi[g] = __float2bfloat16(v);
}

// W fragment-packed: s16x8 index = fid*64 + lane, fid = ((n16*4 + kb)*2 + kh).
__global__ __launch_bounds__(256) void build_wf_kernel(
    const float* __restrict__ w1_r, const float* __restrict__ w1_i,
    const float* __restrict__ w2_r, const float* __restrict__ w2_i,
    bf16* __restrict__ W1f, bf16* __restrict__ W2f)
{
    int g = blockIdx.x * 256 + threadIdx.x;
    if (g >= 2 * 32768) return;
    int which = g >> 15;
    int gg = g & 32767;
    int e = gg & 7, lane = (gg >> 3) & 63, kh = (gg >> 9) & 1;
    int kb = (gg >> 10) & 3, n16 = (gg >> 12) & 7;
    int frow = lane & 15, fcol = (lane >> 4) * 8;
    int n = n16 * 16 + frow;
    int kfull = kb * 64 + kh * 32 + fcol + e;
    int kk = kfull & 127, islo = kfull >> 7;
    const float* wr = which ? w2_r : w1_r;
    const float* wi = which ? w2_i : w1_i;
    float v;
    if (n < 64) v = (kk < 64) ? wr[n * 64 + kk] : -wi[n * 64 + kk - 64];
    else { int p = n - 64; v = (kk < 64) ? wi[p * 64 + kk] : wr[p * 64 + kk - 64]; }
    bf16 h = __float2bfloat16(v);
    bf16 out = islo ? __float2bfloat16(v - __bfloat162float(h)) : h;
    (which ? W2f : W1f)[gg] = out;
}

// ---------------------------------------- row starts (compact + 8-padded)
__global__ __launch_bounds__(512) void row_starts_kernel(const int* __restrict__ rows,
                                                         int T, int* __restrict__ rs,
                                                         int* __restrict__ rs8) {
    int h = threadIdx.x;
    if (h <= Hh) {
        if (h == Hh) rs[Hh] = T;
        else {
            int lo = 0, hi = T;
            while (lo < hi) {
                int mid = (lo + hi) >> 1;
                if (rows[mid] < h) lo = mid + 1; else hi = mid;
            }
            rs[h] = lo;
        }
    }
    __syncthreads();
    if (threadIdx.x == 0) {
        int acc = 0;
        for (int i = 0; i < Hh; ++i) {
            rs8[i] = acc;
            int cnt = rs[i + 1] - rs[i];
            acc += (cnt + 7) & ~7;
        }
        rs8[Hh] = acc;
    }
}

// -------------------------------- pack x chunk -> A_ext (p,q), h-major rows
__global__ __launch_bounds__(256) void pack_kernel(const float* __restrict__ x,
                                                   bf16* __restrict__ Ap,
                                                   bf16* __restrict__ Aq,
                                                   int hbase) {
    int g = blockIdx.x * 256 + threadIdx.x;
    if (g >= CM * KF3) return;
    int wext = g % KF3;
    int r = g / KF3;
    int hl = r >> 7;
    int bc = r & 127;
    const float* xrow = x + ((size_t)bc * Hh + hbase + hl) * Ww;
    int blk = wext / 384;
    int w = wext - blk * 384;
    float p = 0.f, q = 0.f;
    if (w == 0 || w == 360) {
        p = xrow[w];
    } else if (w < 360) {
        float a = xrow[w];
        float b = xrow[Ww - w];
        p = a + b;
        q = a - b;
    }
    bf16 phi = __float2bfloat16(p);
    bf16 qhi = __float2bfloat16(q);
    if (blk == 1) {
        Ap[g] = __float2bfloat16(p - __bfloat162float(phi));
        Aq[g] = __float2bfloat16(q - __bfloat162float(qhi));
    } else {
        Ap[g] = phi;
        Aq[g] = qhi;
    }
}

// ----------------------------------------------------------------- zero fill
__global__ __launch_bounds__(256) void fill_zero_kernel(uint4* __restrict__ p, long n) {
    long i = (long)blockIdx.x * 256 + threadIdx.x;
    long stride = (long)gridDim.x * 256;
    uint4 z = make_uint4(0u, 0u, 0u, 0u);
    for (; i < n; i += stride) p[i] = z;
}

// ------------------- fwd MFMA GEMM, h-uniform tiles + early exit + compact C
__global__ __launch_bounds__(256) void gemm_fwd_compact_kernel(
    const bf16* __restrict__ Ap, const bf16* __restrict__ Aq,
    const bf16* __restrict__ Bc, const bf16* __restrict__ Bsm,
    float* __restrict__ Xcr, float* __restrict__ Xci,
    const int* __restrict__ rs, int T128, int hbase)
{
    __shared__ __align__(128) bf16 As[128][64];
    __shared__ __align__(128) bf16 Bs[128][64];
    const int h = hbase + blockIdx.x;       // one latitude per m-tile
    const int t0 = rs[h];
    const int cnt = rs[h + 1] - t0;
    const int n0 = blockIdx.y * 128;
    if (n0 >= cnt) return;                   // tile stores nothing: dead work
    const bf16* A  = blockIdx.z ? Aq : Ap;
    const bf16* Bt = blockIdx.z ? Bsm : Bc;
    float* Xc      = blockIdx.z ? Xci : Xcr;
    const int tid = threadIdx.x;
    const int lane = tid & 63;
    const int wave = tid >> 6;
    const int m0 = blockIdx.x * 128;
    const int wr = (wave >> 1) * 64;
    const int wc = (wave & 1) * 64;
    const int srow = tid >> 3;
    const int scol = (tid & 7) << 3;
    f32x4 acc[4][4] = {};
    for (int k0 = 0; k0 < KF3; k0 += 64) {
#pragma unroll
        for (int i = 0; i < 4; ++i) {
            const bf16* ga = A  + (size_t)(m0 + i * 32 + srow) * KF3 + k0 + scol;
            const bf16* gb = Bt + (size_t)(n0 + i * 32 + srow) * KF3 + k0 + scol;
            gload_lds16(ga, ((char*)&As[0][0]) + (size_t)(i * 256 + tid) * 16);
            gload_lds16(gb, ((char*)&Bs[0][0]) + (size_t)(i * 256 + tid) * 16);
        }
        __syncthreads();
#pragma unroll
        for (int kk = 0; kk < 64; kk += 32) {
            s16x8 a[4], b[4];
#pragma unroll
            for (int m = 0; m < 4; ++m)
                a[m] = *(const s16x8*)&As[wr + m * 16 + (lane & 15)][kk + (lane >> 4) * 8];
#pragma unroll
            for (int n = 0; n < 4; ++n)
                b[n] = *(const s16x8*)&Bs[wc + n * 16 + (lane & 15)][kk + (lane >> 4) * 8];
#pragma unroll
            for (int m = 0; m < 4; ++m)
#pragma unroll
                for (int n = 0; n < 4; ++n)
                    acc[m][n] = __builtin_amdgcn_mfma_f32_16x16x32_bf16(a[m], b[n], acc[m][n], 0, 0, 0);
        }
        __syncthreads();
    }
    const int rbase = (lane >> 4) * 4;
    const int cidx = lane & 15;
#pragma unroll
    for (int m = 0; m < 4; ++m) {
#pragma unroll
        for (int r = 0; r < 4; ++r) {
            int bc = wr + m * 16 + rbase + r;   // local row within h-tile
#pragma unroll
            for (int n = 0; n < 4; ++n) {
                int j = n0 + wc + n * 16 + cidx;
                if (j < cnt)
                    Xc[(size_t)bc * T128 + t0 + j] = acc[m][n][r];
            }
        }
    }
}

// -------------- inverse GEMM, h-uniform tiles + K-tile early-skip; y h-major
// C row = h*128 + bc, stride NI, bf16.
__global__ __launch_bounds__(256) void gemm_inv_kernel(
    const bf16* __restrict__ Xgr, const bf16* __restrict__ Xgi,
    const bf16* __restrict__ Bt, const int* __restrict__ rs8,
    bf16* __restrict__ C, int T8cap)
{
    __shared__ __align__(128) bf16 As[128][64];
    __shared__ __align__(128) bf16 Bs[128][64];
    const int h = blockIdx.x;               // one latitude per m-tile
    const int t0v = rs8[h];
    const int cnt8 = rs8[h + 1] - t0v;
    const int n0 = blockIdx.y * 128;
    const int tid = threadIdx.x;
    const int lane = tid & 63;
    const int wave = tid >> 6;
    const int wr = (wave >> 1) * 64;
    const int wc = (wave & 1) * 64;
    const int srow = tid >> 3;
    const int scol = (tid & 7) << 3;
    f32x4 acc[4][4] = {};
    for (int k0 = 0; k0 < KI; k0 += 64) {
        const int jb = (k0 < 384) ? k0 : (k0 - 384);
        if (jb >= cnt8) continue;           // A-tile all zero: acc += 0, skip
        const bf16* base = (k0 < 384) ? Xgr : Xgi;
        const int j0 = jb + scol;
#pragma unroll
        for (int i = 0; i < 4; ++i)
            gload_lds16(Bt + (size_t)(n0 + i * 32 + srow) * KI + k0 + scol,
                        ((char*)&Bs[0][0]) + (size_t)(i * 256 + tid) * 16);
#pragma unroll
        for (int i = 0; i < 4; ++i) {
            int bc = i * 32 + srow;
            s16x8 v = (s16x8){0, 0, 0, 0, 0, 0, 0, 0};
            if (j0 < cnt8)
                v = *(const s16x8*)(base + (size_t)bc * T8cap + t0v + j0);
            *(s16x8*)&As[bc][scol] = v;
        }
        __syncthreads();
#pragma unroll
        for (int kk = 0; kk < 64; kk += 32) {
            s16x8 a[4], b[4];
#pragma unroll
            for (int m = 0; m < 4; ++m)
                a[m] = *(const s16x8*)&As[wr + m * 16 + (lane & 15)][kk + (lane >> 4) * 8];
#pragma unroll
            for (int n = 0; n < 4; ++n)
                b[n] = *(const s16x8*)&Bs[wc + n * 16 + (lane & 15)][kk + (lane >> 4) * 8];
#pragma unroll
            for (int m = 0; m < 4; ++m)
#pragma unroll
                for (int n = 0; n < 4; ++n)
                    acc[m][n] = __builtin_amdgcn_mfma_f32_16x16x32_bf16(a[m], b[n], acc[m][n], 0, 0, 0);
        }
        __syncthreads();
    }
    const int rbase = (lane >> 4) * 4;
    const int cidx = lane & 15;
#pragma unroll
    for (int m = 0; m < 4; ++m) {
#pragma unroll
        for (int n = 0; n < 4; ++n) {
            int gcol = n0 + wc + n * 16 + cidx;
            if (gcol < NSTORE_INV) {
#pragma unroll
                for (int r = 0; r < 4; ++r) {
                    int bc = wr + m * 16 + rbase + r;
                    C[(size_t)(h * BC + bc) * NI + gcol] = __float2bfloat16(acc[m][n][r]);
                }
            }
        }
    }
}

// ------------------------------------------------ fused middle stage (v3)
// VERBATIM green round-10/13/14/15 middle.
__device__ __forceinline__ float gelu_exact(float v) {
    return 0.5f * v * (1.0f + erff(v * 0.7071067811865476f));
}

__global__ __launch_bounds__(256, 4) void middle_fused_kernel(
    const float* __restrict__ Xcr, const float* __restrict__ Xci,
    bf16* __restrict__ Xgr, bf16* __restrict__ Xgi,
    const float* __restrict__ mean_r, const float* __restrict__ mean_i,
    const float* __restrict__ stdv,
    const float* __restrict__ mags_r, const float* __restrict__ mags_i,
    const float* __restrict__ bias_r, const float* __restrict__ bias_i,
    const bf16* __restrict__ W1f, const bf16* __restrict__ W2f,
    const float* __restrict__ brelu_p,
    const float* __restrict__ glu_mags, const float* __restrict__ glu_phases,
    const int* __restrict__ rows, const int* __restrict__ cols,
    const int* __restrict__ rs8,
    int T, int T128, int T8cap)
{
    __shared__ __align__(16) char smemA[32 * 264 * 2];   // 16,896 B
    __shared__ __align__(16) char smemB[32 * 264 * 2];
    bf16*  H1 = (bf16*)smemA;    // [32][264] hi/lo split input
    float* aL = (float*)smemA;   // [32][132] GEMM1 result
    float* cL = (float*)smemA;   // [32][132] GEMM2 result
    bf16*  H2 = (bf16*)smemB;    // [32][264] gelu output

    const int tid = threadIdx.x;
    const int b = blockIdx.y;
    const int t0 = blockIdx.x * 32;
    const int tl = tid & 31;
    const int cg = tid >> 5;          // 0..7
    const int t = t0 + tl;
    const bool valid = (t < T);
    const int lane = tid & 63;
    const int wv = tid >> 6;          // 0..3
    const int frow = lane & 15;
    const int fcol = (lane >> 4) * 8;
    const s16x8* W1v = (const s16x8*)W1f;
    const s16x8* W2v = (const s16x8*)W2f;
    constexpr int ASRC[6] = {0, 1, 2, 3, 0, 1};
    constexpr int BSRC[6] = {0, 1, 0, 1, 2, 3};

    // ---- phase 1: normalize -> H1 (lane=t, coalesced global reads)
    {
        float mr = 0.f, mi_ = 0.f, isd = 0.f;
        if (valid) { mr = mean_r[t]; mi_ = mean_i[t]; isd = 1.0f / (1e-12f + stdv[t]); }
        s16x8 vhr, vhi, vlr, vli;
#pragma unroll
        for (int ci = 0; ci < 8; ++ci) {
            int c = cg * 8 + ci;
            float xr = 0.f, xi = 0.f;
            if (valid) {
                xr = Xcr[(size_t)(b * 64 + c) * T128 + t];
                xi = Xci[(size_t)(b * 64 + c) * T128 + t];
            }
            float hr = (xr - mr) * isd;
            float hi = (xi - mi_) * isd;
            float h1r = fmaf(hr, mags_r[c], fmaf(-hi, mags_i[c], bias_r[c]));
            float h1i = fmaf(hr, mags_i[c], fmaf(hi, mags_r[c], bias_i[c]));
            short rh = f2bfs(h1r), ih = f2bfs(h1i);
            vhr[ci] = rh; vhi[ci] = ih;
            vlr[ci] = f2bfs(h1r - bfs2f(rh));
            vli[ci] = f2bfs(h1i - bfs2f(ih));
        }
        *(s16x8*)&H1[tl * 264 + cg * 8]       = vhr;
        *(s16x8*)&H1[tl * 264 + 64 + cg * 8]  = vhi;
        *(s16x8*)&H1[tl * 264 + 128 + cg * 8] = vlr;
        *(s16x8*)&H1[tl * 264 + 192 + cg * 8] = vli;
    }
    __syncthreads();

    // ---- GEMM1: A = H1 [32][264], B frags direct from W1f (L2)
    f32x4 acc[2][2] = {};
#pragma unroll
    for (int lc = 0; lc < 6; ++lc) {
        const int ka = ASRC[lc] * 64;
        const int kb = BSRC[lc];
#pragma unroll
        for (int kh = 0; kh < 2; ++kh) {
            s16x8 a0 = *(const s16x8*)&H1[frow * 264 + ka + kh * 32 + fcol];
            s16x8 a1 = *(const s16x8*)&H1[(16 + frow) * 264 + ka + kh * 32 + fcol];
#pragma unroll
            for (int n = 0; n < 2; ++n) {
                s16x8 bfv = W1v[(size_t)((((wv * 2 + n) * 4 + kb) * 2 + kh) * 64 + lane)];
                acc[0][n] = __builtin_amdgcn_mfma_f32_16x16x32_bf16(a0, bfv, acc[0][n], 0, 0, 0);
                acc[1][n] = __builtin_amdgcn_mfma_f32_16x16x32_bf16(a1, bfv, acc[1][n], 0, 0, 0);
            }
        }
    }
    __syncthreads();

    // ---- phase 3: acc -> aL (overwrites H1)
    const int rbase = (lane >> 4) * 4;
    const int cidx = lane & 15;
#pragma unroll
    for (int m = 0; m < 2; ++m)
#pragma unroll
        for (int n = 0; n < 2; ++n)
#pragma unroll
            for (int r = 0; r < 4; ++r)
                aL[(m * 16 + rbase + r) * 132 + wv * 32 + n * 16 + cidx] = acc[m][n][r];
    __syncthreads();

    // ---- phase 4: gelu (lane=t) -> H2
    {
        const float brelu = brelu_p[0];
        f32x4 ar0 = *(const f32x4*)&aL[tl * 132 + cg * 8];
        f32x4 ar1 = *(const f32x4*)&aL[tl * 132 + cg * 8 + 4];
        f32x4 ai0 = *(const f32x4*)&aL[tl * 132 + 64 + cg * 8];
        f32x4 ai1 = *(const f32x4*)&aL[tl * 132 + 64 + cg * 8 + 4];
        s16x8 vhr, vhi, vlr, vli;
#pragma unroll
        for (int ci = 0; ci < 8; ++ci) {
            float ar = (ci < 4) ? ar0[ci & 3] : ar1[ci & 3];
            float ai = (ci < 4) ? ai0[ci & 3] : ai1[ci & 3];
            float r = sqrtf(ar * ar + ai * ai);
            float g = gelu_exact(r + brelu);
            float h2r, h2i;
            if (r > 0.f) { float f = g / r; h2r = f * ar; h2i = f * ai; }
            else { h2r = g; h2i = 0.f; }
            short rh = f2bfs(h2r), ih = f2bfs(h2i);
            vhr[ci] = rh; vhi[ci] = ih;
            vlr[ci] = f2bfs(h2r - bfs2f(rh));
            vli[ci] = f2bfs(h2i - bfs2f(ih));
        }
        *(s16x8*)&H2[tl * 264 + cg * 8]       = vhr;
        *(s16x8*)&H2[tl * 264 + 64 + cg * 8]  = vhi;
        *(s16x8*)&H2[tl * 264 + 128 + cg * 8] = vlr;
        *(s16x8*)&H2[tl * 264 + 192 + cg * 8] = vli;
    }
    __syncthreads();

    // ---- GEMM2: A = H2, B frags from W2f
    f32x4 acc2[2][2] = {};
#pragma unroll
    for (int lc = 0; lc < 6; ++lc) {
        const int ka = ASRC[lc] * 64;
        const int kb = BSRC[lc];
#pragma unroll
        for (int kh = 0; kh < 2; ++kh) {
            s16x8 a0 = *(const s16x8*)&H2[frow * 264 + ka + kh * 32 + fcol];
            s16x8 a1 = *(const s16x8*)&H2[(16 + frow) * 264 + ka + kh * 32 + fcol];
#pragma unroll
            for (int n = 0; n < 2; ++n) {
                s16x8 bfv = W2v[(size_t)((((wv * 2 + n) * 4 + kb) * 2 + kh) * 64 + lane)];
                acc2[0][n] = __builtin_amdgcn_mfma_f32_16x16x32_bf16(a0, bfv, acc2[0][n], 0, 0, 0);
                acc2[1][n] = __builtin_amdgcn_mfma_f32_16x16x32_bf16(a1, bfv, acc2[1][n], 0, 0, 0);
            }
        }
    }
    // cL aliases aL (smemA): all aL reads completed before the barrier above
    // GEMM2; no thread reads smemA during GEMM2.
#pragma unroll
    for (int m = 0; m < 2; ++m)
#pragma unroll
        for (int n = 0; n < 2; ++n)
#pragma unroll
            for (int r = 0; r < 4; ++r)
                cL[(m * 16 + rbase + r) * 132 + wv * 32 + n * 16 + cidx] = acc2[m][n][r];
    __syncthreads();

    // ---- phase 8: gate + compact coalesced store (lane=t)
    if (valid) {
        int h = rows[t], j = cols[t];
        size_t wbase = (size_t)rs8[h] + j;
        f32x4 cr0 = *(const f32x4*)&cL[tl * 132 + cg * 8];
        f32x4 cr1 = *(const f32x4*)&cL[tl * 132 + cg * 8 + 4];
        f32x4 ci0 = *(const f32x4*)&cL[tl * 132 + 64 + cg * 8];
        f32x4 ci1 = *(const f32x4*)&cL[tl * 132 + 64 + cg * 8 + 4];
#pragma unroll
        for (int ci = 0; ci < 8; ++ci) {
            int c = cg * 8 + ci;
            float cr  = (ci < 4) ? cr0[ci & 3] : cr1[ci & 3];
            float cii = (ci < 4) ? ci0[ci & 3] : ci1[ci & 3];
            float xr = Xcr[(size_t)(b * 64 + c) * T128 + t];
            float xi = Xci[(size_t)(b * 64 + c) * T128 + t];
            float r3 = sqrtf(cr * cr + cii * cii);
            float gm = glu_mags[(size_t)c * T + t];
            float gp = glu_phases[(size_t)c * T + t];
            float sg = 1.0f / (1.0f + expf(-(r3 + gm)));
            float ux, uy;
            if (r3 > 0.f) { float ir3 = 1.0f / r3; ux = cr * ir3; uy = cii * ir3; }
            else { ux = 1.f; uy = 0.f; }
            float sp, cp;
            sincosf(gp, &sp, &cp);
            float gx = sg * (ux * cp - uy * sp);
            float gy = sg * (ux * sp + uy * cp);
            size_t base = (size_t)(b * 64 + c) * T8cap + wbase;
            Xgr[base] = __float2bfloat16(xr * gx - xi * gy);
            Xgi[base] = __float2bfloat16(xr * gy + xi * gx);
        }
    }
}

// ------- depthwise conv + add (bf16 y, h-major rows, 8-wide, XCD swizzle)
__global__ __launch_bounds__(256) void conv_add_kernel(
    const bf16* __restrict__ y, const float* __restrict__ dw,
    float* __restrict__ out)
{
    const int nb = gridDim.x;
    const int chunk = nb >> 3;
    const int orig = blockIdx.x;
    const int swz = (orig & 7) * chunk + (orig >> 3);   // bijective: nb % 8 == 0
    int g = swz * 256 + threadIdx.x;
    int w8 = g % 90;
    int rem = g / 90;
    int h = rem % Hh;
    int bc = rem / Hh;
    int c = bc & (Cc - 1);
    int w = w8 * 8;
    int walt = (w >= Ww / 2) ? (w - Ww / 2) : (w + Ww / 2);
    float acc[8];
    {
        s16x8 v0 = *(const s16x8*)&y[((size_t)h * BC + bc) * NI + w];
#pragma unroll
        for (int e = 0; e < 8; ++e) acc[e] = bfs2f(v0[e]);
    }
#pragma unroll
    for (int k = 0; k < 11; ++k) {
        int hp = h + k - 5;
        int hh, ww;
        if (hp < 0)        { hh = -1 - hp;         ww = walt; }
        else if (hp >= Hh) { hh = 2 * Hh - 1 - hp; ww = walt; }
        else               { hh = hp;              ww = w; }
        s16x8 v = *(const s16x8*)&y[((size_t)hh * BC + bc) * NI + ww];
        float dwk = dw[c * 11 + k];
#pragma unroll
        for (int e = 0; e < 8; ++e)
            acc[e] = fmaf(dwk, bfs2f(v[e]), acc[e]);
    }
    float* ob = &out[((size_t)bc * Hh + h) * Ww + w];
    *(float4*)&ob[0] = make_float4(acc[0], acc[1], acc[2], acc[3]);
    *(float4*)&ob[4] = make_float4(acc[4], acc[5], acc[6], acc[7]);
}

// ------------------------------------------------------------------ launch
extern "C" void kernel_launch(void* const* d_in, const int* in_sizes, int n_in,
                              void* d_out, int out_size, void* d_ws, size_t ws_size,
                              hipStream_t stream)
{
    const float* x      = (const float*)d_in[0];
    const float* mean_r = (const float*)d_in[1];
    const float* mean_i = (const float*)d_in[2];
    const float* stdv   = (const float*)d_in[3];
    const float* mags_r = (const float*)d_in[4];
    const float* mags_i = (const float*)d_in[5];
    const float* bias_r = (const float*)d_in[6];
    const float* bias_i = (const float*)d_in[7];
    const float* w1_r   = (const float*)d_in[8];
    const float* w1_i   = (const float*)d_in[9];
    const float* brelu  = (const float*)d_in[10];
    const float* w2_r   = (const float*)d_in[11];
    const float* w2_i   = (const float*)d_in[12];
    const float* glu_m  = (const float*)d_in[13];
    const float* glu_p  = (const float*)d_in[14];
    const float* dw     = (const float*)d_in[15];
    const int*   rows   = (const int*)d_in[16];
    const int*   cols   = (const int*)d_in[17];
    const int T = in_sizes[16];
    const int T128 = ((T + 127) / 128) * 128;
    const int T8cap = ((T + 7 * Hh) + 127) & ~127;

    char* ws = (char*)d_ws;
    const size_t SApc  = (size_t)CM * KF3 * 2;            // 53,084,160
    const size_t XC_SZ = (size_t)BC * T128 * 4;           // ~42.7 MB
    const size_t XG_SZ = (size_t)BC * T8cap * 2;          // ~22.0 MB
    bf16*  Ap  = (bf16*)ws;
    bf16*  Aq  = (bf16*)(ws + SApc);
    float* Xcr = (float*)(ws + 2 * SApc);
    float* Xci = (float*)(ws + 2 * SApc + XC_SZ);
    bf16*  Xgr = (bf16*)ws;
    bf16*  Xgi = (bf16*)(ws + XG_SZ);
    bf16*  y   = (bf16*)(ws + 2 * XG_SZ);
    size_t boff = 2 * SApc + 2 * XC_SZ;                   // ~191.5 MB
    bf16*  Bce = (bf16*)(ws + boff);
    bf16*  Bse = (bf16*)(ws + boff + (size_t)NF * KF3 * 2);
    bf16*  Bti = (bf16*)(ws + boff + 2 * (size_t)NF * KF3 * 2);
    bf16*  W1f = (bf16*)(ws + boff + 2 * (size_t)NF * KF3 * 2 + (size_t)NI * KI * 2);
    bf16*  W2f = W1f + 32768;
    int*   rs  = (int*)(W2f + 32768);
    int*   rs8 = rs + (Hh + 2);

    build_bfwd_kernel<<<(NF * KF3 + 255) / 256, 256, 0, stream>>>(Bce, Bse);
    build_binv_kernel<<<(NI * KI + 255) / 256, 256, 0, stream>>>(Bti);
    build_wf_kernel<<<(2 * 32768 + 255) / 256, 256, 0, stream>>>(
        w1_r, w1_i, w2_r, w2_i, W1f, W2f);
    row_starts_kernel<<<1, 512, 0, stream>>>(rows, T, rs, rs8);

    for (int ch = 0; ch < CHUNKS; ++ch) {
        pack_kernel<<<(CM * KF3 + 255) / 256, 256, 0, stream>>>(
            x, Ap, Aq, ch * HPC);
        gemm_fwd_compact_kernel<<<dim3(CM / 128, NF / 128, 2), 256, 0, stream>>>(
            Ap, Aq, Bce, Bse, Xcr, Xci, rs, T128, ch * HPC);
    }

    fill_zero_kernel<<<2048, 256, 0, stream>>>((uint4*)Xgr, (long)(2 * XG_SZ / 16));

    const int nT32 = (T + 31) / 32;
    middle_fused_kernel<<<dim3(nT32, Bb), 256, 0, stream>>>(
        Xcr, Xci, Xgr, Xgi, mean_r, mean_i, stdv, mags_r, mags_i,
        bias_r, bias_i, W1f, W2f, brelu, glu_m, glu_p, rows, cols, rs8,
        T, T128, T8cap);

    gemm_inv_kernel<<<dim3(Hh, NI / 128), 256, 0, stream>>>(
        Xgr, Xgi, Bti, rs8, y, T8cap);

    conv_add_kernel<<<(Bb * Cc * Hh * 90) / 256, 256, 0, stream>>>(y, dw, (float*)d_out);
}

// Round 17
// 518.850 us; speedup vs baseline: 2.1679x; 1.1213x over previous
//
#include <hip/hip_runtime.h>
#include <hip/hip_bf16.h>
#include <math.h>

#define Hh 360
#define Ww 720
#define Cc 64
#define Bb 2
#define BC (Bb*Cc)        // 128
#define Mrows (BC*Hh)     // 46080
#define CHUNKS 2
#define CM (Mrows/CHUNKS) // 23040
#define HPC (Hh/CHUNKS)   // 180 latitudes per chunk
#define KA 768            // A row: [hi(384) | lo(384)]
#define KF3 1152          // GEMM K loop: [hi.Bhi | lo.Bhi | hi.Blo]
#define NF 384            // fwd N (361 bins padded)
#define KI 768            // inv K: [Re(384) | Im(384)]
#define NI 768            // inv C row stride (720 used)
#define NSTORE_INV 720
#define SCALE 0.037267799624996496f   // 1/sqrt(720)
#define TWO_PI 6.2831853071795864769f

typedef __attribute__((ext_vector_type(8))) short s16x8;
typedef __attribute__((ext_vector_type(4))) float f32x4;
typedef __hip_bfloat16 bf16;

__device__ __forceinline__ void gload_lds16(const void* g, void* l) {
    __builtin_amdgcn_global_load_lds(
        (const __attribute__((address_space(1))) unsigned int*)g,
        (__attribute__((address_space(3))) unsigned int*)l, 16, 0, 0);
}
__device__ __forceinline__ short f2bfs(float v) {
    bf16 h = __float2bfloat16(v); short s; __builtin_memcpy(&s, &h, 2); return s;
}
__device__ __forceinline__ float bfs2f(short s) {
    bf16 h; __builtin_memcpy(&h, &s, 2); return __bfloat162float(h);
}

// ---------------------------------------------------------- B-matrix builds
// B stays 1152-wide: [Bhi | Bhi | Blo].
__global__ __launch_bounds__(256) void build_bfwd_kernel(bf16* __restrict__ Bc,
                                                         bf16* __restrict__ Bs) {
    int g = blockIdx.x * 256 + threadIdx.x;
    if (g >= NF * KF3) return;
    int wext = g % KF3;
    int j = g / KF3;
    int blk = wext / 384;
    int w = wext - blk * 384;
    float c = 0.f, s = 0.f;
    if (w <= 360 && j <= 360) {
        int idx = (j * w) % Ww;
        float a = (TWO_PI / Ww) * (float)idx;
        float sv, cv;
        sincosf(a, &sv, &cv);
        c = SCALE * cv;
        s = -SCALE * sv;
    }
    bf16 chi = __float2bfloat16(c);
    bf16 shi = __float2bfloat16(s);
    if (blk == 2) {
        Bc[g] = __float2bfloat16(c - __bfloat162float(chi));
        Bs[g] = __float2bfloat16(s - __bfloat162float(shi));
    } else {
        Bc[g] = chi;
        Bs[g] = shi;
    }
}

__global__ __launch_bounds__(256) void build_binv_kernel(bf16* __restrict__ Bi) {
    int g = blockIdx.x * 256 + threadIdx.x;
    if (g >= NI * KI) return;
    int k = g % KI, n = g / KI;
    float v = 0.f;
    if (n < NSTORE_INV) {
        if (k <= 360) {
            int j = k;
            float f = (j == 0 || j == 360) ? 1.f : 2.f;
            int idx = (j * n) % Ww;
            v = SCALE * f * cosf((TWO_PI / Ww) * (float)idx);
        } else if (k >= 384 && k <= 744) {
            int j = k - 384;
            int idx = (j * n) % Ww;
            v = -2.f * SCALE * sinf((TWO_PI / Ww) * (float)idx);
        }
    }
    Bi[g] = __float2bfloat16(v);
}

// W fragment-packed: s16x8 index = fid*64 + lane, fid = ((n16*4 + kb)*2 + kh).
__global__ __launch_bounds__(256) void build_wf_kernel(
    const float* __restrict__ w1_r, const float* __restrict__ w1_i,
    const float* __restrict__ w2_r, const float* __restrict__ w2_i,
    bf16* __restrict__ W1f, bf16* __restrict__ W2f)
{
    int g = blockIdx.x * 256 + threadIdx.x;
    if (g >= 2 * 32768) return;
    int which = g >> 15;
    int gg = g & 32767;
    int e = gg & 7, lane = (gg >> 3) & 63, kh = (gg >> 9) & 1;
    int kb = (gg >> 10) & 3, n16 = (gg >> 12) & 7;
    int frow = lane & 15, fcol = (lane >> 4) * 8;
    int n = n16 * 16 + frow;
    int kfull = kb * 64 + kh * 32 + fcol + e;
    int kk = kfull & 127, islo = kfull >> 7;
    const float* wr = which ? w2_r : w1_r;
    const float* wi = which ? w2_i : w1_i;
    float v;
    if (n < 64) v = (kk < 64) ? wr[n * 64 + kk] : -wi[n * 64 + kk - 64];
    else { int p = n - 64; v = (kk < 64) ? wi[p * 64 + kk] : wr[p * 64 + kk - 64]; }
    bf16 h = __float2bfloat16(v);
    bf16 out = islo ? __float2bfloat16(v - __bfloat162float(h)) : h;
    (which ? W2f : W1f)[gg] = out;
}

// ---------------------------------------- row starts (compact + 8-padded)
__global__ __launch_bounds__(512) void row_starts_kernel(const int* __restrict__ rows,
                                                         int T, int* __restrict__ rs,
                                                         int* __restrict__ rs8) {
    int h = threadIdx.x;
    if (h <= Hh) {
        if (h == Hh) rs[Hh] = T;
        else {
            int lo = 0, hi = T;
            while (lo < hi) {
                int mid = (lo + hi) >> 1;
                if (rows[mid] < h) lo = mid + 1; else hi = mid;
            }
            rs[h] = lo;
        }
    }
    __syncthreads();
    if (threadIdx.x == 0) {
        int acc = 0;
        for (int i = 0; i < Hh; ++i) {
            rs8[i] = acc;
            int cnt = rs[i + 1] - rs[i];
            acc += (cnt + 7) & ~7;
        }
        rs8[Hh] = acc;
    }
}

// ------------------- pack x chunk -> A [hi|lo] (768-wide), h-major rows
__global__ __launch_bounds__(256) void pack_kernel(const float* __restrict__ x,
                                                   bf16* __restrict__ Ap,
                                                   bf16* __restrict__ Aq,
                                                   int hbase) {
    int g = blockIdx.x * 256 + threadIdx.x;
    if (g >= CM * KA) return;
    int wext = g % KA;
    int r = g / KA;
    int hl = r >> 7;
    int bc = r & 127;
    const float* xrow = x + ((size_t)bc * Hh + hbase + hl) * Ww;
    int islo = (wext >= 384);
    int w = islo ? (wext - 384) : wext;
    float p = 0.f, q = 0.f;
    if (w == 0 || w == 360) {
        p = xrow[w];
    } else if (w < 360) {
        float a = xrow[w];
        float b = xrow[Ww - w];
        p = a + b;
        q = a - b;
    }
    bf16 phi = __float2bfloat16(p);
    bf16 qhi = __float2bfloat16(q);
    if (islo) {
        Ap[g] = __float2bfloat16(p - __bfloat162float(phi));
        Aq[g] = __float2bfloat16(q - __bfloat162float(qhi));
    } else {
        Ap[g] = phi;
        Aq[g] = qhi;
    }
}

// ----------------------------------------------------------------- zero fill
__global__ __launch_bounds__(256) void fill_zero_kernel(uint4* __restrict__ p, long n) {
    long i = (long)blockIdx.x * 256 + threadIdx.x;
    long stride = (long)gridDim.x * 256;
    uint4 z = make_uint4(0u, 0u, 0u, 0u);
    for (; i < n; i += stride) p[i] = z;
}

// ------------------- fwd MFMA GEMM, h-uniform tiles + early exit + compact C
// A is [CM][768]=[hi|lo]; K loop runs 1152 with cols [768,1152) re-reading
// A's hi block (B supplies Blo there). Bit-identical to [hi|lo|hi] layout.
__global__ __launch_bounds__(256) void gemm_fwd_compact_kernel(
    const bf16* __restrict__ Ap, const bf16* __restrict__ Aq,
    const bf16* __restrict__ Bc, const bf16* __restrict__ Bsm,
    float* __restrict__ Xcr, float* __restrict__ Xci,
    const int* __restrict__ rs, int T128, int hbase)
{
    __shared__ __align__(128) bf16 As[128][64];
    __shared__ __align__(128) bf16 Bs[128][64];
    const int h = hbase + blockIdx.x;       // one latitude per m-tile
    const int t0 = rs[h];
    const int cnt = rs[h + 1] - t0;
    const int n0 = blockIdx.y * 128;
    if (n0 >= cnt) return;                   // tile stores nothing: dead work
    const bf16* A  = blockIdx.z ? Aq : Ap;
    const bf16* Bt = blockIdx.z ? Bsm : Bc;
    float* Xc      = blockIdx.z ? Xci : Xcr;
    const int tid = threadIdx.x;
    const int lane = tid & 63;
    const int wave = tid >> 6;
    const int m0 = blockIdx.x * 128;
    const int wr = (wave >> 1) * 64;
    const int wc = (wave & 1) * 64;
    const int srow = tid >> 3;
    const int scol = (tid & 7) << 3;
    f32x4 acc[4][4] = {};
    for (int k0 = 0; k0 < KF3; k0 += 64) {
        const int ka0 = (k0 >= 768) ? (k0 - 768) : k0;
#pragma unroll
        for (int i = 0; i < 4; ++i) {
            const bf16* ga = A  + (size_t)(m0 + i * 32 + srow) * KA + ka0 + scol;
            const bf16* gb = Bt + (size_t)(n0 + i * 32 + srow) * KF3 + k0 + scol;
            gload_lds16(ga, ((char*)&As[0][0]) + (size_t)(i * 256 + tid) * 16);
            gload_lds16(gb, ((char*)&Bs[0][0]) + (size_t)(i * 256 + tid) * 16);
        }
        __syncthreads();
#pragma unroll
        for (int kk = 0; kk < 64; kk += 32) {
            s16x8 a[4], b[4];
#pragma unroll
            for (int m = 0; m < 4; ++m)
                a[m] = *(const s16x8*)&As[wr + m * 16 + (lane & 15)][kk + (lane >> 4) * 8];
#pragma unroll
            for (int n = 0; n < 4; ++n)
                b[n] = *(const s16x8*)&Bs[wc + n * 16 + (lane & 15)][kk + (lane >> 4) * 8];
#pragma unroll
            for (int m = 0; m < 4; ++m)
#pragma unroll
                for (int n = 0; n < 4; ++n)
                    acc[m][n] = __builtin_amdgcn_mfma_f32_16x16x32_bf16(a[m], b[n], acc[m][n], 0, 0, 0);
        }
        __syncthreads();
    }
    const int rbase = (lane >> 4) * 4;
    const int cidx = lane & 15;
#pragma unroll
    for (int m = 0; m < 4; ++m) {
#pragma unroll
        for (int r = 0; r < 4; ++r) {
            int bc = wr + m * 16 + rbase + r;   // local row within h-tile
#pragma unroll
            for (int n = 0; n < 4; ++n) {
                int j = n0 + wc + n * 16 + cidx;
                if (j < cnt)
                    Xc[(size_t)bc * T128 + t0 + j] = acc[m][n][r];
            }
        }
    }
}

// -------------- inverse GEMM, h-uniform tiles + K-tile early-skip; y h-major
__global__ __launch_bounds__(256) void gemm_inv_kernel(
    const bf16* __restrict__ Xgr, const bf16* __restrict__ Xgi,
    const bf16* __restrict__ Bt, const int* __restrict__ rs8,
    bf16* __restrict__ C, int T8cap)
{
    __shared__ __align__(128) bf16 As[128][64];
    __shared__ __align__(128) bf16 Bs[128][64];
    const int h = blockIdx.x;               // one latitude per m-tile
    const int t0v = rs8[h];
    const int cnt8 = rs8[h + 1] - t0v;
    const int n0 = blockIdx.y * 128;
    const int tid = threadIdx.x;
    const int lane = tid & 63;
    const int wave = tid >> 6;
    const int wr = (wave >> 1) * 64;
    const int wc = (wave & 1) * 64;
    const int srow = tid >> 3;
    const int scol = (tid & 7) << 3;
    f32x4 acc[4][4] = {};
    for (int k0 = 0; k0 < KI; k0 += 64) {
        const int jb = (k0 < 384) ? k0 : (k0 - 384);
        if (jb >= cnt8) continue;           // A-tile all zero: acc += 0, skip
        const bf16* base = (k0 < 384) ? Xgr : Xgi;
        const int j0 = jb + scol;
#pragma unroll
        for (int i = 0; i < 4; ++i)
            gload_lds16(Bt + (size_t)(n0 + i * 32 + srow) * KI + k0 + scol,
                        ((char*)&Bs[0][0]) + (size_t)(i * 256 + tid) * 16);
#pragma unroll
        for (int i = 0; i < 4; ++i) {
            int bc = i * 32 + srow;
            s16x8 v = (s16x8){0, 0, 0, 0, 0, 0, 0, 0};
            if (j0 < cnt8)
                v = *(const s16x8*)(base + (size_t)bc * T8cap + t0v + j0);
            *(s16x8*)&As[bc][scol] = v;
        }
        __syncthreads();
#pragma unroll
        for (int kk = 0; kk < 64; kk += 32) {
            s16x8 a[4], b[4];
#pragma unroll
            for (int m = 0; m < 4; ++m)
                a[m] = *(const s16x8*)&As[wr + m * 16 + (lane & 15)][kk + (lane >> 4) * 8];
#pragma unroll
            for (int n = 0; n < 4; ++n)
                b[n] = *(const s16x8*)&Bs[wc + n * 16 + (lane & 15)][kk + (lane >> 4) * 8];
#pragma unroll
            for (int m = 0; m < 4; ++m)
#pragma unroll
                for (int n = 0; n < 4; ++n)
                    acc[m][n] = __builtin_amdgcn_mfma_f32_16x16x32_bf16(a[m], b[n], acc[m][n], 0, 0, 0);
        }
        __syncthreads();
    }
    const int rbase = (lane >> 4) * 4;
    const int cidx = lane & 15;
#pragma unroll
    for (int m = 0; m < 4; ++m) {
#pragma unroll
        for (int n = 0; n < 4; ++n) {
            int gcol = n0 + wc + n * 16 + cidx;
            if (gcol < NSTORE_INV) {
#pragma unroll
                for (int r = 0; r < 4; ++r) {
                    int bc = wr + m * 16 + rbase + r;
                    C[(size_t)(h * BC + bc) * NI + gcol] = __float2bfloat16(acc[m][n][r]);
                }
            }
        }
    }
}

// ------------------------------------------------ fused middle stage (v3)
// VERBATIM green round-10..16 middle.
__device__ __forceinline__ float gelu_exact(float v) {
    return 0.5f * v * (1.0f + erff(v * 0.7071067811865476f));
}

__global__ __launch_bounds__(256, 4) void middle_fused_kernel(
    const float* __restrict__ Xcr, const float* __restrict__ Xci,
    bf16* __restrict__ Xgr, bf16* __restrict__ Xgi,
    const float* __restrict__ mean_r, const float* __restrict__ mean_i,
    const float* __restrict__ stdv,
    const float* __restrict__ mags_r, const float* __restrict__ mags_i,
    const float* __restrict__ bias_r, const float* __restrict__ bias_i,
    const bf16* __restrict__ W1f, const bf16* __restrict__ W2f,
    const float* __restrict__ brelu_p,
    const float* __restrict__ glu_mags, const float* __restrict__ glu_phases,
    const int* __restrict__ rows, const int* __restrict__ cols,
    const int* __restrict__ rs8,
    int T, int T128, int T8cap)
{
    __shared__ __align__(16) char smemA[32 * 264 * 2];   // 16,896 B
    __shared__ __align__(16) char smemB[32 * 264 * 2];
    bf16*  H1 = (bf16*)smemA;    // [32][264] hi/lo split input
    float* aL = (float*)smemA;   // [32][132] GEMM1 result
    float* cL = (float*)smemA;   // [32][132] GEMM2 result
    bf16*  H2 = (bf16*)smemB;    // [32][264] gelu output

    const int tid = threadIdx.x;
    const int b = blockIdx.y;
    const int t0 = blockIdx.x * 32;
    const int tl = tid & 31;
    const int cg = tid >> 5;          // 0..7
    const int t = t0 + tl;
    const bool valid = (t < T);
    const int lane = tid & 63;
    const int wv = tid >> 6;          // 0..3
    const int frow = lane & 15;
    const int fcol = (lane >> 4) * 8;
    const s16x8* W1v = (const s16x8*)W1f;
    const s16x8* W2v = (const s16x8*)W2f;
    constexpr int ASRC[6] = {0, 1, 2, 3, 0, 1};
    constexpr int BSRC[6] = {0, 1, 0, 1, 2, 3};

    // ---- phase 1: normalize -> H1 (lane=t, coalesced global reads)
    {
        float mr = 0.f, mi_ = 0.f, isd = 0.f;
        if (valid) { mr = mean_r[t]; mi_ = mean_i[t]; isd = 1.0f / (1e-12f + stdv[t]); }
        s16x8 vhr, vhi, vlr, vli;
#pragma unroll
        for (int ci = 0; ci < 8; ++ci) {
            int c = cg * 8 + ci;
            float xr = 0.f, xi = 0.f;
            if (valid) {
                xr = Xcr[(size_t)(b * 64 + c) * T128 + t];
                xi = Xci[(size_t)(b * 64 + c) * T128 + t];
            }
            float hr = (xr - mr) * isd;
            float hi = (xi - mi_) * isd;
            float h1r = fmaf(hr, mags_r[c], fmaf(-hi, mags_i[c], bias_r[c]));
            float h1i = fmaf(hr, mags_i[c], fmaf(hi, mags_r[c], bias_i[c]));
            short rh = f2bfs(h1r), ih = f2bfs(h1i);
            vhr[ci] = rh; vhi[ci] = ih;
            vlr[ci] = f2bfs(h1r - bfs2f(rh));
            vli[ci] = f2bfs(h1i - bfs2f(ih));
        }
        *(s16x8*)&H1[tl * 264 + cg * 8]       = vhr;
        *(s16x8*)&H1[tl * 264 + 64 + cg * 8]  = vhi;
        *(s16x8*)&H1[tl * 264 + 128 + cg * 8] = vlr;
        *(s16x8*)&H1[tl * 264 + 192 + cg * 8] = vli;
    }
    __syncthreads();

    // ---- GEMM1: A = H1 [32][264], B frags direct from W1f (L2)
    f32x4 acc[2][2] = {};
#pragma unroll
    for (int lc = 0; lc < 6; ++lc) {
        const int ka = ASRC[lc] * 64;
        const int kb = BSRC[lc];
#pragma unroll
        for (int kh = 0; kh < 2; ++kh) {
            s16x8 a0 = *(const s16x8*)&H1[frow * 264 + ka + kh * 32 + fcol];
            s16x8 a1 = *(const s16x8*)&H1[(16 + frow) * 264 + ka + kh * 32 + fcol];
#pragma unroll
            for (int n = 0; n < 2; ++n) {
                s16x8 bfv = W1v[(size_t)((((wv * 2 + n) * 4 + kb) * 2 + kh) * 64 + lane)];
                acc[0][n] = __builtin_amdgcn_mfma_f32_16x16x32_bf16(a0, bfv, acc[0][n], 0, 0, 0);
                acc[1][n] = __builtin_amdgcn_mfma_f32_16x16x32_bf16(a1, bfv, acc[1][n], 0, 0, 0);
            }
        }
    }
    __syncthreads();

    // ---- phase 3: acc -> aL (overwrites H1)
    const int rbase = (lane >> 4) * 4;
    const int cidx = lane & 15;
#pragma unroll
    for (int m = 0; m < 2; ++m)
#pragma unroll
        for (int n = 0; n < 2; ++n)
#pragma unroll
            for (int r = 0; r < 4; ++r)
                aL[(m * 16 + rbase + r) * 132 + wv * 32 + n * 16 + cidx] = acc[m][n][r];
    __syncthreads();

    // ---- phase 4: gelu (lane=t) -> H2
    {
        const float brelu = brelu_p[0];
        f32x4 ar0 = *(const f32x4*)&aL[tl * 132 + cg * 8];
        f32x4 ar1 = *(const f32x4*)&aL[tl * 132 + cg * 8 + 4];
        f32x4 ai0 = *(const f32x4*)&aL[tl * 132 + 64 + cg * 8];
        f32x4 ai1 = *(const f32x4*)&aL[tl * 132 + 64 + cg * 8 + 4];
        s16x8 vhr, vhi, vlr, vli;
#pragma unroll
        for (int ci = 0; ci < 8; ++ci) {
            float ar = (ci < 4) ? ar0[ci & 3] : ar1[ci & 3];
            float ai = (ci < 4) ? ai0[ci & 3] : ai1[ci & 3];
            float r = sqrtf(ar * ar + ai * ai);
            float g = gelu_exact(r + brelu);
            float h2r, h2i;
            if (r > 0.f) { float f = g / r; h2r = f * ar; h2i = f * ai; }
            else { h2r = g; h2i = 0.f; }
            short rh = f2bfs(h2r), ih = f2bfs(h2i);
            vhr[ci] = rh; vhi[ci] = ih;
            vlr[ci] = f2bfs(h2r - bfs2f(rh));
            vli[ci] = f2bfs(h2i - bfs2f(ih));
        }
        *(s16x8*)&H2[tl * 264 + cg * 8]       = vhr;
        *(s16x8*)&H2[tl * 264 + 64 + cg * 8]  = vhi;
        *(s16x8*)&H2[tl * 264 + 128 + cg * 8] = vlr;
        *(s16x8*)&H2[tl * 264 + 192 + cg * 8] = vli;
    }
    __syncthreads();

    // ---- GEMM2: A = H2, B frags from W2f
    f32x4 acc2[2][2] = {};
#pragma unroll
    for (int lc = 0; lc < 6; ++lc) {
        const int ka = ASRC[lc] * 64;
        const int kb = BSRC[lc];
#pragma unroll
        for (int kh = 0; kh < 2; ++kh) {
            s16x8 a0 = *(const s16x8*)&H2[frow * 264 + ka + kh * 32 + fcol];
            s16x8 a1 = *(const s16x8*)&H2[(16 + frow) * 264 + ka + kh * 32 + fcol];
#pragma unroll
            for (int n = 0; n < 2; ++n) {
                s16x8 bfv = W2v[(size_t)((((wv * 2 + n) * 4 + kb) * 2 + kh) * 64 + lane)];
                acc2[0][n] = __builtin_amdgcn_mfma_f32_16x16x32_bf16(a0, bfv, acc2[0][n], 0, 0, 0);
                acc2[1][n] = __builtin_amdgcn_mfma_f32_16x16x32_bf16(a1, bfv, acc2[1][n], 0, 0, 0);
            }
        }
    }
    // cL aliases aL (smemA): all aL reads completed before the barrier above
    // GEMM2; no thread reads smemA during GEMM2.
#pragma unroll
    for (int m = 0; m < 2; ++m)
#pragma unroll
        for (int n = 0; n < 2; ++n)
#pragma unroll
            for (int r = 0; r < 4; ++r)
                cL[(m * 16 + rbase + r) * 132 + wv * 32 + n * 16 + cidx] = acc2[m][n][r];
    __syncthreads();

    // ---- phase 8: gate + compact coalesced store (lane=t)
    if (valid) {
        int h = rows[t], j = cols[t];
        size_t wbase = (size_t)rs8[h] + j;
        f32x4 cr0 = *(const f32x4*)&cL[tl * 132 + cg * 8];
        f32x4 cr1 = *(const f32x4*)&cL[tl * 132 + cg * 8 + 4];
        f32x4 ci0 = *(const f32x4*)&cL[tl * 132 + 64 + cg * 8];
        f32x4 ci1 = *(const f32x4*)&cL[tl * 132 + 64 + cg * 8 + 4];
#pragma unroll
        for (int ci = 0; ci < 8; ++ci) {
            int c = cg * 8 + ci;
            float cr  = (ci < 4) ? cr0[ci & 3] : cr1[ci & 3];
            float cii = (ci < 4) ? ci0[ci & 3] : ci1[ci & 3];
            float xr = Xcr[(size_t)(b * 64 + c) * T128 + t];
            float xi = Xci[(size_t)(b * 64 + c) * T128 + t];
            float r3 = sqrtf(cr * cr + cii * cii);
            float gm = glu_mags[(size_t)c * T + t];
            float gp = glu_phases[(size_t)c * T + t];
            float sg = 1.0f / (1.0f + expf(-(r3 + gm)));
            float ux, uy;
            if (r3 > 0.f) { float ir3 = 1.0f / r3; ux = cr * ir3; uy = cii * ir3; }
            else { ux = 1.f; uy = 0.f; }
            float sp, cp;
            sincosf(gp, &sp, &cp);
            float gx = sg * (ux * cp - uy * sp);
            float gy = sg * (ux * sp + uy * cp);
            size_t base = (size_t)(b * 64 + c) * T8cap + wbase;
            Xgr[base] = __float2bfloat16(xr * gx - xi * gy);
            Xgi[base] = __float2bfloat16(xr * gy + xi * gx);
        }
    }
}

// ------- depthwise conv + add (bf16 y, h-major rows, 8-wide, XCD swizzle)
__global__ __launch_bounds__(256) void conv_add_kernel(
    const bf16* __restrict__ y, const float* __restrict__ dw,
    float* __restrict__ out)
{
    const int nb = gridDim.x;
    const int chunk = nb >> 3;
    const int orig = blockIdx.x;
    const int swz = (orig & 7) * chunk + (orig >> 3);   // bijective: nb % 8 == 0
    int g = swz * 256 + threadIdx.x;
    int w8 = g % 90;
    int rem = g / 90;
    int h = rem % Hh;
    int bc = rem / Hh;
    int c = bc & (Cc - 1);
    int w = w8 * 8;
    int walt = (w >= Ww / 2) ? (w - Ww / 2) : (w + Ww / 2);
    float acc[8];
    {
        s16x8 v0 = *(const s16x8*)&y[((size_t)h * BC + bc) * NI + w];
#pragma unroll
        for (int e = 0; e < 8; ++e) acc[e] = bfs2f(v0[e]);
    }
#pragma unroll
    for (int k = 0; k < 11; ++k) {
        int hp = h + k - 5;
        int hh, ww;
        if (hp < 0)        { hh = -1 - hp;         ww = walt; }
        else if (hp >= Hh) { hh = 2 * Hh - 1 - hp; ww = walt; }
        else               { hh = hp;              ww = w; }
        s16x8 v = *(const s16x8*)&y[((size_t)hh * BC + bc) * NI + ww];
        float dwk = dw[c * 11 + k];
#pragma unroll
        for (int e = 0; e < 8; ++e)
            acc[e] = fmaf(dwk, bfs2f(v[e]), acc[e]);
    }
    float* ob = &out[((size_t)bc * Hh + h) * Ww + w];
    *(float4*)&ob[0] = make_float4(acc[0], acc[1], acc[2], acc[3]);
    *(float4*)&ob[4] = make_float4(acc[4], acc[5], acc[6], acc[7]);
}

// ------------------------------------------------------------------ launch
extern "C" void kernel_launch(void* const* d_in, const int* in_sizes, int n_in,
                              void* d_out, int out_size, void* d_ws, size_t ws_size,
                              hipStream_t stream)
{
    const float* x      = (const float*)d_in[0];
    const float* mean_r = (const float*)d_in[1];
    const float* mean_i = (const float*)d_in[2];
    const float* stdv   = (const float*)d_in[3];
    const float* mags_r = (const float*)d_in[4];
    const float* mags_i = (const float*)d_in[5];
    const float* bias_r = (const float*)d_in[6];
    const float* bias_i = (const float*)d_in[7];
    const float* w1_r   = (const float*)d_in[8];
    const float* w1_i   = (const float*)d_in[9];
    const float* brelu  = (const float*)d_in[10];
    const float* w2_r   = (const float*)d_in[11];
    const float* w2_i   = (const float*)d_in[12];
    const float* glu_m  = (const float*)d_in[13];
    const float* glu_p  = (const float*)d_in[14];
    const float* dw     = (const float*)d_in[15];
    const int*   rows   = (const int*)d_in[16];
    const int*   cols   = (const int*)d_in[17];
    const int T = in_sizes[16];
    const int T128 = ((T + 127) / 128) * 128;
    const int T8cap = ((T + 7 * Hh) + 127) & ~127;

    char* ws = (char*)d_ws;
    const size_t SApc  = (size_t)CM * KA * 2;             // 35,389,440
    const size_t XC_SZ = (size_t)BC * T128 * 4;           // ~42.7 MB
    const size_t XG_SZ = (size_t)BC * T8cap * 2;          // ~22.0 MB
    // Lifetimes (stream-ordered):
    //   fwd:    Ap/Aq [0, 2*SApc=70.8M)  write Xc [70.8M, ~156.1M)
    //   fill:   Xg [0, 2*XG=44M)         (Ap/Aq dead)
    //   middle: read Xc, write Xg        (disjoint)
    //   inv:    read Xg, write y [44M, ~114.8M)  (Ap/Aq/Xcr dead; Xci tail
    //           overlap is dead by inv time)
    //   conv:   read y
    //   builds at [~156.1M, ~159.2M)
    bf16*  Ap  = (bf16*)ws;
    bf16*  Aq  = (bf16*)(ws + SApc);
    float* Xcr = (float*)(ws + 2 * SApc);
    float* Xci = (float*)(ws + 2 * SApc + XC_SZ);
    bf16*  Xgr = (bf16*)ws;
    bf16*  Xgi = (bf16*)(ws + XG_SZ);
    bf16*  y   = (bf16*)(ws + 2 * XG_SZ);
    size_t boff = 2 * SApc + 2 * XC_SZ;                   // ~156.1 MB
    bf16*  Bce = (bf16*)(ws + boff);
    bf16*  Bse = (bf16*)(ws + boff + (size_t)NF * KF3 * 2);
    bf16*  Bti = (bf16*)(ws + boff + 2 * (size_t)NF * KF3 * 2);
    bf16*  W1f = (bf16*)(ws + boff + 2 * (size_t)NF * KF3 * 2 + (size_t)NI * KI * 2);
    bf16*  W2f = W1f + 32768;
    int*   rs  = (int*)(W2f + 32768);
    int*   rs8 = rs + (Hh + 2);

    build_bfwd_kernel<<<(NF * KF3 + 255) / 256, 256, 0, stream>>>(Bce, Bse);
    build_binv_kernel<<<(NI * KI + 255) / 256, 256, 0, stream>>>(Bti);
    build_wf_kernel<<<(2 * 32768 + 255) / 256, 256, 0, stream>>>(
        w1_r, w1_i, w2_r, w2_i, W1f, W2f);
    row_starts_kernel<<<1, 512, 0, stream>>>(rows, T, rs, rs8);

    for (int ch = 0; ch < CHUNKS; ++ch) {
        pack_kernel<<<(CM * KA + 255) / 256, 256, 0, stream>>>(
            x, Ap, Aq, ch * HPC);
        gemm_fwd_compact_kernel<<<dim3(CM / 128, NF / 128, 2), 256, 0, stream>>>(
            Ap, Aq, Bce, Bse, Xcr, Xci, rs, T128, ch * HPC);
    }

    fill_zero_kernel<<<2048, 256, 0, stream>>>((uint4*)Xgr, (long)(2 * XG_SZ / 16));

    const int nT32 = (T + 31) / 32;
    middle_fused_kernel<<<dim3(nT32, Bb), 256, 0, stream>>>(
        Xcr, Xci, Xgr, Xgi, mean_r, mean_i, stdv, mags_r, mags_i,
        bias_r, bias_i, W1f, W2f, brelu, glu_m, glu_p, rows, cols, rs8,
        T, T128, T8cap);

    gemm_inv_kernel<<<dim3(Hh, NI / 128), 256, 0, stream>>>(
        Xgr, Xgi, Bti, rs8, y, T8cap);

    conv_add_kernel<<<(Bb * Cc * Hh * 90) / 256, 256, 0, stream>>>(y, dw, (float*)d_out);
}